// Round 4
// baseline (1056.632 us; speedup 1.0000x reference)
//
#include <hip/hip_runtime.h>
#include <math.h>

#define N_NODES 100000
#define N_EDGES 1000000
#define HID     64
#define HIER    32
#define NDIM    128
#define EDIM    32
#define K1      96    // HIER + HID
#define C1      128   // 2*HID
#define NCLS    10
#define BN_EPS  1e-5f
#define SCAN_B  98    // ceil(N_NODES/1024)
#define RB      8     // row-block factor (N_NODES % RB == 0)

// ---------------- CSR build ----------------

__global__ void k_count(const int* __restrict__ ei, int* __restrict__ cnt) {
    int i = blockIdx.x * blockDim.x + threadIdx.x;
    if (i < N_EDGES) atomicAdd(&cnt[ei[N_EDGES + i]], 1);
}

__global__ void k_scan1(const int* __restrict__ cnt, int* __restrict__ offs,
                        float* __restrict__ dinv, int* __restrict__ bsum) {
    __shared__ int buf[2][1024];
    int t = threadIdx.x, b = blockIdx.x;
    int i = b * 1024 + t;
    int v = (i < N_NODES) ? cnt[i] : 0;
    buf[0][t] = v; __syncthreads();
    int pi = 0;
    for (int off = 1; off < 1024; off <<= 1) {
        int x = buf[pi][t];
        if (t >= off) x += buf[pi][t - off];
        buf[pi ^ 1][t] = x; __syncthreads(); pi ^= 1;
    }
    int incl = buf[pi][t];
    if (i < N_NODES) {
        offs[i] = incl - v;                       // exclusive within block
        dinv[i] = rsqrtf((float)(v + 1));         // +1 self loop
    }
    if (t == 1023) bsum[b] = incl;
}

__global__ void k_scan2(int* __restrict__ bsum, int nb) {
    __shared__ int buf[2][1024];
    int t = threadIdx.x;
    int v = (t < nb) ? bsum[t] : 0;
    buf[0][t] = v; __syncthreads();
    int pi = 0;
    for (int off = 1; off < 1024; off <<= 1) {
        int x = buf[pi][t];
        if (t >= off) x += buf[pi][t - off];
        buf[pi ^ 1][t] = x; __syncthreads(); pi ^= 1;
    }
    int incl = buf[pi][t];
    if (t < nb) bsum[t] = incl - v;               // exclusive
}

__global__ void k_scan3(const int* __restrict__ bsum, int* __restrict__ offs) {
    int b = blockIdx.x;
    int i = b * 1024 + threadIdx.x;
    if (i < N_NODES) offs[i] += bsum[b];
    if (i == 0) offs[N_NODES] = N_EDGES;
}

__global__ void k_fill(const int* __restrict__ ei, const int* __restrict__ offs,
                       int* __restrict__ cursor, int* __restrict__ csr_src,
                       int* __restrict__ csr_eid) {
    int i = blockIdx.x * blockDim.x + threadIdx.x;
    if (i >= N_EDGES) return;
    int s = ei[i], d = ei[N_EDGES + i];
    int pos = offs[d] + atomicAdd(&cursor[d], 1);
    csr_src[pos] = s;
    csr_eid[pos] = i;
}

// ---------------- node encoder: h0 = x @ w_node + b ----------------
// Row-blocked: each LDS weight scalar is read once and applied to RB rows.

__global__ __launch_bounds__(256) void k_h0(const float* __restrict__ x,
                                            const float* __restrict__ w,
                                            const float* __restrict__ bias,
                                            float* __restrict__ h,
                                            float* __restrict__ hsum) {
    __shared__ float ws[NDIM * HID];  // 32 KB
    for (int i = threadIdx.x; i < NDIM * HID; i += 256) ws[i] = w[i];
    __syncthreads();
    int lane = threadIdx.x & 63, wid = threadIdx.x >> 6;
    float bl = bias[lane];
    for (int g = blockIdx.x * 4 + wid; g < N_NODES / RB; g += gridDim.x * 4) {
        int row0 = g * RB;
        float acc[RB];
        #pragma unroll
        for (int r = 0; r < RB; ++r) acc[r] = bl;
        for (int k4 = 0; k4 < NDIM / 4; ++k4) {
            int k = k4 * 4;
            float w0 = ws[(k + 0) * HID + lane];
            float w1 = ws[(k + 1) * HID + lane];
            float w2 = ws[(k + 2) * HID + lane];
            float w3 = ws[(k + 3) * HID + lane];
            #pragma unroll
            for (int r = 0; r < RB; ++r) {
                float4 xv = *(const float4*)(x + (size_t)(row0 + r) * NDIM + k);
                acc[r] += xv.x * w0 + xv.y * w1 + xv.z * w2 + xv.w * w3;
            }
        }
        #pragma unroll
        for (int r = 0; r < RB; ++r) {
            h[(size_t)(row0 + r) * HID + lane] = acc[r];
            hsum[(size_t)(row0 + r) * HID + lane] = acc[r];
        }
    }
}

// ---------------- edge aggregation: agg[v] = sum norm*e_raw, wsum[v] = sum norm ----------------

__global__ __launch_bounds__(256) void k_agg(const float* __restrict__ e,
                                             const int* __restrict__ csr_src,
                                             const int* __restrict__ csr_eid,
                                             const int* __restrict__ offs,
                                             const float* __restrict__ dinv,
                                             float* __restrict__ agg,
                                             float* __restrict__ wsumv) {
    int wid = threadIdx.x >> 6;
    int v = blockIdx.x * 4 + wid;
    if (v >= N_NODES) return;
    int lane = threadIdx.x & 63;
    int half = lane >> 5, dim = lane & 31;
    int start = offs[v], end = offs[v + 1];
    float dv = dinv[v];
    float acc = 0.f, wacc = 0.f;
    for (int i = start + half; i < end; i += 2) {
        int s = csr_src[i];
        int eid = csr_eid[i];
        float ds = dinv[s];
        acc += ds * e[(size_t)eid * EDIM + dim];
        wacc += ds;
    }
    acc += __shfl_xor(acc, 32);
    wacc += __shfl_xor(wacc, 32);
    if (half == 0) agg[(size_t)v * EDIM + dim] = dv * acc;
    if (lane == 0) wsumv[v] = dv * wacc;
}

// ---------------- s_e = agg @ w_edge + wsum * b_edge ----------------

__global__ __launch_bounds__(256) void k_se(const float* __restrict__ agg,
                                            const float* __restrict__ wsumv,
                                            const float* __restrict__ we,
                                            const float* __restrict__ be,
                                            float* __restrict__ se) {
    int lane = threadIdx.x & 63, wid = threadIdx.x >> 6;
    float wreg[EDIM];
    #pragma unroll
    for (int k = 0; k < EDIM; ++k) wreg[k] = we[k * HID + lane];
    float bl = be[lane];
    for (int v = blockIdx.x * 4 + wid; v < N_NODES; v += gridDim.x * 4) {
        const float4* ar = (const float4*)(agg + (size_t)v * EDIM);
        float acc = wsumv[v] * bl;
        #pragma unroll
        for (int k4 = 0; k4 < EDIM / 4; ++k4) {
            float4 av = ar[k4];
            int k = k4 * 4;
            acc += av.x * wreg[k + 0] + av.y * wreg[k + 1] +
                   av.z * wreg[k + 2] + av.w * wreg[k + 3];
        }
        se[(size_t)v * HID + lane] = acc;
    }
}

// ---------------- one GCN layer (pull) ----------------

__global__ __launch_bounds__(256) void k_layer(const float* __restrict__ hold,
                                               const float* __restrict__ se,
                                               const int* __restrict__ csr_src,
                                               const int* __restrict__ offs,
                                               const float* __restrict__ dinv,
                                               float* __restrict__ hnew,
                                               float* __restrict__ hsum) {
    int wid = threadIdx.x >> 6;
    int v = blockIdx.x * 4 + wid;
    if (v >= N_NODES) return;
    int lane = threadIdx.x & 63;
    int start = offs[v], end = offs[v + 1];
    float dv = dinv[v];
    size_t vi = (size_t)v * HID + lane;
    float acc = se[vi] + dv * dv * hold[vi];
    for (int i = start; i < end; ++i) {
        int s = csr_src[i];
        acc += dv * dinv[s] * hold[(size_t)s * HID + lane];
    }
    float hv = (acc > 0.f) ? acc : 0.2f * acc;
    hnew[vi] = hv;
    hsum[vi] += hv;
}

// ---------------- z block helper: z = [hsum|c] @ w_out1 + b_out1 for RB rows ----------------
// lane = output col pair (lane, lane+64); weights read once per k, reused RB times.

__device__ __forceinline__ void compute_z_block(const float* __restrict__ hsum,
                                                const float* __restrict__ c,
                                                const float* ws, float b0, float b1v,
                                                int row0, int lane,
                                                float* z0, float* z1) {
    #pragma unroll
    for (int r = 0; r < RB; ++r) { z0[r] = b0; z1[r] = b1v; }
    for (int k4 = 0; k4 < HID / 4; ++k4) {
        int k = k4 * 4;
        float wa0 = ws[(k + 0) * C1 + lane], wb0 = ws[(k + 0) * C1 + 64 + lane];
        float wa1 = ws[(k + 1) * C1 + lane], wb1 = ws[(k + 1) * C1 + 64 + lane];
        float wa2 = ws[(k + 2) * C1 + lane], wb2 = ws[(k + 2) * C1 + 64 + lane];
        float wa3 = ws[(k + 3) * C1 + lane], wb3 = ws[(k + 3) * C1 + 64 + lane];
        #pragma unroll
        for (int r = 0; r < RB; ++r) {
            float4 xv = *(const float4*)(hsum + (size_t)(row0 + r) * HID + k);
            z0[r] += xv.x * wa0 + xv.y * wa1 + xv.z * wa2 + xv.w * wa3;
            z1[r] += xv.x * wb0 + xv.y * wb1 + xv.z * wb2 + xv.w * wb3;
        }
    }
    for (int k4 = 0; k4 < HIER / 4; ++k4) {
        int k = HID + k4 * 4;
        float wa0 = ws[(k + 0) * C1 + lane], wb0 = ws[(k + 0) * C1 + 64 + lane];
        float wa1 = ws[(k + 1) * C1 + lane], wb1 = ws[(k + 1) * C1 + 64 + lane];
        float wa2 = ws[(k + 2) * C1 + lane], wb2 = ws[(k + 2) * C1 + 64 + lane];
        float wa3 = ws[(k + 3) * C1 + lane], wb3 = ws[(k + 3) * C1 + 64 + lane];
        #pragma unroll
        for (int r = 0; r < RB; ++r) {
            float4 xv = *(const float4*)(c + (size_t)(row0 + r) * HIER + k4 * 4);
            z0[r] += xv.x * wa0 + xv.y * wa1 + xv.z * wa2 + xv.w * wa3;
            z1[r] += xv.x * wb0 + xv.y * wb1 + xv.z * wb2 + xv.w * wb3;
        }
    }
}

// ---------------- BN stats ----------------

__global__ __launch_bounds__(256) void k_stats(const float* __restrict__ hsum,
                                               const float* __restrict__ c,
                                               const float* __restrict__ w1,
                                               const float* __restrict__ b1,
                                               float* __restrict__ stats) {
    __shared__ float ws[K1 * C1];   // 48 KB
    __shared__ float red[4][C1];
    for (int i = threadIdx.x; i < K1 * C1; i += 256) ws[i] = w1[i];
    __syncthreads();
    int lane = threadIdx.x & 63, wid = threadIdx.x >> 6;
    float b0 = b1[lane], bb1 = b1[64 + lane];
    float s0 = 0.f, s1 = 0.f, q0 = 0.f, q1 = 0.f;
    for (int g = blockIdx.x * 4 + wid; g < N_NODES / RB; g += gridDim.x * 4) {
        float z0[RB], z1[RB];
        compute_z_block(hsum, c, ws, b0, bb1, g * RB, lane, z0, z1);
        #pragma unroll
        for (int r = 0; r < RB; ++r) {
            s0 += z0[r]; q0 += z0[r] * z0[r];
            s1 += z1[r]; q1 += z1[r] * z1[r];
        }
    }
    red[wid][lane] = s0; red[wid][64 + lane] = s1;
    __syncthreads();
    if (threadIdx.x < C1) {
        float t = red[0][threadIdx.x] + red[1][threadIdx.x] +
                  red[2][threadIdx.x] + red[3][threadIdx.x];
        atomicAdd(&stats[threadIdx.x], t);
    }
    __syncthreads();
    red[wid][lane] = q0; red[wid][64 + lane] = q1;
    __syncthreads();
    if (threadIdx.x < C1) {
        float t = red[0][threadIdx.x] + red[1][threadIdx.x] +
                  red[2][threadIdx.x] + red[3][threadIdx.x];
        atomicAdd(&stats[C1 + threadIdx.x], t);
    }
}

__global__ void k_ab(const float* __restrict__ stats, const float* __restrict__ gamma,
                     const float* __restrict__ beta, float* __restrict__ ab) {
    int t = threadIdx.x;
    if (t < C1) {
        float mu = stats[t] / (float)N_NODES;
        float var = stats[C1 + t] / (float)N_NODES - mu * mu;
        float inv = rsqrtf(var + BN_EPS);
        float a = gamma[t] * inv;
        ab[t] = a;
        ab[C1 + t] = beta[t] - mu * a;
    }
}

// ---------------- output: PReLU(BN(z)) @ w_out2 + b_out2 ----------------

__global__ __launch_bounds__(256) void k_out(const float* __restrict__ hsum,
                                             const float* __restrict__ c,
                                             const float* __restrict__ w1,
                                             const float* __restrict__ b1,
                                             const float* __restrict__ ab,
                                             const float* __restrict__ pa,
                                             const float* __restrict__ w2,
                                             const float* __restrict__ b2,
                                             float* __restrict__ out) {
    __shared__ float ws[K1 * C1];   // 48 KB
    for (int i = threadIdx.x; i < K1 * C1; i += 256) ws[i] = w1[i];
    __syncthreads();
    int lane = threadIdx.x & 63, wid = threadIdx.x >> 6;
    float w2a[NCLS], w2b[NCLS];
    #pragma unroll
    for (int j = 0; j < NCLS; ++j) {
        w2a[j] = w2[lane * NCLS + j];
        w2b[j] = w2[(64 + lane) * NCLS + j];
    }
    float b0 = b1[lane], bb1 = b1[64 + lane];
    float sa0 = ab[lane], sa1 = ab[64 + lane];
    float sb0 = ab[C1 + lane], sb1 = ab[C1 + 64 + lane];
    float alpha = pa[0];
    for (int g = blockIdx.x * 4 + wid; g < N_NODES / RB; g += gridDim.x * 4) {
        int row0 = g * RB;
        float z0[RB], z1[RB];
        compute_z_block(hsum, c, ws, b0, bb1, row0, lane, z0, z1);
        #pragma unroll
        for (int r = 0; r < RB; ++r) {
            float p0 = z0[r] * sa0 + sb0; p0 = (p0 > 0.f) ? p0 : alpha * p0;
            float p1 = z1[r] * sa1 + sb1; p1 = (p1 > 0.f) ? p1 : alpha * p1;
            float pj[NCLS];
            #pragma unroll
            for (int j = 0; j < NCLS; ++j) pj[j] = p0 * w2a[j] + p1 * w2b[j];
            #pragma unroll
            for (int j = 0; j < NCLS; ++j) {
                #pragma unroll
                for (int d = 32; d >= 1; d >>= 1) pj[j] += __shfl_xor(pj[j], d);
            }
            if (lane == 0) {
                #pragma unroll
                for (int j = 0; j < NCLS; ++j)
                    out[(size_t)(row0 + r) * NCLS + j] = pj[j] + b2[j];
            }
        }
    }
}

// ---------------- host ----------------

extern "C" void kernel_launch(void* const* d_in, const int* in_sizes, int n_in,
                              void* d_out, int out_size, void* d_ws, size_t ws_size,
                              hipStream_t stream) {
    const float* x      = (const float*)d_in[0];
    const float* e      = (const float*)d_in[1];
    const float* c      = (const float*)d_in[2];
    const float* w_node = (const float*)d_in[3];
    const float* b_node = (const float*)d_in[4];
    const float* w_edge = (const float*)d_in[5];
    const float* b_edge = (const float*)d_in[6];
    const float* w_out1 = (const float*)d_in[7];
    const float* b_out1 = (const float*)d_in[8];
    const float* gamma  = (const float*)d_in[9];
    const float* beta   = (const float*)d_in[10];
    const float* pa     = (const float*)d_in[11];
    const float* w_out2 = (const float*)d_in[12];
    const float* b_out2 = (const float*)d_in[13];
    const int*   ei     = (const int*)d_in[14];
    float* out = (float*)d_out;

    char* wsb = (char*)d_ws;
    size_t off = 0;
    auto alloc = [&](size_t bytes) {
        void* p = wsb + off;
        off = (off + bytes + 255) & ~(size_t)255;
        return p;
    };
    int*   cnt     = (int*)alloc(4ull * N_NODES);
    int*   offs    = (int*)alloc(4ull * (N_NODES + 1));
    float* dinv    = (float*)alloc(4ull * N_NODES);
    int*   bsum    = (int*)alloc(4ull * 128);
    int*   csr_src = (int*)alloc(4ull * N_EDGES);
    int*   csr_eid = (int*)alloc(4ull * N_EDGES);
    float* agg     = (float*)alloc(4ull * N_NODES * EDIM);
    float* wsumv   = (float*)alloc(4ull * N_NODES);
    float* se      = (float*)alloc(4ull * N_NODES * HID);
    float* h_a     = (float*)alloc(4ull * N_NODES * HID);
    float* h_b     = (float*)alloc(4ull * N_NODES * HID);
    float* h_sum   = (float*)alloc(4ull * N_NODES * HID);
    float* stats   = (float*)alloc(4ull * 256);
    float* ab      = (float*)alloc(4ull * 256);

    hipMemsetAsync(cnt, 0, 4ull * N_NODES, stream);
    hipMemsetAsync(stats, 0, 4ull * 256, stream);

    k_count<<<(N_EDGES + 255) / 256, 256, 0, stream>>>(ei, cnt);
    k_scan1<<<SCAN_B, 1024, 0, stream>>>(cnt, offs, dinv, bsum);
    k_scan2<<<1, 1024, 0, stream>>>(bsum, SCAN_B);
    k_scan3<<<SCAN_B, 1024, 0, stream>>>(bsum, offs);
    hipMemsetAsync(cnt, 0, 4ull * N_NODES, stream);
    k_fill<<<(N_EDGES + 255) / 256, 256, 0, stream>>>(ei, offs, cnt, csr_src, csr_eid);

    k_h0<<<1024, 256, 0, stream>>>(x, w_node, b_node, h_a, h_sum);
    k_agg<<<N_NODES / 4, 256, 0, stream>>>(e, csr_src, csr_eid, offs, dinv, agg, wsumv);
    k_se<<<1280, 256, 0, stream>>>(agg, wsumv, w_edge, b_edge, se);

    k_layer<<<N_NODES / 4, 256, 0, stream>>>(h_a, se, csr_src, offs, dinv, h_b, h_sum);
    k_layer<<<N_NODES / 4, 256, 0, stream>>>(h_b, se, csr_src, offs, dinv, h_a, h_sum);
    k_layer<<<N_NODES / 4, 256, 0, stream>>>(h_a, se, csr_src, offs, dinv, h_b, h_sum);

    k_stats<<<768, 256, 0, stream>>>(h_sum, c, w_out1, b_out1, stats);
    k_ab<<<1, 128, 0, stream>>>(stats, gamma, beta, ab);
    k_out<<<768, 256, 0, stream>>>(h_sum, c, w_out1, b_out1, ab, pa, w_out2, b_out2, out);
}

// Round 5
// 732.145 us; speedup vs baseline: 1.4432x; 1.4432x over previous
//
#include <hip/hip_runtime.h>
#include <math.h>

#define N_NODES 100000
#define N_EDGES 1000000
#define HID     64
#define HIER    32
#define NDIM    128
#define EDIM    32
#define K1      96    // HIER + HID
#define C1      128   // 2*HID
#define NCLS    10
#define BN_EPS  1e-5f
#define SCAN_B  98    // ceil(N_NODES/1024)
#define ZTILES  782   // ceil(N_NODES/128)
#define HTILES  391   // ceil(N_NODES/256)

// ---------------- CSR build ----------------

__global__ void k_count(const int* __restrict__ ei, int* __restrict__ cnt) {
    int i = blockIdx.x * blockDim.x + threadIdx.x;
    if (i < N_EDGES) atomicAdd(&cnt[ei[N_EDGES + i]], 1);
}

__global__ void k_scan1(const int* __restrict__ cnt, int* __restrict__ offs,
                        float* __restrict__ dinv, int* __restrict__ bsum) {
    __shared__ int buf[2][1024];
    int t = threadIdx.x, b = blockIdx.x;
    int i = b * 1024 + t;
    int v = (i < N_NODES) ? cnt[i] : 0;
    buf[0][t] = v; __syncthreads();
    int pi = 0;
    for (int off = 1; off < 1024; off <<= 1) {
        int x = buf[pi][t];
        if (t >= off) x += buf[pi][t - off];
        buf[pi ^ 1][t] = x; __syncthreads(); pi ^= 1;
    }
    int incl = buf[pi][t];
    if (i < N_NODES) {
        offs[i] = incl - v;
        dinv[i] = rsqrtf((float)(v + 1));
    }
    if (t == 1023) bsum[b] = incl;
}

__global__ void k_scan2(int* __restrict__ bsum, int nb) {
    __shared__ int buf[2][1024];
    int t = threadIdx.x;
    int v = (t < nb) ? bsum[t] : 0;
    buf[0][t] = v; __syncthreads();
    int pi = 0;
    for (int off = 1; off < 1024; off <<= 1) {
        int x = buf[pi][t];
        if (t >= off) x += buf[pi][t - off];
        buf[pi ^ 1][t] = x; __syncthreads(); pi ^= 1;
    }
    int incl = buf[pi][t];
    if (t < nb) bsum[t] = incl - v;
}

__global__ void k_scan3(const int* __restrict__ bsum, int* __restrict__ offs) {
    int b = blockIdx.x;
    int i = b * 1024 + threadIdx.x;
    if (i < N_NODES) offs[i] += bsum[b];
    if (i == 0) offs[N_NODES] = N_EDGES;
}

__global__ void k_fill(const int* __restrict__ ei, const int* __restrict__ offs,
                       int* __restrict__ cursor, int* __restrict__ csr_src,
                       int* __restrict__ csr_eid) {
    int i = blockIdx.x * blockDim.x + threadIdx.x;
    if (i >= N_EDGES) return;
    int s = ei[i], d = ei[N_EDGES + i];
    int pos = offs[d] + atomicAdd(&cursor[d], 1);
    csr_src[pos] = s;
    csr_eid[pos] = i;
}

// ---------------- node encoder (tiled GEMM): h0 = x @ w_node + b ----------------
// 256-row x 64-col block tile; U staged coalesced to LDS (stride 33, 2-way banks);
// thread tile 8x8; k chunked by 32.

__global__ __launch_bounds__(256) void k_h0t(const float* __restrict__ x,
                                             const float* __restrict__ w,
                                             const float* __restrict__ bias,
                                             float* __restrict__ h,
                                             float* __restrict__ hsum) {
    __shared__ float ws[NDIM * HID];   // 32 KB
    __shared__ float xt[256 * 33];     // 33.8 KB
    for (int i = threadIdx.x; i < NDIM * HID; i += 256) ws[i] = w[i];
    int tid = threadIdx.x;
    int lane = tid & 63, wave = tid >> 6;
    int lr = lane >> 3, lc = lane & 7;
    int rbase = wave * 64 + lr * 8;
    int cbase = lc * 8;
    float bA[8];
    #pragma unroll
    for (int j = 0; j < 8; ++j) bA[j] = bias[cbase + j];
    for (int tile = blockIdx.x; tile < HTILES; tile += gridDim.x) {
        int row0 = tile * 256;
        float acc[8][8];
        #pragma unroll
        for (int i = 0; i < 8; ++i)
            #pragma unroll
            for (int j = 0; j < 8; ++j) acc[i][j] = 0.f;
        for (int ch = 0; ch < 4; ++ch) {
            __syncthreads();
            #pragma unroll
            for (int p = 0; p < 8; ++p) {
                int idx = p * 256 + tid;
                int row = idx >> 3, kq = idx & 7;
                int gk = ch * 32 + kq * 4;
                float4 v = make_float4(0.f, 0.f, 0.f, 0.f);
                int gr = row0 + row;
                if (gr < N_NODES) v = *(const float4*)&x[(size_t)gr * NDIM + gk];
                float* d = &xt[row * 33 + kq * 4];
                d[0] = v.x; d[1] = v.y; d[2] = v.z; d[3] = v.w;
            }
            __syncthreads();
            for (int k = 0; k < 32; ++k) {
                float u[8];
                #pragma unroll
                for (int i = 0; i < 8; ++i) u[i] = xt[(rbase + i) * 33 + k];
                const float* wrow = &ws[(ch * 32 + k) * HID + cbase];
                float4 wa = *(const float4*)&wrow[0];
                float4 wb = *(const float4*)&wrow[4];
                #pragma unroll
                for (int i = 0; i < 8; ++i) {
                    acc[i][0] += u[i] * wa.x; acc[i][1] += u[i] * wa.y;
                    acc[i][2] += u[i] * wa.z; acc[i][3] += u[i] * wa.w;
                    acc[i][4] += u[i] * wb.x; acc[i][5] += u[i] * wb.y;
                    acc[i][6] += u[i] * wb.z; acc[i][7] += u[i] * wb.w;
                }
            }
        }
        #pragma unroll
        for (int i = 0; i < 8; ++i) {
            int gr = row0 + rbase + i;
            if (gr < N_NODES) {
                float4 lo = make_float4(acc[i][0] + bA[0], acc[i][1] + bA[1],
                                        acc[i][2] + bA[2], acc[i][3] + bA[3]);
                float4 hi = make_float4(acc[i][4] + bA[4], acc[i][5] + bA[5],
                                        acc[i][6] + bA[6], acc[i][7] + bA[7]);
                *(float4*)&h[(size_t)gr * HID + cbase] = lo;
                *(float4*)&h[(size_t)gr * HID + cbase + 4] = hi;
                *(float4*)&hsum[(size_t)gr * HID + cbase] = lo;
                *(float4*)&hsum[(size_t)gr * HID + cbase + 4] = hi;
            }
        }
    }
}

// ---------------- edge aggregation ----------------

__global__ __launch_bounds__(256) void k_agg(const float* __restrict__ e,
                                             const int* __restrict__ csr_src,
                                             const int* __restrict__ csr_eid,
                                             const int* __restrict__ offs,
                                             const float* __restrict__ dinv,
                                             float* __restrict__ agg,
                                             float* __restrict__ wsumv) {
    int wid = threadIdx.x >> 6;
    int v = blockIdx.x * 4 + wid;
    if (v >= N_NODES) return;
    int lane = threadIdx.x & 63;
    int half = lane >> 5, dim = lane & 31;
    int start = offs[v], end = offs[v + 1];
    float dv = dinv[v];
    float acc = 0.f, wacc = 0.f;
    for (int i = start + half; i < end; i += 2) {
        int s = csr_src[i];
        int eid = csr_eid[i];
        float ds = dinv[s];
        acc += ds * e[(size_t)eid * EDIM + dim];
        wacc += ds;
    }
    acc += __shfl_xor(acc, 32);
    wacc += __shfl_xor(wacc, 32);
    if (half == 0) agg[(size_t)v * EDIM + dim] = dv * acc;
    if (lane == 0) wsumv[v] = dv * wacc;
}

// ---------------- s_e = agg @ w_edge + wsum * b_edge ----------------

__global__ __launch_bounds__(256) void k_se(const float* __restrict__ agg,
                                            const float* __restrict__ wsumv,
                                            const float* __restrict__ we,
                                            const float* __restrict__ be,
                                            float* __restrict__ se) {
    int lane = threadIdx.x & 63, wid = threadIdx.x >> 6;
    float wreg[EDIM];
    #pragma unroll
    for (int k = 0; k < EDIM; ++k) wreg[k] = we[k * HID + lane];
    float bl = be[lane];
    for (int v = blockIdx.x * 4 + wid; v < N_NODES; v += gridDim.x * 4) {
        const float4* ar = (const float4*)(agg + (size_t)v * EDIM);
        float acc = wsumv[v] * bl;
        #pragma unroll
        for (int k4 = 0; k4 < EDIM / 4; ++k4) {
            float4 av = ar[k4];
            int k = k4 * 4;
            acc += av.x * wreg[k + 0] + av.y * wreg[k + 1] +
                   av.z * wreg[k + 2] + av.w * wreg[k + 3];
        }
        se[(size_t)v * HID + lane] = acc;
    }
}

// ---------------- one GCN layer (pull) ----------------

__global__ __launch_bounds__(256) void k_layer(const float* __restrict__ hold,
                                               const float* __restrict__ se,
                                               const int* __restrict__ csr_src,
                                               const int* __restrict__ offs,
                                               const float* __restrict__ dinv,
                                               float* __restrict__ hnew,
                                               float* __restrict__ hsum) {
    int wid = threadIdx.x >> 6;
    int v = blockIdx.x * 4 + wid;
    if (v >= N_NODES) return;
    int lane = threadIdx.x & 63;
    int start = offs[v], end = offs[v + 1];
    float dv = dinv[v];
    size_t vi = (size_t)v * HID + lane;
    float acc = se[vi] + dv * dv * hold[vi];
    for (int i = start; i < end; ++i) {
        int s = csr_src[i];
        acc += dv * dinv[s] * hold[(size_t)s * HID + lane];
    }
    float hv = (acc > 0.f) ? acc : 0.2f * acc;
    hnew[vi] = hv;
    hsum[vi] += hv;
}

// ---------------- z GEMM + BN stats: z = [hsum|c] @ w_out1 + b_out1 ----------------
// 128-row x 128-col tile, k chunked by 48; U staged to LDS stride 49 (2-way banks);
// thread tile 8x8; writes z and accumulates per-col sum/sumsq.

__global__ __launch_bounds__(256) void k_zstats(const float* __restrict__ hsum,
                                                const float* __restrict__ cfeat,
                                                const float* __restrict__ w1,
                                                const float* __restrict__ b1,
                                                float* __restrict__ z,
                                                float* __restrict__ stats) {
    __shared__ float ws[K1 * C1];    // 48 KB
    __shared__ float ut[128 * 49];   // 24.5 KB
    __shared__ float red[4][64];     // 1 KB
    for (int i = threadIdx.x; i < K1 * C1; i += 256) ws[i] = w1[i];
    int tid = threadIdx.x;
    int lane = tid & 63, wave = tid >> 6;
    int lr = lane >> 3, lc = lane & 7;
    int wr = wave >> 1, wc = wave & 1;
    int rbase = wr * 64 + lr * 8;
    int cbase = wc * 64 + lc * 8;
    float bA[8];
    #pragma unroll
    for (int j = 0; j < 8; ++j) bA[j] = b1[cbase + j];
    float s[8], q[8];
    #pragma unroll
    for (int j = 0; j < 8; ++j) { s[j] = 0.f; q[j] = 0.f; }

    for (int tile = blockIdx.x; tile < ZTILES; tile += gridDim.x) {
        int row0 = tile * 128;
        float acc[8][8];
        #pragma unroll
        for (int i = 0; i < 8; ++i)
            #pragma unroll
            for (int j = 0; j < 8; ++j) acc[i][j] = 0.f;
        for (int ch = 0; ch < 2; ++ch) {
            int kbase = ch * 48;
            __syncthreads();
            #pragma unroll
            for (int p = 0; p < 6; ++p) {
                int idx = p * 256 + tid;
                int row = idx / 12, kq = idx % 12;
                int gk = kbase + kq * 4;
                float4 v = make_float4(0.f, 0.f, 0.f, 0.f);
                int gr = row0 + row;
                if (gr < N_NODES) {
                    if (gk < HID) v = *(const float4*)&hsum[(size_t)gr * HID + gk];
                    else          v = *(const float4*)&cfeat[(size_t)gr * HIER + (gk - HID)];
                }
                float* d = &ut[row * 49 + kq * 4];
                d[0] = v.x; d[1] = v.y; d[2] = v.z; d[3] = v.w;
            }
            __syncthreads();
            for (int k = 0; k < 48; ++k) {
                float u[8];
                #pragma unroll
                for (int i = 0; i < 8; ++i) u[i] = ut[(rbase + i) * 49 + k];
                const float* wrow = &ws[(kbase + k) * C1 + cbase];
                float4 wa = *(const float4*)&wrow[0];
                float4 wb = *(const float4*)&wrow[4];
                #pragma unroll
                for (int i = 0; i < 8; ++i) {
                    acc[i][0] += u[i] * wa.x; acc[i][1] += u[i] * wa.y;
                    acc[i][2] += u[i] * wa.z; acc[i][3] += u[i] * wa.w;
                    acc[i][4] += u[i] * wb.x; acc[i][5] += u[i] * wb.y;
                    acc[i][6] += u[i] * wb.z; acc[i][7] += u[i] * wb.w;
                }
            }
        }
        #pragma unroll
        for (int i = 0; i < 8; ++i) {
            int gr = row0 + rbase + i;
            if (gr < N_NODES) {
                float zz[8];
                #pragma unroll
                for (int j = 0; j < 8; ++j) {
                    zz[j] = acc[i][j] + bA[j];
                    s[j] += zz[j]; q[j] += zz[j] * zz[j];
                }
                *(float4*)&z[(size_t)gr * C1 + cbase] =
                    make_float4(zz[0], zz[1], zz[2], zz[3]);
                *(float4*)&z[(size_t)gr * C1 + cbase + 4] =
                    make_float4(zz[4], zz[5], zz[6], zz[7]);
            }
        }
    }

    // reduce stats: sum over lr lanes (masks 8/16/32), then over wr via LDS.
    #pragma unroll
    for (int j = 0; j < 8; ++j) {
        s[j] += __shfl_xor(s[j], 8); s[j] += __shfl_xor(s[j], 16); s[j] += __shfl_xor(s[j], 32);
        q[j] += __shfl_xor(q[j], 8); q[j] += __shfl_xor(q[j], 16); q[j] += __shfl_xor(q[j], 32);
    }
    __syncthreads();
    if (lr == 0) {
        #pragma unroll
        for (int j = 0; j < 8; ++j) red[wave][lc * 8 + j] = s[j];
    }
    __syncthreads();
    if (tid < 128) {
        int wc2 = tid >> 6, cl = tid & 63;
        atomicAdd(&stats[wc2 * 64 + cl], red[wc2][cl] + red[wc2 + 2][cl]);
    }
    __syncthreads();
    if (lr == 0) {
        #pragma unroll
        for (int j = 0; j < 8; ++j) red[wave][lc * 8 + j] = q[j];
    }
    __syncthreads();
    if (tid < 128) {
        int wc2 = tid >> 6, cl = tid & 63;
        atomicAdd(&stats[C1 + wc2 * 64 + cl], red[wc2][cl] + red[wc2 + 2][cl]);
    }
}

__global__ void k_ab(const float* __restrict__ stats, const float* __restrict__ gamma,
                     const float* __restrict__ beta, float* __restrict__ ab) {
    int t = threadIdx.x;
    if (t < C1) {
        float mu = stats[t] / (float)N_NODES;
        float var = stats[C1 + t] / (float)N_NODES - mu * mu;
        float inv = rsqrtf(var + BN_EPS);
        float a = gamma[t] * inv;
        ab[t] = a;
        ab[C1 + t] = beta[t] - mu * a;
    }
}

// ---------------- output: PReLU(BN(z)) @ w_out2 + b_out2 (streaming z) ----------------

__global__ __launch_bounds__(256) void k_out2(const float* __restrict__ z,
                                              const float* __restrict__ ab,
                                              const float* __restrict__ pa,
                                              const float* __restrict__ w2,
                                              const float* __restrict__ b2,
                                              float* __restrict__ out) {
    int lane = threadIdx.x & 63, wid = threadIdx.x >> 6;
    float w2a[NCLS], w2b[NCLS], bb[NCLS];
    #pragma unroll
    for (int j = 0; j < NCLS; ++j) {
        w2a[j] = w2[lane * NCLS + j];
        w2b[j] = w2[(64 + lane) * NCLS + j];
        bb[j] = b2[j];
    }
    float sa0 = ab[lane], sa1 = ab[64 + lane];
    float sb0 = ab[C1 + lane], sb1 = ab[C1 + 64 + lane];
    float alpha = pa[0];
    for (int v = blockIdx.x * 4 + wid; v < N_NODES; v += gridDim.x * 4) {
        float z0 = z[(size_t)v * C1 + lane];
        float z1 = z[(size_t)v * C1 + 64 + lane];
        float p0 = z0 * sa0 + sb0; p0 = (p0 > 0.f) ? p0 : alpha * p0;
        float p1 = z1 * sa1 + sb1; p1 = (p1 > 0.f) ? p1 : alpha * p1;
        float pj[NCLS];
        #pragma unroll
        for (int j = 0; j < NCLS; ++j) pj[j] = p0 * w2a[j] + p1 * w2b[j];
        #pragma unroll
        for (int j = 0; j < NCLS; ++j) {
            #pragma unroll
            for (int d = 32; d >= 1; d >>= 1) pj[j] += __shfl_xor(pj[j], d);
        }
        if (lane == 0) {
            #pragma unroll
            for (int j = 0; j < NCLS; ++j)
                out[(size_t)v * NCLS + j] = pj[j] + bb[j];
        }
    }
}

// ---------------- host ----------------

extern "C" void kernel_launch(void* const* d_in, const int* in_sizes, int n_in,
                              void* d_out, int out_size, void* d_ws, size_t ws_size,
                              hipStream_t stream) {
    const float* x      = (const float*)d_in[0];
    const float* e      = (const float*)d_in[1];
    const float* c      = (const float*)d_in[2];
    const float* w_node = (const float*)d_in[3];
    const float* b_node = (const float*)d_in[4];
    const float* w_edge = (const float*)d_in[5];
    const float* b_edge = (const float*)d_in[6];
    const float* w_out1 = (const float*)d_in[7];
    const float* b_out1 = (const float*)d_in[8];
    const float* gamma  = (const float*)d_in[9];
    const float* beta   = (const float*)d_in[10];
    const float* pa     = (const float*)d_in[11];
    const float* w_out2 = (const float*)d_in[12];
    const float* b_out2 = (const float*)d_in[13];
    const int*   ei     = (const int*)d_in[14];
    float* out = (float*)d_out;

    char* wsb = (char*)d_ws;
    size_t off = 0;
    auto alloc = [&](size_t bytes) {
        void* p = wsb + off;
        off = (off + bytes + 255) & ~(size_t)255;
        return p;
    };
    int*   cnt     = (int*)alloc(4ull * N_NODES);
    int*   offs    = (int*)alloc(4ull * (N_NODES + 1));
    float* dinv    = (float*)alloc(4ull * N_NODES);
    int*   bsum    = (int*)alloc(4ull * 128);
    int*   csr_src = (int*)alloc(4ull * N_EDGES);
    int*   csr_eid = (int*)alloc(4ull * N_EDGES);
    float* agg     = (float*)alloc(4ull * N_NODES * EDIM);
    float* wsumv   = (float*)alloc(4ull * N_NODES);
    float* se      = (float*)alloc(4ull * N_NODES * HID);
    float* h_a     = (float*)alloc(4ull * N_NODES * HID);   // h ping
    float* h_b     = (float*)alloc(4ull * N_NODES * HID);   // h pong (contiguous after h_a)
    float* h_sum   = (float*)alloc(4ull * N_NODES * HID);
    float* stats   = (float*)alloc(4ull * 256);
    float* ab      = (float*)alloc(4ull * 256);
    // z [N x 128] aliases h_a+h_b (both dead after layer 3; 2*25.6MB = 51.2MB exactly)
    float* z = h_a;

    hipMemsetAsync(cnt, 0, 4ull * N_NODES, stream);
    hipMemsetAsync(stats, 0, 4ull * 256, stream);

    k_count<<<(N_EDGES + 255) / 256, 256, 0, stream>>>(ei, cnt);
    k_scan1<<<SCAN_B, 1024, 0, stream>>>(cnt, offs, dinv, bsum);
    k_scan2<<<1, 1024, 0, stream>>>(bsum, SCAN_B);
    k_scan3<<<SCAN_B, 1024, 0, stream>>>(bsum, offs);
    hipMemsetAsync(cnt, 0, 4ull * N_NODES, stream);
    k_fill<<<(N_EDGES + 255) / 256, 256, 0, stream>>>(ei, offs, cnt, csr_src, csr_eid);

    k_h0t<<<HTILES, 256, 0, stream>>>(x, w_node, b_node, h_a, h_sum);
    k_agg<<<N_NODES / 4, 256, 0, stream>>>(e, csr_src, csr_eid, offs, dinv, agg, wsumv);
    k_se<<<1280, 256, 0, stream>>>(agg, wsumv, w_edge, b_edge, se);

    k_layer<<<N_NODES / 4, 256, 0, stream>>>(h_a, se, csr_src, offs, dinv, h_b, h_sum);
    k_layer<<<N_NODES / 4, 256, 0, stream>>>(h_b, se, csr_src, offs, dinv, h_a, h_sum);
    k_layer<<<N_NODES / 4, 256, 0, stream>>>(h_a, se, csr_src, offs, dinv, h_b, h_sum);

    k_zstats<<<512, 256, 0, stream>>>(h_sum, c, w_out1, b_out1, z, stats);
    k_ab<<<1, 128, 0, stream>>>(stats, gamma, beta, ab);
    k_out2<<<2048, 256, 0, stream>>>(z, ab, pa, w_out2, b_out2, out);
}

// Round 6
// 656.365 us; speedup vs baseline: 1.6098x; 1.1155x over previous
//
#include <hip/hip_runtime.h>
#include <math.h>

#define N_NODES 100000
#define N_EDGES 1000000
#define HID     64
#define HIER    32
#define NDIM    128
#define EDIM    32
#define K1      96    // HIER + HID
#define C1      128   // 2*HID
#define NCLS    10
#define BN_EPS  1e-5f
#define SCAN_B  98    // ceil(N_NODES/1024)
#define ZTILES  782   // ceil(N_NODES/128)
#define HTILES  391   // ceil(N_NODES/256)

// ---------------- CSR build ----------------

__global__ void k_count(const int* __restrict__ ei, int* __restrict__ cnt) {
    int i = blockIdx.x * blockDim.x + threadIdx.x;
    if (i < N_EDGES) atomicAdd(&cnt[ei[N_EDGES + i]], 1);
}

__global__ void k_scan1(const int* __restrict__ cnt, int* __restrict__ offs,
                        float* __restrict__ dinv, int* __restrict__ bsum) {
    __shared__ int buf[2][1024];
    int t = threadIdx.x, b = blockIdx.x;
    int i = b * 1024 + t;
    int v = (i < N_NODES) ? cnt[i] : 0;
    buf[0][t] = v; __syncthreads();
    int pi = 0;
    for (int off = 1; off < 1024; off <<= 1) {
        int x = buf[pi][t];
        if (t >= off) x += buf[pi][t - off];
        buf[pi ^ 1][t] = x; __syncthreads(); pi ^= 1;
    }
    int incl = buf[pi][t];
    if (i < N_NODES) {
        offs[i] = incl - v;
        dinv[i] = rsqrtf((float)(v + 1));
    }
    if (t == 1023) bsum[b] = incl;
}

__global__ void k_scan2(int* __restrict__ bsum, int nb) {
    __shared__ int buf[2][1024];
    int t = threadIdx.x;
    int v = (t < nb) ? bsum[t] : 0;
    buf[0][t] = v; __syncthreads();
    int pi = 0;
    for (int off = 1; off < 1024; off <<= 1) {
        int x = buf[pi][t];
        if (t >= off) x += buf[pi][t - off];
        buf[pi ^ 1][t] = x; __syncthreads(); pi ^= 1;
    }
    int incl = buf[pi][t];
    if (t < nb) bsum[t] = incl - v;
}

__global__ void k_scan3(const int* __restrict__ bsum, int* __restrict__ offs) {
    int b = blockIdx.x;
    int i = b * 1024 + threadIdx.x;
    if (i < N_NODES) offs[i] += bsum[b];
    if (i == 0) offs[N_NODES] = N_EDGES;
}

__global__ void k_fill(const int* __restrict__ ei, const int* __restrict__ offs,
                       int* __restrict__ cursor, const float* __restrict__ dinv,
                       int* __restrict__ csr_src, int* __restrict__ csr_eid,
                       float* __restrict__ csr_norm) {
    int i = blockIdx.x * blockDim.x + threadIdx.x;
    if (i >= N_EDGES) return;
    int s = ei[i], d = ei[N_EDGES + i];
    int pos = offs[d] + atomicAdd(&cursor[d], 1);
    csr_src[pos] = s;
    csr_eid[pos] = i;
    csr_norm[pos] = dinv[s];   // hoists the dinv[src] gather out of agg + 3 layers
}

// ---------------- node encoder (tiled GEMM): h0 = x @ w_node + b ----------------

__global__ __launch_bounds__(256) void k_h0t(const float* __restrict__ x,
                                             const float* __restrict__ w,
                                             const float* __restrict__ bias,
                                             float* __restrict__ h,
                                             float* __restrict__ hsum) {
    __shared__ float ws[NDIM * HID];   // 32 KB
    __shared__ float xt[256 * 33];     // 33.8 KB
    for (int i = threadIdx.x; i < NDIM * HID; i += 256) ws[i] = w[i];
    int tid = threadIdx.x;
    int lane = tid & 63, wave = tid >> 6;
    int lr = lane >> 3, lc = lane & 7;
    int rbase = wave * 64 + lr * 8;
    int cbase = lc * 8;
    float bA[8];
    #pragma unroll
    for (int j = 0; j < 8; ++j) bA[j] = bias[cbase + j];
    for (int tile = blockIdx.x; tile < HTILES; tile += gridDim.x) {
        int row0 = tile * 256;
        float acc[8][8];
        #pragma unroll
        for (int i = 0; i < 8; ++i)
            #pragma unroll
            for (int j = 0; j < 8; ++j) acc[i][j] = 0.f;
        for (int ch = 0; ch < 4; ++ch) {
            __syncthreads();
            #pragma unroll
            for (int p = 0; p < 8; ++p) {
                int idx = p * 256 + tid;
                int row = idx >> 3, kq = idx & 7;
                int gk = ch * 32 + kq * 4;
                float4 v = make_float4(0.f, 0.f, 0.f, 0.f);
                int gr = row0 + row;
                if (gr < N_NODES) v = *(const float4*)&x[(size_t)gr * NDIM + gk];
                float* d = &xt[row * 33 + kq * 4];
                d[0] = v.x; d[1] = v.y; d[2] = v.z; d[3] = v.w;
            }
            __syncthreads();
            for (int k = 0; k < 32; ++k) {
                float u[8];
                #pragma unroll
                for (int i = 0; i < 8; ++i) u[i] = xt[(rbase + i) * 33 + k];
                const float* wrow = &ws[(ch * 32 + k) * HID + cbase];
                float4 wa = *(const float4*)&wrow[0];
                float4 wb = *(const float4*)&wrow[4];
                #pragma unroll
                for (int i = 0; i < 8; ++i) {
                    acc[i][0] += u[i] * wa.x; acc[i][1] += u[i] * wa.y;
                    acc[i][2] += u[i] * wa.z; acc[i][3] += u[i] * wa.w;
                    acc[i][4] += u[i] * wb.x; acc[i][5] += u[i] * wb.y;
                    acc[i][6] += u[i] * wb.z; acc[i][7] += u[i] * wb.w;
                }
            }
        }
        #pragma unroll
        for (int i = 0; i < 8; ++i) {
            int gr = row0 + rbase + i;
            if (gr < N_NODES) {
                float4 lo = make_float4(acc[i][0] + bA[0], acc[i][1] + bA[1],
                                        acc[i][2] + bA[2], acc[i][3] + bA[3]);
                float4 hi = make_float4(acc[i][4] + bA[4], acc[i][5] + bA[5],
                                        acc[i][6] + bA[6], acc[i][7] + bA[7]);
                *(float4*)&h[(size_t)gr * HID + cbase] = lo;
                *(float4*)&h[(size_t)gr * HID + cbase + 4] = hi;
                *(float4*)&hsum[(size_t)gr * HID + cbase] = lo;
                *(float4*)&hsum[(size_t)gr * HID + cbase + 4] = hi;
            }
        }
    }
}

// ---------------- edge aggregation (4-way unrolled gathers) ----------------
// agg[v] = dinv[v] * sum_e norm_e * e_raw[e];  wsum[v] = dinv[v] * sum_e norm_e

__global__ __launch_bounds__(256) void k_agg(const float* __restrict__ e,
                                             const int* __restrict__ csr_eid,
                                             const float* __restrict__ csr_norm,
                                             const int* __restrict__ offs,
                                             const float* __restrict__ dinv,
                                             float* __restrict__ agg,
                                             float* __restrict__ wsumv) {
    int wid = threadIdx.x >> 6;
    int v = blockIdx.x * 4 + wid;
    if (v >= N_NODES) return;
    int lane = threadIdx.x & 63;
    int half = lane >> 5, dim = lane & 31;
    int start = offs[v], end = offs[v + 1];
    float dv = dinv[v];
    float acc = 0.f, wacc = 0.f;
    // each half-wave covers edges start+half, start+half+2, ...; unroll 4 deep
    for (int i = start + half; i < end; i += 8) {
        int i1 = i + 2, i2 = i + 4, i3 = i + 6;
        int e0 = csr_eid[i];
        int e1 = (i1 < end) ? csr_eid[i1] : 0;
        int e2 = (i2 < end) ? csr_eid[i2] : 0;
        int e3 = (i3 < end) ? csr_eid[i3] : 0;
        float n0 = csr_norm[i];
        float n1 = (i1 < end) ? csr_norm[i1] : 0.f;
        float n2 = (i2 < end) ? csr_norm[i2] : 0.f;
        float n3 = (i3 < end) ? csr_norm[i3] : 0.f;
        float v0 = e[(size_t)e0 * EDIM + dim];
        float v1 = e[(size_t)e1 * EDIM + dim];
        float v2 = e[(size_t)e2 * EDIM + dim];
        float v3 = e[(size_t)e3 * EDIM + dim];
        acc += n0 * v0 + n1 * v1 + n2 * v2 + n3 * v3;
        wacc += n0 + n1 + n2 + n3;
    }
    acc += __shfl_xor(acc, 32);
    wacc += __shfl_xor(wacc, 32);
    if (half == 0) agg[(size_t)v * EDIM + dim] = dv * acc;
    if (lane == 0) wsumv[v] = dv * wacc;
}

// ---------------- s_e = agg @ w_edge + wsum * b_edge ----------------

__global__ __launch_bounds__(256) void k_se(const float* __restrict__ agg,
                                            const float* __restrict__ wsumv,
                                            const float* __restrict__ we,
                                            const float* __restrict__ be,
                                            float* __restrict__ se) {
    int lane = threadIdx.x & 63, wid = threadIdx.x >> 6;
    float wreg[EDIM];
    #pragma unroll
    for (int k = 0; k < EDIM; ++k) wreg[k] = we[k * HID + lane];
    float bl = be[lane];
    for (int v = blockIdx.x * 4 + wid; v < N_NODES; v += gridDim.x * 4) {
        const float4* ar = (const float4*)(agg + (size_t)v * EDIM);
        float acc = wsumv[v] * bl;
        #pragma unroll
        for (int k4 = 0; k4 < EDIM / 4; ++k4) {
            float4 av = ar[k4];
            int k = k4 * 4;
            acc += av.x * wreg[k + 0] + av.y * wreg[k + 1] +
                   av.z * wreg[k + 2] + av.w * wreg[k + 3];
        }
        se[(size_t)v * HID + lane] = acc;
    }
}

// ---------------- one GCN layer (pull, 4-way unrolled gathers) ----------------

__global__ __launch_bounds__(256) void k_layer(const float* __restrict__ hold,
                                               const float* __restrict__ se,
                                               const int* __restrict__ csr_src,
                                               const float* __restrict__ csr_norm,
                                               const int* __restrict__ offs,
                                               const float* __restrict__ dinv,
                                               float* __restrict__ hnew,
                                               float* __restrict__ hsum) {
    int wid = threadIdx.x >> 6;
    int v = blockIdx.x * 4 + wid;
    if (v >= N_NODES) return;
    int lane = threadIdx.x & 63;
    int start = offs[v], end = offs[v + 1];
    float dv = dinv[v];
    size_t vi = (size_t)v * HID + lane;
    float aedge = dv * hold[vi];   // self loop contributes dv*(dv*h[v])
    for (int i = start; i < end; i += 4) {
        int i1 = i + 1, i2 = i + 2, i3 = i + 3;
        int s0 = csr_src[i];
        int s1 = (i1 < end) ? csr_src[i1] : 0;
        int s2 = (i2 < end) ? csr_src[i2] : 0;
        int s3 = (i3 < end) ? csr_src[i3] : 0;
        float n0 = csr_norm[i];
        float n1 = (i1 < end) ? csr_norm[i1] : 0.f;
        float n2 = (i2 < end) ? csr_norm[i2] : 0.f;
        float n3 = (i3 < end) ? csr_norm[i3] : 0.f;
        float h0 = hold[(size_t)s0 * HID + lane];
        float h1 = hold[(size_t)s1 * HID + lane];
        float h2 = hold[(size_t)s2 * HID + lane];
        float h3 = hold[(size_t)s3 * HID + lane];
        aedge += n0 * h0 + n1 * h1 + n2 * h2 + n3 * h3;
    }
    float acc = se[vi] + dv * aedge;
    float hv = (acc > 0.f) ? acc : 0.2f * acc;
    hnew[vi] = hv;
    hsum[vi] += hv;
}

// ---------------- z GEMM + BN stats ----------------

__global__ __launch_bounds__(256) void k_zstats(const float* __restrict__ hsum,
                                                const float* __restrict__ cfeat,
                                                const float* __restrict__ w1,
                                                const float* __restrict__ b1,
                                                float* __restrict__ z,
                                                float* __restrict__ stats) {
    __shared__ float ws[K1 * C1];    // 48 KB
    __shared__ float ut[128 * 49];   // 24.5 KB
    __shared__ float red[4][64];     // 1 KB
    for (int i = threadIdx.x; i < K1 * C1; i += 256) ws[i] = w1[i];
    int tid = threadIdx.x;
    int lane = tid & 63, wave = tid >> 6;
    int lr = lane >> 3, lc = lane & 7;
    int wr = wave >> 1, wc = wave & 1;
    int rbase = wr * 64 + lr * 8;
    int cbase = wc * 64 + lc * 8;
    float bA[8];
    #pragma unroll
    for (int j = 0; j < 8; ++j) bA[j] = b1[cbase + j];
    float s[8], q[8];
    #pragma unroll
    for (int j = 0; j < 8; ++j) { s[j] = 0.f; q[j] = 0.f; }

    for (int tile = blockIdx.x; tile < ZTILES; tile += gridDim.x) {
        int row0 = tile * 128;
        float acc[8][8];
        #pragma unroll
        for (int i = 0; i < 8; ++i)
            #pragma unroll
            for (int j = 0; j < 8; ++j) acc[i][j] = 0.f;
        for (int ch = 0; ch < 2; ++ch) {
            int kbase = ch * 48;
            __syncthreads();
            #pragma unroll
            for (int p = 0; p < 6; ++p) {
                int idx = p * 256 + tid;
                int row = idx / 12, kq = idx % 12;
                int gk = kbase + kq * 4;
                float4 v = make_float4(0.f, 0.f, 0.f, 0.f);
                int gr = row0 + row;
                if (gr < N_NODES) {
                    if (gk < HID) v = *(const float4*)&hsum[(size_t)gr * HID + gk];
                    else          v = *(const float4*)&cfeat[(size_t)gr * HIER + (gk - HID)];
                }
                float* d = &ut[row * 49 + kq * 4];
                d[0] = v.x; d[1] = v.y; d[2] = v.z; d[3] = v.w;
            }
            __syncthreads();
            for (int k = 0; k < 48; ++k) {
                float u[8];
                #pragma unroll
                for (int i = 0; i < 8; ++i) u[i] = ut[(rbase + i) * 49 + k];
                const float* wrow = &ws[(kbase + k) * C1 + cbase];
                float4 wa = *(const float4*)&wrow[0];
                float4 wb = *(const float4*)&wrow[4];
                #pragma unroll
                for (int i = 0; i < 8; ++i) {
                    acc[i][0] += u[i] * wa.x; acc[i][1] += u[i] * wa.y;
                    acc[i][2] += u[i] * wa.z; acc[i][3] += u[i] * wa.w;
                    acc[i][4] += u[i] * wb.x; acc[i][5] += u[i] * wb.y;
                    acc[i][6] += u[i] * wb.z; acc[i][7] += u[i] * wb.w;
                }
            }
        }
        #pragma unroll
        for (int i = 0; i < 8; ++i) {
            int gr = row0 + rbase + i;
            if (gr < N_NODES) {
                float zz[8];
                #pragma unroll
                for (int j = 0; j < 8; ++j) {
                    zz[j] = acc[i][j] + bA[j];
                    s[j] += zz[j]; q[j] += zz[j] * zz[j];
                }
                *(float4*)&z[(size_t)gr * C1 + cbase] =
                    make_float4(zz[0], zz[1], zz[2], zz[3]);
                *(float4*)&z[(size_t)gr * C1 + cbase + 4] =
                    make_float4(zz[4], zz[5], zz[6], zz[7]);
            }
        }
    }

    #pragma unroll
    for (int j = 0; j < 8; ++j) {
        s[j] += __shfl_xor(s[j], 8); s[j] += __shfl_xor(s[j], 16); s[j] += __shfl_xor(s[j], 32);
        q[j] += __shfl_xor(q[j], 8); q[j] += __shfl_xor(q[j], 16); q[j] += __shfl_xor(q[j], 32);
    }
    __syncthreads();
    if (lr == 0) {
        #pragma unroll
        for (int j = 0; j < 8; ++j) red[wave][lc * 8 + j] = s[j];
    }
    __syncthreads();
    if (tid < 128) {
        int wc2 = tid >> 6, cl = tid & 63;
        atomicAdd(&stats[wc2 * 64 + cl], red[wc2][cl] + red[wc2 + 2][cl]);
    }
    __syncthreads();
    if (lr == 0) {
        #pragma unroll
        for (int j = 0; j < 8; ++j) red[wave][lc * 8 + j] = q[j];
    }
    __syncthreads();
    if (tid < 128) {
        int wc2 = tid >> 6, cl = tid & 63;
        atomicAdd(&stats[C1 + wc2 * 64 + cl], red[wc2][cl] + red[wc2 + 2][cl]);
    }
}

__global__ void k_ab(const float* __restrict__ stats, const float* __restrict__ gamma,
                     const float* __restrict__ beta, float* __restrict__ ab) {
    int t = threadIdx.x;
    if (t < C1) {
        float mu = stats[t] / (float)N_NODES;
        float var = stats[C1 + t] / (float)N_NODES - mu * mu;
        float inv = rsqrtf(var + BN_EPS);
        float a = gamma[t] * inv;
        ab[t] = a;
        ab[C1 + t] = beta[t] - mu * a;
    }
}

// ---------------- output: PReLU(BN(z)) @ w_out2 + b_out2 (streaming z) ----------------

__global__ __launch_bounds__(256) void k_out2(const float* __restrict__ z,
                                              const float* __restrict__ ab,
                                              const float* __restrict__ pa,
                                              const float* __restrict__ w2,
                                              const float* __restrict__ b2,
                                              float* __restrict__ out) {
    int lane = threadIdx.x & 63, wid = threadIdx.x >> 6;
    float w2a[NCLS], w2b[NCLS], bb[NCLS];
    #pragma unroll
    for (int j = 0; j < NCLS; ++j) {
        w2a[j] = w2[lane * NCLS + j];
        w2b[j] = w2[(64 + lane) * NCLS + j];
        bb[j] = b2[j];
    }
    float sa0 = ab[lane], sa1 = ab[64 + lane];
    float sb0 = ab[C1 + lane], sb1 = ab[C1 + 64 + lane];
    float alpha = pa[0];
    for (int v = blockIdx.x * 4 + wid; v < N_NODES; v += gridDim.x * 4) {
        float z0 = z[(size_t)v * C1 + lane];
        float z1 = z[(size_t)v * C1 + 64 + lane];
        float p0 = z0 * sa0 + sb0; p0 = (p0 > 0.f) ? p0 : alpha * p0;
        float p1 = z1 * sa1 + sb1; p1 = (p1 > 0.f) ? p1 : alpha * p1;
        float pj[NCLS];
        #pragma unroll
        for (int j = 0; j < NCLS; ++j) pj[j] = p0 * w2a[j] + p1 * w2b[j];
        #pragma unroll
        for (int j = 0; j < NCLS; ++j) {
            #pragma unroll
            for (int d = 32; d >= 1; d >>= 1) pj[j] += __shfl_xor(pj[j], d);
        }
        if (lane == 0) {
            #pragma unroll
            for (int j = 0; j < NCLS; ++j)
                out[(size_t)v * NCLS + j] = pj[j] + bb[j];
        }
    }
}

// ---------------- host ----------------

extern "C" void kernel_launch(void* const* d_in, const int* in_sizes, int n_in,
                              void* d_out, int out_size, void* d_ws, size_t ws_size,
                              hipStream_t stream) {
    const float* x      = (const float*)d_in[0];
    const float* e      = (const float*)d_in[1];
    const float* c      = (const float*)d_in[2];
    const float* w_node = (const float*)d_in[3];
    const float* b_node = (const float*)d_in[4];
    const float* w_edge = (const float*)d_in[5];
    const float* b_edge = (const float*)d_in[6];
    const float* w_out1 = (const float*)d_in[7];
    const float* b_out1 = (const float*)d_in[8];
    const float* gamma  = (const float*)d_in[9];
    const float* beta   = (const float*)d_in[10];
    const float* pa     = (const float*)d_in[11];
    const float* w_out2 = (const float*)d_in[12];
    const float* b_out2 = (const float*)d_in[13];
    const int*   ei     = (const int*)d_in[14];
    float* out = (float*)d_out;

    char* wsb = (char*)d_ws;
    size_t off = 0;
    auto alloc = [&](size_t bytes) {
        void* p = wsb + off;
        off = (off + bytes + 255) & ~(size_t)255;
        return p;
    };
    int*   cnt      = (int*)alloc(4ull * N_NODES);
    int*   offs     = (int*)alloc(4ull * (N_NODES + 1));
    float* dinv     = (float*)alloc(4ull * N_NODES);
    int*   bsum     = (int*)alloc(4ull * 128);
    int*   csr_src  = (int*)alloc(4ull * N_EDGES);
    int*   csr_eid  = (int*)alloc(4ull * N_EDGES);
    float* csr_norm = (float*)alloc(4ull * N_EDGES);
    float* agg      = (float*)alloc(4ull * N_NODES * EDIM);
    float* wsumv    = (float*)alloc(4ull * N_NODES);
    float* se       = (float*)alloc(4ull * N_NODES * HID);
    float* h_a      = (float*)alloc(4ull * N_NODES * HID);   // h ping
    float* h_b      = (float*)alloc(4ull * N_NODES * HID);   // h pong (contiguous after h_a)
    float* h_sum    = (float*)alloc(4ull * N_NODES * HID);
    float* stats    = (float*)alloc(4ull * 256);
    float* ab       = (float*)alloc(4ull * 256);
    // z [N x 128] aliases h_a+h_b (both dead after layer 3; 2*25.6MB = 51.2MB exactly)
    float* z = h_a;

    hipMemsetAsync(cnt, 0, 4ull * N_NODES, stream);
    hipMemsetAsync(stats, 0, 4ull * 256, stream);

    k_count<<<(N_EDGES + 255) / 256, 256, 0, stream>>>(ei, cnt);
    k_scan1<<<SCAN_B, 1024, 0, stream>>>(cnt, offs, dinv, bsum);
    k_scan2<<<1, 1024, 0, stream>>>(bsum, SCAN_B);
    k_scan3<<<SCAN_B, 1024, 0, stream>>>(bsum, offs);
    hipMemsetAsync(cnt, 0, 4ull * N_NODES, stream);
    k_fill<<<(N_EDGES + 255) / 256, 256, 0, stream>>>(ei, offs, cnt, dinv,
                                                      csr_src, csr_eid, csr_norm);

    k_h0t<<<HTILES, 256, 0, stream>>>(x, w_node, b_node, h_a, h_sum);
    k_agg<<<N_NODES / 4, 256, 0, stream>>>(e, csr_eid, csr_norm, offs, dinv, agg, wsumv);
    k_se<<<1280, 256, 0, stream>>>(agg, wsumv, w_edge, b_edge, se);

    k_layer<<<N_NODES / 4, 256, 0, stream>>>(h_a, se, csr_src, csr_norm, offs, dinv, h_b, h_sum);
    k_layer<<<N_NODES / 4, 256, 0, stream>>>(h_b, se, csr_src, csr_norm, offs, dinv, h_a, h_sum);
    k_layer<<<N_NODES / 4, 256, 0, stream>>>(h_a, se, csr_src, csr_norm, offs, dinv, h_b, h_sum);

    k_zstats<<<512, 256, 0, stream>>>(h_sum, c, w_out1, b_out1, z, stats);
    k_ab<<<1, 128, 0, stream>>>(stats, gamma, beta, ab);
    k_out2<<<2048, 256, 0, stream>>>(z, ab, pa, w_out2, b_out2, out);
}

// Round 7
// 617.084 us; speedup vs baseline: 1.7123x; 1.0637x over previous
//
#include <hip/hip_runtime.h>
#include <math.h>

#define N_NODES 100000
#define N_EDGES 1000000
#define HID     64
#define HIER    32
#define NDIM    128
#define EDIM    32
#define K1      96    // HIER + HID
#define C1      128   // 2*HID
#define NCLS    10
#define BN_EPS  1e-5f
#define SCAN_B  98    // ceil(N_NODES/1024)
#define ZTILES  782   // ceil(N_NODES/128)
#define HTILES  391   // ceil(N_NODES/256)

// ---------------- CSR build ----------------

__global__ void k_count(const int* __restrict__ ei, int* __restrict__ cnt) {
    int i = blockIdx.x * blockDim.x + threadIdx.x;
    if (i < N_EDGES) atomicAdd(&cnt[ei[N_EDGES + i]], 1);
}

__global__ void k_scan1(const int* __restrict__ cnt, int* __restrict__ offs,
                        float* __restrict__ dinv, int* __restrict__ bsum) {
    __shared__ int buf[2][1024];
    int t = threadIdx.x, b = blockIdx.x;
    int i = b * 1024 + t;
    int v = (i < N_NODES) ? cnt[i] : 0;
    buf[0][t] = v; __syncthreads();
    int pi = 0;
    for (int off = 1; off < 1024; off <<= 1) {
        int x = buf[pi][t];
        if (t >= off) x += buf[pi][t - off];
        buf[pi ^ 1][t] = x; __syncthreads(); pi ^= 1;
    }
    int incl = buf[pi][t];
    if (i < N_NODES) {
        offs[i] = incl - v;
        dinv[i] = rsqrtf((float)(v + 1));
    }
    if (t == 1023) bsum[b] = incl;
}

__global__ void k_scan2(int* __restrict__ bsum, int nb) {
    __shared__ int buf[2][1024];
    int t = threadIdx.x;
    int v = (t < nb) ? bsum[t] : 0;
    buf[0][t] = v; __syncthreads();
    int pi = 0;
    for (int off = 1; off < 1024; off <<= 1) {
        int x = buf[pi][t];
        if (t >= off) x += buf[pi][t - off];
        buf[pi ^ 1][t] = x; __syncthreads(); pi ^= 1;
    }
    int incl = buf[pi][t];
    if (t < nb) bsum[t] = incl - v;
}

__global__ void k_scan3(const int* __restrict__ bsum, int* __restrict__ offs) {
    int b = blockIdx.x;
    int i = b * 1024 + threadIdx.x;
    if (i < N_NODES) offs[i] += bsum[b];
    if (i == 0) offs[N_NODES] = N_EDGES;
}

__global__ void k_fill(const int* __restrict__ ei, const int* __restrict__ offs,
                       int* __restrict__ cursor, const float* __restrict__ dinv,
                       int* __restrict__ csr_src, float* __restrict__ csr_norm,
                       int* __restrict__ ipos) {
    int i = blockIdx.x * blockDim.x + threadIdx.x;
    if (i >= N_EDGES) return;
    int s = ei[i], d = ei[N_EDGES + i];
    int pos = offs[d] + atomicAdd(&cursor[d], 1);
    csr_src[pos] = s;
    csr_norm[pos] = dinv[s];
    ipos[i] = pos;     // eid -> CSR slot, for the streaming permute
}

// ---------------- permute: ecsr[pos] = bf16(dinv[src] * e[eid]) ----------------
// Sequential READ of e (coalesced, full-burst HBM); scattered 64B WRITES
// (fire-and-forget, L2/L3-absorbed). Converts k_agg's random-HBM-read
// (DRAM-row-bound, ~910 GB/s) into streaming.

__global__ __launch_bounds__(256) void k_perm(const float* __restrict__ e,
                                              const int* __restrict__ ei,
                                              const int* __restrict__ ipos,
                                              const float* __restrict__ dinv,
                                              ushort* __restrict__ ecsr) {
    int gw = (blockIdx.x * 256 + threadIdx.x) >> 6;
    int lane = threadIdx.x & 63;
    int half = lane >> 5, d = lane & 31;
    int eid = gw * 2 + half;
    if (eid >= N_EDGES) return;
    int s = ei[eid];
    int pos = ipos[eid];
    float val = dinv[s] * e[(size_t)eid * EDIM + d];
    unsigned u = __float_as_uint(val);
    unsigned r = (u + 0x7FFFu + ((u >> 16) & 1u)) >> 16;   // RNE f32->bf16
    ecsr[(size_t)pos * EDIM + d] = (ushort)r;
}

// ---------------- segment sum over CSR-ordered scaled edge rows ----------------
// Pure sequential stream (half-wave per node, rows contiguous across nodes).

__global__ __launch_bounds__(256) void k_agg2(const ushort* __restrict__ ecsr,
                                              const float* __restrict__ csr_norm,
                                              const int* __restrict__ offs,
                                              const float* __restrict__ dinv,
                                              float* __restrict__ agg,
                                              float* __restrict__ wsumv) {
    int gw = (blockIdx.x * 256 + threadIdx.x) >> 6;
    int lane = threadIdx.x & 63;
    int half = lane >> 5, d = lane & 31;
    int v = gw * 2 + half;
    if (v >= N_NODES) return;
    int start = offs[v], end = offs[v + 1];
    float acc = 0.f, wacc = 0.f;
    for (int i = start; i < end; i += 4) {
        int i1 = i + 1, i2 = i + 2, i3 = i + 3;
        ushort u0 = ecsr[(size_t)i * EDIM + d];
        ushort u1 = (i1 < end) ? ecsr[(size_t)i1 * EDIM + d] : (ushort)0;
        ushort u2 = (i2 < end) ? ecsr[(size_t)i2 * EDIM + d] : (ushort)0;
        ushort u3 = (i3 < end) ? ecsr[(size_t)i3 * EDIM + d] : (ushort)0;
        float n0 = csr_norm[i];
        float n1 = (i1 < end) ? csr_norm[i1] : 0.f;
        float n2 = (i2 < end) ? csr_norm[i2] : 0.f;
        float n3 = (i3 < end) ? csr_norm[i3] : 0.f;
        acc += __uint_as_float((unsigned)u0 << 16) + __uint_as_float((unsigned)u1 << 16)
             + __uint_as_float((unsigned)u2 << 16) + __uint_as_float((unsigned)u3 << 16);
        wacc += n0 + n1 + n2 + n3;
    }
    float dv = dinv[v];
    agg[(size_t)v * EDIM + d] = dv * acc;
    if (d == 0) wsumv[v] = dv * wacc;
}

// ---------------- node encoder (tiled GEMM): h0 = x @ w_node + b ----------------

__global__ __launch_bounds__(256) void k_h0t(const float* __restrict__ x,
                                             const float* __restrict__ w,
                                             const float* __restrict__ bias,
                                             float* __restrict__ h,
                                             float* __restrict__ hsum) {
    __shared__ float ws[NDIM * HID];   // 32 KB
    __shared__ float xt[256 * 33];     // 33.8 KB
    for (int i = threadIdx.x; i < NDIM * HID; i += 256) ws[i] = w[i];
    int tid = threadIdx.x;
    int lane = tid & 63, wave = tid >> 6;
    int lr = lane >> 3, lc = lane & 7;
    int rbase = wave * 64 + lr * 8;
    int cbase = lc * 8;
    float bA[8];
    #pragma unroll
    for (int j = 0; j < 8; ++j) bA[j] = bias[cbase + j];
    for (int tile = blockIdx.x; tile < HTILES; tile += gridDim.x) {
        int row0 = tile * 256;
        float acc[8][8];
        #pragma unroll
        for (int i = 0; i < 8; ++i)
            #pragma unroll
            for (int j = 0; j < 8; ++j) acc[i][j] = 0.f;
        for (int ch = 0; ch < 4; ++ch) {
            __syncthreads();
            #pragma unroll
            for (int p = 0; p < 8; ++p) {
                int idx = p * 256 + tid;
                int row = idx >> 3, kq = idx & 7;
                int gk = ch * 32 + kq * 4;
                float4 v = make_float4(0.f, 0.f, 0.f, 0.f);
                int gr = row0 + row;
                if (gr < N_NODES) v = *(const float4*)&x[(size_t)gr * NDIM + gk];
                float* d = &xt[row * 33 + kq * 4];
                d[0] = v.x; d[1] = v.y; d[2] = v.z; d[3] = v.w;
            }
            __syncthreads();
            for (int k = 0; k < 32; ++k) {
                float u[8];
                #pragma unroll
                for (int i = 0; i < 8; ++i) u[i] = xt[(rbase + i) * 33 + k];
                const float* wrow = &ws[(ch * 32 + k) * HID + cbase];
                float4 wa = *(const float4*)&wrow[0];
                float4 wb = *(const float4*)&wrow[4];
                #pragma unroll
                for (int i = 0; i < 8; ++i) {
                    acc[i][0] += u[i] * wa.x; acc[i][1] += u[i] * wa.y;
                    acc[i][2] += u[i] * wa.z; acc[i][3] += u[i] * wa.w;
                    acc[i][4] += u[i] * wb.x; acc[i][5] += u[i] * wb.y;
                    acc[i][6] += u[i] * wb.z; acc[i][7] += u[i] * wb.w;
                }
            }
        }
        #pragma unroll
        for (int i = 0; i < 8; ++i) {
            int gr = row0 + rbase + i;
            if (gr < N_NODES) {
                float4 lo = make_float4(acc[i][0] + bA[0], acc[i][1] + bA[1],
                                        acc[i][2] + bA[2], acc[i][3] + bA[3]);
                float4 hi = make_float4(acc[i][4] + bA[4], acc[i][5] + bA[5],
                                        acc[i][6] + bA[6], acc[i][7] + bA[7]);
                *(float4*)&h[(size_t)gr * HID + cbase] = lo;
                *(float4*)&h[(size_t)gr * HID + cbase + 4] = hi;
                *(float4*)&hsum[(size_t)gr * HID + cbase] = lo;
                *(float4*)&hsum[(size_t)gr * HID + cbase + 4] = hi;
            }
        }
    }
}

// ---------------- s_e = agg @ w_edge + wsum * b_edge ----------------

__global__ __launch_bounds__(256) void k_se(const float* __restrict__ agg,
                                            const float* __restrict__ wsumv,
                                            const float* __restrict__ we,
                                            const float* __restrict__ be,
                                            float* __restrict__ se) {
    int lane = threadIdx.x & 63, wid = threadIdx.x >> 6;
    float wreg[EDIM];
    #pragma unroll
    for (int k = 0; k < EDIM; ++k) wreg[k] = we[k * HID + lane];
    float bl = be[lane];
    for (int v = blockIdx.x * 4 + wid; v < N_NODES; v += gridDim.x * 4) {
        const float4* ar = (const float4*)(agg + (size_t)v * EDIM);
        float acc = wsumv[v] * bl;
        #pragma unroll
        for (int k4 = 0; k4 < EDIM / 4; ++k4) {
            float4 av = ar[k4];
            int k = k4 * 4;
            acc += av.x * wreg[k + 0] + av.y * wreg[k + 1] +
                   av.z * wreg[k + 2] + av.w * wreg[k + 3];
        }
        se[(size_t)v * HID + lane] = acc;
    }
}

// ---------------- one GCN layer (pull; half-wave per node, float2 lanes) ----------------
// 2 nodes/wave x unroll-4 = 8 independent 256B h-row gathers in flight.

__global__ __launch_bounds__(256) void k_layer(const float* __restrict__ hold,
                                               const float* __restrict__ se,
                                               const int* __restrict__ csr_src,
                                               const float* __restrict__ csr_norm,
                                               const int* __restrict__ offs,
                                               const float* __restrict__ dinv,
                                               float* __restrict__ hnew,
                                               float* __restrict__ hsum) {
    int gw = (blockIdx.x * 256 + threadIdx.x) >> 6;
    int lane = threadIdx.x & 63;
    int half = lane >> 5, d2 = (lane & 31) * 2;
    int v = gw * 2 + half;
    if (v >= N_NODES) return;
    int start = offs[v], end = offs[v + 1];
    float dv = dinv[v];
    size_t vi = (size_t)v * HID + d2;
    float2 hv = *(const float2*)&hold[vi];
    float a0 = dv * hv.x, a1 = dv * hv.y;      // self loop (x dv again below)
    for (int i = start; i < end; i += 4) {
        int i1 = i + 1, i2 = i + 2, i3 = i + 3;
        int s0 = csr_src[i];
        int s1 = (i1 < end) ? csr_src[i1] : 0;
        int s2 = (i2 < end) ? csr_src[i2] : 0;
        int s3 = (i3 < end) ? csr_src[i3] : 0;
        float n0 = csr_norm[i];
        float n1 = (i1 < end) ? csr_norm[i1] : 0.f;
        float n2 = (i2 < end) ? csr_norm[i2] : 0.f;
        float n3 = (i3 < end) ? csr_norm[i3] : 0.f;
        float2 g0 = *(const float2*)&hold[(size_t)s0 * HID + d2];
        float2 g1 = *(const float2*)&hold[(size_t)s1 * HID + d2];
        float2 g2 = *(const float2*)&hold[(size_t)s2 * HID + d2];
        float2 g3 = *(const float2*)&hold[(size_t)s3 * HID + d2];
        a0 += n0 * g0.x + n1 * g1.x + n2 * g2.x + n3 * g3.x;
        a1 += n0 * g0.y + n1 * g1.y + n2 * g2.y + n3 * g3.y;
    }
    float2 sv = *(const float2*)&se[vi];
    float r0 = sv.x + dv * a0;
    float r1 = sv.y + dv * a1;
    r0 = (r0 > 0.f) ? r0 : 0.2f * r0;
    r1 = (r1 > 0.f) ? r1 : 0.2f * r1;
    *(float2*)&hnew[vi] = make_float2(r0, r1);
    float2 hs = *(const float2*)&hsum[vi];
    *(float2*)&hsum[vi] = make_float2(hs.x + r0, hs.y + r1);
}

// ---------------- z GEMM + BN stats ----------------

__global__ __launch_bounds__(256) void k_zstats(const float* __restrict__ hsum,
                                                const float* __restrict__ cfeat,
                                                const float* __restrict__ w1,
                                                const float* __restrict__ b1,
                                                float* __restrict__ z,
                                                float* __restrict__ stats) {
    __shared__ float ws[K1 * C1];    // 48 KB
    __shared__ float ut[128 * 49];   // 24.5 KB
    __shared__ float red[4][64];     // 1 KB
    for (int i = threadIdx.x; i < K1 * C1; i += 256) ws[i] = w1[i];
    int tid = threadIdx.x;
    int lane = tid & 63, wave = tid >> 6;
    int lr = lane >> 3, lc = lane & 7;
    int wr = wave >> 1, wc = wave & 1;
    int rbase = wr * 64 + lr * 8;
    int cbase = wc * 64 + lc * 8;
    float bA[8];
    #pragma unroll
    for (int j = 0; j < 8; ++j) bA[j] = b1[cbase + j];
    float s[8], q[8];
    #pragma unroll
    for (int j = 0; j < 8; ++j) { s[j] = 0.f; q[j] = 0.f; }

    for (int tile = blockIdx.x; tile < ZTILES; tile += gridDim.x) {
        int row0 = tile * 128;
        float acc[8][8];
        #pragma unroll
        for (int i = 0; i < 8; ++i)
            #pragma unroll
            for (int j = 0; j < 8; ++j) acc[i][j] = 0.f;
        for (int ch = 0; ch < 2; ++ch) {
            int kbase = ch * 48;
            __syncthreads();
            #pragma unroll
            for (int p = 0; p < 6; ++p) {
                int idx = p * 256 + tid;
                int row = idx / 12, kq = idx % 12;
                int gk = kbase + kq * 4;
                float4 v = make_float4(0.f, 0.f, 0.f, 0.f);
                int gr = row0 + row;
                if (gr < N_NODES) {
                    if (gk < HID) v = *(const float4*)&hsum[(size_t)gr * HID + gk];
                    else          v = *(const float4*)&cfeat[(size_t)gr * HIER + (gk - HID)];
                }
                float* d = &ut[row * 49 + kq * 4];
                d[0] = v.x; d[1] = v.y; d[2] = v.z; d[3] = v.w;
            }
            __syncthreads();
            for (int k = 0; k < 48; ++k) {
                float u[8];
                #pragma unroll
                for (int i = 0; i < 8; ++i) u[i] = ut[(rbase + i) * 49 + k];
                const float* wrow = &ws[(kbase + k) * C1 + cbase];
                float4 wa = *(const float4*)&wrow[0];
                float4 wb = *(const float4*)&wrow[4];
                #pragma unroll
                for (int i = 0; i < 8; ++i) {
                    acc[i][0] += u[i] * wa.x; acc[i][1] += u[i] * wa.y;
                    acc[i][2] += u[i] * wa.z; acc[i][3] += u[i] * wa.w;
                    acc[i][4] += u[i] * wb.x; acc[i][5] += u[i] * wb.y;
                    acc[i][6] += u[i] * wb.z; acc[i][7] += u[i] * wb.w;
                }
            }
        }
        #pragma unroll
        for (int i = 0; i < 8; ++i) {
            int gr = row0 + rbase + i;
            if (gr < N_NODES) {
                float zz[8];
                #pragma unroll
                for (int j = 0; j < 8; ++j) {
                    zz[j] = acc[i][j] + bA[j];
                    s[j] += zz[j]; q[j] += zz[j] * zz[j];
                }
                *(float4*)&z[(size_t)gr * C1 + cbase] =
                    make_float4(zz[0], zz[1], zz[2], zz[3]);
                *(float4*)&z[(size_t)gr * C1 + cbase + 4] =
                    make_float4(zz[4], zz[5], zz[6], zz[7]);
            }
        }
    }

    #pragma unroll
    for (int j = 0; j < 8; ++j) {
        s[j] += __shfl_xor(s[j], 8); s[j] += __shfl_xor(s[j], 16); s[j] += __shfl_xor(s[j], 32);
        q[j] += __shfl_xor(q[j], 8); q[j] += __shfl_xor(q[j], 16); q[j] += __shfl_xor(q[j], 32);
    }
    __syncthreads();
    if (lr == 0) {
        #pragma unroll
        for (int j = 0; j < 8; ++j) red[wave][lc * 8 + j] = s[j];
    }
    __syncthreads();
    if (tid < 128) {
        int wc2 = tid >> 6, cl = tid & 63;
        atomicAdd(&stats[wc2 * 64 + cl], red[wc2][cl] + red[wc2 + 2][cl]);
    }
    __syncthreads();
    if (lr == 0) {
        #pragma unroll
        for (int j = 0; j < 8; ++j) red[wave][lc * 8 + j] = q[j];
    }
    __syncthreads();
    if (tid < 128) {
        int wc2 = tid >> 6, cl = tid & 63;
        atomicAdd(&stats[C1 + wc2 * 64 + cl], red[wc2][cl] + red[wc2 + 2][cl]);
    }
}

__global__ void k_ab(const float* __restrict__ stats, const float* __restrict__ gamma,
                     const float* __restrict__ beta, float* __restrict__ ab) {
    int t = threadIdx.x;
    if (t < C1) {
        float mu = stats[t] / (float)N_NODES;
        float var = stats[C1 + t] / (float)N_NODES - mu * mu;
        float inv = rsqrtf(var + BN_EPS);
        float a = gamma[t] * inv;
        ab[t] = a;
        ab[C1 + t] = beta[t] - mu * a;
    }
}

// ---------------- output: PReLU(BN(z)) @ w_out2 + b_out2 (streaming z) ----------------

__global__ __launch_bounds__(256) void k_out2(const float* __restrict__ z,
                                              const float* __restrict__ ab,
                                              const float* __restrict__ pa,
                                              const float* __restrict__ w2,
                                              const float* __restrict__ b2,
                                              float* __restrict__ out) {
    int lane = threadIdx.x & 63, wid = threadIdx.x >> 6;
    float w2a[NCLS], w2b[NCLS], bb[NCLS];
    #pragma unroll
    for (int j = 0; j < NCLS; ++j) {
        w2a[j] = w2[lane * NCLS + j];
        w2b[j] = w2[(64 + lane) * NCLS + j];
        bb[j] = b2[j];
    }
    float sa0 = ab[lane], sa1 = ab[64 + lane];
    float sb0 = ab[C1 + lane], sb1 = ab[C1 + 64 + lane];
    float alpha = pa[0];
    for (int v = blockIdx.x * 4 + wid; v < N_NODES; v += gridDim.x * 4) {
        float z0 = z[(size_t)v * C1 + lane];
        float z1 = z[(size_t)v * C1 + 64 + lane];
        float p0 = z0 * sa0 + sb0; p0 = (p0 > 0.f) ? p0 : alpha * p0;
        float p1 = z1 * sa1 + sb1; p1 = (p1 > 0.f) ? p1 : alpha * p1;
        float pj[NCLS];
        #pragma unroll
        for (int j = 0; j < NCLS; ++j) pj[j] = p0 * w2a[j] + p1 * w2b[j];
        #pragma unroll
        for (int j = 0; j < NCLS; ++j) {
            #pragma unroll
            for (int d = 32; d >= 1; d >>= 1) pj[j] += __shfl_xor(pj[j], d);
        }
        if (lane == 0) {
            #pragma unroll
            for (int j = 0; j < NCLS; ++j)
                out[(size_t)v * NCLS + j] = pj[j] + bb[j];
        }
    }
}

// ---------------- host ----------------

extern "C" void kernel_launch(void* const* d_in, const int* in_sizes, int n_in,
                              void* d_out, int out_size, void* d_ws, size_t ws_size,
                              hipStream_t stream) {
    const float* x      = (const float*)d_in[0];
    const float* e      = (const float*)d_in[1];
    const float* c      = (const float*)d_in[2];
    const float* w_node = (const float*)d_in[3];
    const float* b_node = (const float*)d_in[4];
    const float* w_edge = (const float*)d_in[5];
    const float* b_edge = (const float*)d_in[6];
    const float* w_out1 = (const float*)d_in[7];
    const float* b_out1 = (const float*)d_in[8];
    const float* gamma  = (const float*)d_in[9];
    const float* beta   = (const float*)d_in[10];
    const float* pa     = (const float*)d_in[11];
    const float* w_out2 = (const float*)d_in[12];
    const float* b_out2 = (const float*)d_in[13];
    const int*   ei     = (const int*)d_in[14];
    float* out = (float*)d_out;

    char* wsb = (char*)d_ws;
    // Region A (64 MB): ecsr [bf16 1M x 32]; dead after k_agg2, then reused as
    //   se (25.6 MB) + h_a (25.6 MB); later z (51.2 MB) overlays se+h_a.
    ushort* ecsr = (ushort*)wsb;
    float*  se   = (float*)wsb;
    float*  h_a  = (float*)(wsb + 25600000);
    float*  z    = (float*)wsb;              // [N x 128] over se+h_a (dead at zstats)
    size_t off = (64000000 + 255) & ~(size_t)255;
    auto alloc = [&](size_t bytes) {
        void* p = wsb + off;
        off = (off + bytes + 255) & ~(size_t)255;
        return p;
    };
    // Region B: small persistent arrays
    int*   cnt      = (int*)alloc(4ull * N_NODES);
    int*   offs     = (int*)alloc(4ull * (N_NODES + 1));
    float* dinv     = (float*)alloc(4ull * N_NODES);
    int*   bsum     = (int*)alloc(4ull * 128);
    int*   csr_src  = (int*)alloc(4ull * N_EDGES);
    float* csr_norm = (float*)alloc(4ull * N_EDGES);
    int*   ipos     = (int*)alloc(4ull * N_EDGES);
    float* agg      = (float*)alloc(4ull * N_NODES * EDIM);
    float* wsumv    = (float*)alloc(4ull * N_NODES);
    float* stats    = (float*)alloc(4ull * 256);
    float* ab       = (float*)alloc(4ull * 256);
    // Region C: h ping-pong partner + running sum
    float* h_b      = (float*)alloc(4ull * N_NODES * HID);
    float* h_sum    = (float*)alloc(4ull * N_NODES * HID);

    hipMemsetAsync(cnt, 0, 4ull * N_NODES, stream);
    hipMemsetAsync(stats, 0, 4ull * 256, stream);

    k_count<<<(N_EDGES + 255) / 256, 256, 0, stream>>>(ei, cnt);
    k_scan1<<<SCAN_B, 1024, 0, stream>>>(cnt, offs, dinv, bsum);
    k_scan2<<<1, 1024, 0, stream>>>(bsum, SCAN_B);
    k_scan3<<<SCAN_B, 1024, 0, stream>>>(bsum, offs);
    hipMemsetAsync(cnt, 0, 4ull * N_NODES, stream);
    k_fill<<<(N_EDGES + 255) / 256, 256, 0, stream>>>(ei, offs, cnt, dinv,
                                                      csr_src, csr_norm, ipos);

    // streaming permute (e -> CSR order, scaled, bf16), then streaming segment sum
    k_perm<<<N_EDGES / 8, 256, 0, stream>>>(e, ei, ipos, dinv, ecsr);
    k_agg2<<<N_NODES / 8, 256, 0, stream>>>(ecsr, csr_norm, offs, dinv, agg, wsumv);

    k_se<<<1280, 256, 0, stream>>>(agg, wsumv, w_edge, b_edge, se);     // se over dead ecsr
    k_h0t<<<HTILES, 256, 0, stream>>>(x, w_node, b_node, h_a, h_sum);   // h_a over dead ecsr

    k_layer<<<N_NODES / 8, 256, 0, stream>>>(h_a, se, csr_src, csr_norm, offs, dinv, h_b, h_sum);
    k_layer<<<N_NODES / 8, 256, 0, stream>>>(h_b, se, csr_src, csr_norm, offs, dinv, h_a, h_sum);
    k_layer<<<N_NODES / 8, 256, 0, stream>>>(h_a, se, csr_src, csr_norm, offs, dinv, h_b, h_sum);

    k_zstats<<<512, 256, 0, stream>>>(h_sum, c, w_out1, b_out1, z, stats);
    k_ab<<<1, 128, 0, stream>>>(stats, gamma, beta, ab);
    k_out2<<<2048, 256, 0, stream>>>(z, ab, pa, w_out2, b_out2, out);
}

// Round 8
// 590.800 us; speedup vs baseline: 1.7885x; 1.0445x over previous
//
#include <hip/hip_runtime.h>
#include <math.h>

#define N_NODES 100000
#define N_EDGES 1000000
#define HID     64
#define HIER    32
#define NDIM    128
#define EDIM    32
#define K1      96    // HIER + HID
#define C1      128   // 2*HID
#define NCLS    10
#define BN_EPS  1e-5f
#define SCAN_B  98    // ceil(N_NODES/1024)
#define ZTILES  782   // ceil(N_NODES/128)
#define HTILES  391   // ceil(N_NODES/256)

// round-to-nearest-even f32 -> bf16 (as ushort in low 16)
__device__ __forceinline__ unsigned rnd_bf16(float a) {
    unsigned u = __float_as_uint(a);
    return (u + 0x7FFFu + ((u >> 16) & 1u)) >> 16;
}
// pack two f32 -> (bf16(a) | bf16(b)<<16)
__device__ __forceinline__ unsigned pk_bf16(float a, float b) {
    unsigned ua = __float_as_uint(a);
    ua = (ua + 0x7FFFu + ((ua >> 16) & 1u)) >> 16;
    unsigned ub = __float_as_uint(b);
    ub = (ub + 0x7FFFu + ((ub >> 16) & 1u)) & 0xFFFF0000u;
    return ua | ub;
}
__device__ __forceinline__ float bf_lo(unsigned g) { return __uint_as_float(g << 16); }
__device__ __forceinline__ float bf_hi(unsigned g) { return __uint_as_float(g & 0xFFFF0000u); }

// ---------------- CSR build ----------------

__global__ void k_count(const int* __restrict__ ei, int* __restrict__ cnt) {
    int i = blockIdx.x * blockDim.x + threadIdx.x;
    if (i < N_EDGES) atomicAdd(&cnt[ei[N_EDGES + i]], 1);
}

__global__ void k_scan1(const int* __restrict__ cnt, int* __restrict__ offs,
                        float* __restrict__ dinv, int* __restrict__ bsum) {
    __shared__ int buf[2][1024];
    int t = threadIdx.x, b = blockIdx.x;
    int i = b * 1024 + t;
    int v = (i < N_NODES) ? cnt[i] : 0;
    buf[0][t] = v; __syncthreads();
    int pi = 0;
    for (int off = 1; off < 1024; off <<= 1) {
        int x = buf[pi][t];
        if (t >= off) x += buf[pi][t - off];
        buf[pi ^ 1][t] = x; __syncthreads(); pi ^= 1;
    }
    int incl = buf[pi][t];
    if (i < N_NODES) {
        offs[i] = incl - v;
        dinv[i] = rsqrtf((float)(v + 1));
    }
    if (t == 1023) bsum[b] = incl;
}

__global__ void k_scan2(int* __restrict__ bsum, int nb) {
    __shared__ int buf[2][1024];
    int t = threadIdx.x;
    int v = (t < nb) ? bsum[t] : 0;
    buf[0][t] = v; __syncthreads();
    int pi = 0;
    for (int off = 1; off < 1024; off <<= 1) {
        int x = buf[pi][t];
        if (t >= off) x += buf[pi][t - off];
        buf[pi ^ 1][t] = x; __syncthreads(); pi ^= 1;
    }
    int incl = buf[pi][t];
    if (t < nb) bsum[t] = incl - v;
}

__global__ void k_scan3(const int* __restrict__ bsum, int* __restrict__ offs) {
    int b = blockIdx.x;
    int i = b * 1024 + threadIdx.x;
    if (i < N_NODES) offs[i] += bsum[b];
    if (i == 0) offs[N_NODES] = N_EDGES;
}

__global__ void k_fill(const int* __restrict__ ei, const int* __restrict__ offs,
                       int* __restrict__ cursor, const float* __restrict__ dinv,
                       int* __restrict__ csr_src, int* __restrict__ csr_eid,
                       float* __restrict__ csr_norm) {
    int i = blockIdx.x * blockDim.x + threadIdx.x;
    if (i >= N_EDGES) return;
    int s = ei[i], d = ei[N_EDGES + i];
    int pos = offs[d] + atomicAdd(&cursor[d], 1);
    csr_src[pos] = s;
    csr_eid[pos] = i;
    csr_norm[pos] = dinv[s];
}

// ---------------- sequential convert: ebf[eid] = bf16(dinv[src]*e[eid]) ----------------
// Pure streaming both sides (eid order). No scattered writes anywhere.

__global__ __launch_bounds__(256) void k_conv(const float* __restrict__ e,
                                              const int* __restrict__ ei,
                                              const float* __restrict__ dinv,
                                              ushort* __restrict__ ebf) {
    int gw = (blockIdx.x * 256 + threadIdx.x) >> 6;
    int lane = threadIdx.x & 63;
    int half = lane >> 5, d = lane & 31;
    int eid = gw * 2 + half;
    if (eid >= N_EDGES) return;
    int s = ei[eid];
    float val = dinv[s] * e[(size_t)eid * EDIM + d];
    ebf[(size_t)eid * EDIM + d] = (ushort)rnd_bf16(val);
}

// ---------------- edge aggregation: gather 64B bf16 rows from L3-resident ebf ----------------
// agg[v] = dinv[v] * sum ebf[eid] (norm baked in); wsum[v] = dinv[v] * sum norm.

__global__ __launch_bounds__(256) void k_agg3(const ushort* __restrict__ ebf,
                                              const int* __restrict__ csr_eid,
                                              const float* __restrict__ csr_norm,
                                              const int* __restrict__ offs,
                                              const float* __restrict__ dinv,
                                              float* __restrict__ agg,
                                              float* __restrict__ wsumv) {
    int gw = (blockIdx.x * 256 + threadIdx.x) >> 6;
    int lane = threadIdx.x & 63;
    int half = lane >> 5, d = lane & 31;
    int v = gw * 2 + half;
    if (v >= N_NODES) return;
    int start = offs[v], end = offs[v + 1];
    float acc = 0.f, wacc = 0.f;
    for (int i = start; i < end; i += 4) {
        int i1 = i + 1, i2 = i + 2, i3 = i + 3;
        int e0 = csr_eid[i];
        int e1 = (i1 < end) ? csr_eid[i1] : 0;
        int e2 = (i2 < end) ? csr_eid[i2] : 0;
        int e3 = (i3 < end) ? csr_eid[i3] : 0;
        ushort u0 = ebf[(size_t)e0 * EDIM + d];
        ushort u1 = (i1 < end) ? ebf[(size_t)e1 * EDIM + d] : (ushort)0;
        ushort u2 = (i2 < end) ? ebf[(size_t)e2 * EDIM + d] : (ushort)0;
        ushort u3 = (i3 < end) ? ebf[(size_t)e3 * EDIM + d] : (ushort)0;
        float n0 = csr_norm[i];
        float n1 = (i1 < end) ? csr_norm[i1] : 0.f;
        float n2 = (i2 < end) ? csr_norm[i2] : 0.f;
        float n3 = (i3 < end) ? csr_norm[i3] : 0.f;
        acc += __uint_as_float((unsigned)u0 << 16) + __uint_as_float((unsigned)u1 << 16)
             + __uint_as_float((unsigned)u2 << 16) + __uint_as_float((unsigned)u3 << 16);
        wacc += n0 + n1 + n2 + n3;
    }
    float dv = dinv[v];
    agg[(size_t)v * EDIM + d] = dv * acc;
    if (d == 0) wsumv[v] = dv * wacc;
}

// ---------------- node encoder (tiled GEMM): h0 = x @ w_node + b ----------------
// Writes packed-bf16 h (for layer gathers) + f32 hsum.

__global__ __launch_bounds__(256) void k_h0t(const float* __restrict__ x,
                                             const float* __restrict__ w,
                                             const float* __restrict__ bias,
                                             unsigned* __restrict__ hbf,
                                             float* __restrict__ hsum) {
    __shared__ float ws[NDIM * HID];   // 32 KB
    __shared__ float xt[256 * 33];     // 33.8 KB
    for (int i = threadIdx.x; i < NDIM * HID; i += 256) ws[i] = w[i];
    int tid = threadIdx.x;
    int lane = tid & 63, wave = tid >> 6;
    int lr = lane >> 3, lc = lane & 7;
    int rbase = wave * 64 + lr * 8;
    int cbase = lc * 8;
    float bA[8];
    #pragma unroll
    for (int j = 0; j < 8; ++j) bA[j] = bias[cbase + j];
    for (int tile = blockIdx.x; tile < HTILES; tile += gridDim.x) {
        int row0 = tile * 256;
        float acc[8][8];
        #pragma unroll
        for (int i = 0; i < 8; ++i)
            #pragma unroll
            for (int j = 0; j < 8; ++j) acc[i][j] = 0.f;
        for (int ch = 0; ch < 4; ++ch) {
            __syncthreads();
            #pragma unroll
            for (int p = 0; p < 8; ++p) {
                int idx = p * 256 + tid;
                int row = idx >> 3, kq = idx & 7;
                int gk = ch * 32 + kq * 4;
                float4 v = make_float4(0.f, 0.f, 0.f, 0.f);
                int gr = row0 + row;
                if (gr < N_NODES) v = *(const float4*)&x[(size_t)gr * NDIM + gk];
                float* d = &xt[row * 33 + kq * 4];
                d[0] = v.x; d[1] = v.y; d[2] = v.z; d[3] = v.w;
            }
            __syncthreads();
            for (int k = 0; k < 32; ++k) {
                float u[8];
                #pragma unroll
                for (int i = 0; i < 8; ++i) u[i] = xt[(rbase + i) * 33 + k];
                const float* wrow = &ws[(ch * 32 + k) * HID + cbase];
                float4 wa = *(const float4*)&wrow[0];
                float4 wb = *(const float4*)&wrow[4];
                #pragma unroll
                for (int i = 0; i < 8; ++i) {
                    acc[i][0] += u[i] * wa.x; acc[i][1] += u[i] * wa.y;
                    acc[i][2] += u[i] * wa.z; acc[i][3] += u[i] * wa.w;
                    acc[i][4] += u[i] * wb.x; acc[i][5] += u[i] * wb.y;
                    acc[i][6] += u[i] * wb.z; acc[i][7] += u[i] * wb.w;
                }
            }
        }
        #pragma unroll
        for (int i = 0; i < 8; ++i) {
            int gr = row0 + rbase + i;
            if (gr < N_NODES) {
                float v0 = acc[i][0] + bA[0], v1 = acc[i][1] + bA[1];
                float v2 = acc[i][2] + bA[2], v3 = acc[i][3] + bA[3];
                float v4 = acc[i][4] + bA[4], v5 = acc[i][5] + bA[5];
                float v6 = acc[i][6] + bA[6], v7 = acc[i][7] + bA[7];
                uint4 pk;
                pk.x = pk_bf16(v0, v1); pk.y = pk_bf16(v2, v3);
                pk.z = pk_bf16(v4, v5); pk.w = pk_bf16(v6, v7);
                *(uint4*)&hbf[(size_t)gr * 32 + (cbase >> 1)] = pk;
                *(float4*)&hsum[(size_t)gr * HID + cbase] = make_float4(v0, v1, v2, v3);
                *(float4*)&hsum[(size_t)gr * HID + cbase + 4] = make_float4(v4, v5, v6, v7);
            }
        }
    }
}

// ---------------- s_e = agg @ w_edge + wsum * b_edge ----------------

__global__ __launch_bounds__(256) void k_se(const float* __restrict__ agg,
                                            const float* __restrict__ wsumv,
                                            const float* __restrict__ we,
                                            const float* __restrict__ be,
                                            float* __restrict__ se) {
    int lane = threadIdx.x & 63, wid = threadIdx.x >> 6;
    float wreg[EDIM];
    #pragma unroll
    for (int k = 0; k < EDIM; ++k) wreg[k] = we[k * HID + lane];
    float bl = be[lane];
    for (int v = blockIdx.x * 4 + wid; v < N_NODES; v += gridDim.x * 4) {
        const float4* ar = (const float4*)(agg + (size_t)v * EDIM);
        float acc = wsumv[v] * bl;
        #pragma unroll
        for (int k4 = 0; k4 < EDIM / 4; ++k4) {
            float4 av = ar[k4];
            int k = k4 * 4;
            acc += av.x * wreg[k + 0] + av.y * wreg[k + 1] +
                   av.z * wreg[k + 2] + av.w * wreg[k + 3];
        }
        se[(size_t)v * HID + lane] = acc;
    }
}

// ---------------- one GCN layer (pull; bf16 h state, 128B row gathers) ----------------
// half-wave per node; lane owns a dim-pair (packed bf16x2). hsum stays f32.

__global__ __launch_bounds__(256) void k_layer(const unsigned* __restrict__ hbf_old,
                                               const float* __restrict__ se,
                                               const int* __restrict__ csr_src,
                                               const float* __restrict__ csr_norm,
                                               const int* __restrict__ offs,
                                               const float* __restrict__ dinv,
                                               unsigned* __restrict__ hbf_new,
                                               float* __restrict__ hsum) {
    int gw = (blockIdx.x * 256 + threadIdx.x) >> 6;
    int lane = threadIdx.x & 63;
    int half = lane >> 5, dp = lane & 31;          // dim pair 2*dp, 2*dp+1
    int v = gw * 2 + half;
    if (v >= N_NODES) return;
    int start = offs[v], end = offs[v + 1];
    float dv = dinv[v];
    size_t vp = (size_t)v * 32 + dp;
    unsigned hv = hbf_old[vp];
    float a0 = dv * bf_lo(hv), a1 = dv * bf_hi(hv);   // self loop (x dv again below)
    for (int i = start; i < end; i += 4) {
        int i1 = i + 1, i2 = i + 2, i3 = i + 3;
        int s0 = csr_src[i];
        int s1 = (i1 < end) ? csr_src[i1] : 0;
        int s2 = (i2 < end) ? csr_src[i2] : 0;
        int s3 = (i3 < end) ? csr_src[i3] : 0;
        float n0 = csr_norm[i];
        float n1 = (i1 < end) ? csr_norm[i1] : 0.f;
        float n2 = (i2 < end) ? csr_norm[i2] : 0.f;
        float n3 = (i3 < end) ? csr_norm[i3] : 0.f;
        unsigned g0 = hbf_old[(size_t)s0 * 32 + dp];
        unsigned g1 = hbf_old[(size_t)s1 * 32 + dp];
        unsigned g2 = hbf_old[(size_t)s2 * 32 + dp];
        unsigned g3 = hbf_old[(size_t)s3 * 32 + dp];
        a0 += n0 * bf_lo(g0) + n1 * bf_lo(g1) + n2 * bf_lo(g2) + n3 * bf_lo(g3);
        a1 += n0 * bf_hi(g0) + n1 * bf_hi(g1) + n2 * bf_hi(g2) + n3 * bf_hi(g3);
    }
    size_t vi = (size_t)v * HID + dp * 2;
    float2 sv = *(const float2*)&se[vi];
    float r0 = sv.x + dv * a0;
    float r1 = sv.y + dv * a1;
    r0 = (r0 > 0.f) ? r0 : 0.2f * r0;
    r1 = (r1 > 0.f) ? r1 : 0.2f * r1;
    hbf_new[vp] = pk_bf16(r0, r1);
    float2 hs = *(const float2*)&hsum[vi];
    *(float2*)&hsum[vi] = make_float2(hs.x + r0, hs.y + r1);
}

// ---------------- z GEMM + BN stats ----------------

__global__ __launch_bounds__(256) void k_zstats(const float* __restrict__ hsum,
                                                const float* __restrict__ cfeat,
                                                const float* __restrict__ w1,
                                                const float* __restrict__ b1,
                                                float* __restrict__ z,
                                                float* __restrict__ stats) {
    __shared__ float ws[K1 * C1];    // 48 KB
    __shared__ float ut[128 * 49];   // 24.5 KB
    __shared__ float red[4][64];     // 1 KB
    for (int i = threadIdx.x; i < K1 * C1; i += 256) ws[i] = w1[i];
    int tid = threadIdx.x;
    int lane = tid & 63, wave = tid >> 6;
    int lr = lane >> 3, lc = lane & 7;
    int wr = wave >> 1, wc = wave & 1;
    int rbase = wr * 64 + lr * 8;
    int cbase = wc * 64 + lc * 8;
    float bA[8];
    #pragma unroll
    for (int j = 0; j < 8; ++j) bA[j] = b1[cbase + j];
    float s[8], q[8];
    #pragma unroll
    for (int j = 0; j < 8; ++j) { s[j] = 0.f; q[j] = 0.f; }

    for (int tile = blockIdx.x; tile < ZTILES; tile += gridDim.x) {
        int row0 = tile * 128;
        float acc[8][8];
        #pragma unroll
        for (int i = 0; i < 8; ++i)
            #pragma unroll
            for (int j = 0; j < 8; ++j) acc[i][j] = 0.f;
        for (int ch = 0; ch < 2; ++ch) {
            int kbase = ch * 48;
            __syncthreads();
            #pragma unroll
            for (int p = 0; p < 6; ++p) {
                int idx = p * 256 + tid;
                int row = idx / 12, kq = idx % 12;
                int gk = kbase + kq * 4;
                float4 v = make_float4(0.f, 0.f, 0.f, 0.f);
                int gr = row0 + row;
                if (gr < N_NODES) {
                    if (gk < HID) v = *(const float4*)&hsum[(size_t)gr * HID + gk];
                    else          v = *(const float4*)&cfeat[(size_t)gr * HIER + (gk - HID)];
                }
                float* d = &ut[row * 49 + kq * 4];
                d[0] = v.x; d[1] = v.y; d[2] = v.z; d[3] = v.w;
            }
            __syncthreads();
            for (int k = 0; k < 48; ++k) {
                float u[8];
                #pragma unroll
                for (int i = 0; i < 8; ++i) u[i] = ut[(rbase + i) * 49 + k];
                const float* wrow = &ws[(kbase + k) * C1 + cbase];
                float4 wa = *(const float4*)&wrow[0];
                float4 wb = *(const float4*)&wrow[4];
                #pragma unroll
                for (int i = 0; i < 8; ++i) {
                    acc[i][0] += u[i] * wa.x; acc[i][1] += u[i] * wa.y;
                    acc[i][2] += u[i] * wa.z; acc[i][3] += u[i] * wa.w;
                    acc[i][4] += u[i] * wb.x; acc[i][5] += u[i] * wb.y;
                    acc[i][6] += u[i] * wb.z; acc[i][7] += u[i] * wb.w;
                }
            }
        }
        #pragma unroll
        for (int i = 0; i < 8; ++i) {
            int gr = row0 + rbase + i;
            if (gr < N_NODES) {
                float zz[8];
                #pragma unroll
                for (int j = 0; j < 8; ++j) {
                    zz[j] = acc[i][j] + bA[j];
                    s[j] += zz[j]; q[j] += zz[j] * zz[j];
                }
                *(float4*)&z[(size_t)gr * C1 + cbase] =
                    make_float4(zz[0], zz[1], zz[2], zz[3]);
                *(float4*)&z[(size_t)gr * C1 + cbase + 4] =
                    make_float4(zz[4], zz[5], zz[6], zz[7]);
            }
        }
    }

    #pragma unroll
    for (int j = 0; j < 8; ++j) {
        s[j] += __shfl_xor(s[j], 8); s[j] += __shfl_xor(s[j], 16); s[j] += __shfl_xor(s[j], 32);
        q[j] += __shfl_xor(q[j], 8); q[j] += __shfl_xor(q[j], 16); q[j] += __shfl_xor(q[j], 32);
    }
    __syncthreads();
    if (lr == 0) {
        #pragma unroll
        for (int j = 0; j < 8; ++j) red[wave][lc * 8 + j] = s[j];
    }
    __syncthreads();
    if (tid < 128) {
        int wc2 = tid >> 6, cl = tid & 63;
        atomicAdd(&stats[wc2 * 64 + cl], red[wc2][cl] + red[wc2 + 2][cl]);
    }
    __syncthreads();
    if (lr == 0) {
        #pragma unroll
        for (int j = 0; j < 8; ++j) red[wave][lc * 8 + j] = q[j];
    }
    __syncthreads();
    if (tid < 128) {
        int wc2 = tid >> 6, cl = tid & 63;
        atomicAdd(&stats[C1 + wc2 * 64 + cl], red[wc2][cl] + red[wc2 + 2][cl]);
    }
}

__global__ void k_ab(const float* __restrict__ stats, const float* __restrict__ gamma,
                     const float* __restrict__ beta, float* __restrict__ ab) {
    int t = threadIdx.x;
    if (t < C1) {
        float mu = stats[t] / (float)N_NODES;
        float var = stats[C1 + t] / (float)N_NODES - mu * mu;
        float inv = rsqrtf(var + BN_EPS);
        float a = gamma[t] * inv;
        ab[t] = a;
        ab[C1 + t] = beta[t] - mu * a;
    }
}

// ---------------- output: PReLU(BN(z)) @ w_out2 + b_out2 (streaming z) ----------------

__global__ __launch_bounds__(256) void k_out2(const float* __restrict__ z,
                                              const float* __restrict__ ab,
                                              const float* __restrict__ pa,
                                              const float* __restrict__ w2,
                                              const float* __restrict__ b2,
                                              float* __restrict__ out) {
    int lane = threadIdx.x & 63, wid = threadIdx.x >> 6;
    float w2a[NCLS], w2b[NCLS], bb[NCLS];
    #pragma unroll
    for (int j = 0; j < NCLS; ++j) {
        w2a[j] = w2[lane * NCLS + j];
        w2b[j] = w2[(64 + lane) * NCLS + j];
        bb[j] = b2[j];
    }
    float sa0 = ab[lane], sa1 = ab[64 + lane];
    float sb0 = ab[C1 + lane], sb1 = ab[C1 + 64 + lane];
    float alpha = pa[0];
    for (int v = blockIdx.x * 4 + wid; v < N_NODES; v += gridDim.x * 4) {
        float z0 = z[(size_t)v * C1 + lane];
        float z1 = z[(size_t)v * C1 + 64 + lane];
        float p0 = z0 * sa0 + sb0; p0 = (p0 > 0.f) ? p0 : alpha * p0;
        float p1 = z1 * sa1 + sb1; p1 = (p1 > 0.f) ? p1 : alpha * p1;
        float pj[NCLS];
        #pragma unroll
        for (int j = 0; j < NCLS; ++j) pj[j] = p0 * w2a[j] + p1 * w2b[j];
        #pragma unroll
        for (int j = 0; j < NCLS; ++j) {
            #pragma unroll
            for (int d = 32; d >= 1; d >>= 1) pj[j] += __shfl_xor(pj[j], d);
        }
        if (lane == 0) {
            #pragma unroll
            for (int j = 0; j < NCLS; ++j)
                out[(size_t)v * NCLS + j] = pj[j] + bb[j];
        }
    }
}

// ---------------- host ----------------

extern "C" void kernel_launch(void* const* d_in, const int* in_sizes, int n_in,
                              void* d_out, int out_size, void* d_ws, size_t ws_size,
                              hipStream_t stream) {
    const float* x      = (const float*)d_in[0];
    const float* e      = (const float*)d_in[1];
    const float* c      = (const float*)d_in[2];
    const float* w_node = (const float*)d_in[3];
    const float* b_node = (const float*)d_in[4];
    const float* w_edge = (const float*)d_in[5];
    const float* b_edge = (const float*)d_in[6];
    const float* w_out1 = (const float*)d_in[7];
    const float* b_out1 = (const float*)d_in[8];
    const float* gamma  = (const float*)d_in[9];
    const float* beta   = (const float*)d_in[10];
    const float* pa     = (const float*)d_in[11];
    const float* w_out2 = (const float*)d_in[12];
    const float* b_out2 = (const float*)d_in[13];
    const int*   ei     = (const int*)d_in[14];
    float* out = (float*)d_out;

    char* wsb = (char*)d_ws;
    // Region A (64MB): ebf [bf16 1M x 32] in eid order; dead after k_agg3.
    //   Then se (25.6MB) at offset 0 (lives through layers);
    //   z (51.2MB) at offset 0 overlays se after layers are done.
    ushort* ebf = (ushort*)wsb;
    float*  se  = (float*)wsb;
    float*  z   = (float*)wsb;
    size_t off = (64000000 + 255) & ~(size_t)255;
    auto alloc = [&](size_t bytes) {
        void* p = wsb + off;
        off = (off + bytes + 255) & ~(size_t)255;
        return p;
    };
    int*      cnt      = (int*)alloc(4ull * N_NODES);
    int*      offs     = (int*)alloc(4ull * (N_NODES + 1));
    float*    dinv     = (float*)alloc(4ull * N_NODES);
    int*      bsum     = (int*)alloc(4ull * 128);
    int*      csr_src  = (int*)alloc(4ull * N_EDGES);
    int*      csr_eid  = (int*)alloc(4ull * N_EDGES);
    float*    csr_norm = (float*)alloc(4ull * N_EDGES);
    float*    agg      = (float*)alloc(4ull * N_NODES * EDIM);
    float*    wsumv    = (float*)alloc(4ull * N_NODES);
    float*    stats    = (float*)alloc(4ull * 256);
    float*    ab       = (float*)alloc(4ull * 256);
    unsigned* hbf_a    = (unsigned*)alloc(4ull * N_NODES * 32);  // bf16x2 packed
    unsigned* hbf_b    = (unsigned*)alloc(4ull * N_NODES * 32);
    float*    h_sum    = (float*)alloc(4ull * N_NODES * HID);

    hipMemsetAsync(cnt, 0, 4ull * N_NODES, stream);
    hipMemsetAsync(stats, 0, 4ull * 256, stream);

    k_count<<<(N_EDGES + 255) / 256, 256, 0, stream>>>(ei, cnt);
    k_scan1<<<SCAN_B, 1024, 0, stream>>>(cnt, offs, dinv, bsum);
    k_scan2<<<1, 1024, 0, stream>>>(bsum, SCAN_B);
    k_scan3<<<SCAN_B, 1024, 0, stream>>>(bsum, offs);
    hipMemsetAsync(cnt, 0, 4ull * N_NODES, stream);
    k_fill<<<(N_EDGES + 255) / 256, 256, 0, stream>>>(ei, offs, cnt, dinv,
                                                      csr_src, csr_eid, csr_norm);

    // sequential bf16 convert (eid order), then gather-sum from L3-hot ebf
    k_conv<<<N_EDGES / 8, 256, 0, stream>>>(e, ei, dinv, ebf);
    k_agg3<<<N_NODES / 8, 256, 0, stream>>>(ebf, csr_eid, csr_norm, offs, dinv, agg, wsumv);

    k_se<<<1280, 256, 0, stream>>>(agg, wsumv, w_edge, b_edge, se);   // se over dead ebf
    k_h0t<<<HTILES, 256, 0, stream>>>(x, w_node, b_node, hbf_a, h_sum);

    k_layer<<<N_NODES / 8, 256, 0, stream>>>(hbf_a, se, csr_src, csr_norm, offs, dinv, hbf_b, h_sum);
    k_layer<<<N_NODES / 8, 256, 0, stream>>>(hbf_b, se, csr_src, csr_norm, offs, dinv, hbf_a, h_sum);
    k_layer<<<N_NODES / 8, 256, 0, stream>>>(hbf_a, se, csr_src, csr_norm, offs, dinv, hbf_b, h_sum);

    k_zstats<<<512, 256, 0, stream>>>(h_sum, c, w_out1, b_out1, z, stats);
    k_ab<<<1, 128, 0, stream>>>(stats, gamma, beta, ab);
    k_out2<<<2048, 256, 0, stream>>>(z, ab, pa, w_out2, b_out2, out);
}

// Round 9
// 518.303 us; speedup vs baseline: 2.0386x; 1.1399x over previous
//
#include <hip/hip_runtime.h>
#include <math.h>

#define N_NODES 100000
#define N_EDGES 1000000
#define HID     64
#define HIER    32
#define NDIM    128
#define EDIM    32
#define K1      96    // HIER + HID
#define C1      128   // 2*HID
#define NCLS    10
#define BN_EPS  1e-5f
#define SCAN_B  98    // ceil(N_NODES/1024)
#define ZTILES  782   // ceil(N_NODES/128)
#define HTILES  391   // ceil(N_NODES/256)

// pack two f32 -> (bf16(a) | bf16(b)<<16), round-to-nearest-even
__device__ __forceinline__ unsigned pk_bf16(float a, float b) {
    unsigned ua = __float_as_uint(a);
    ua = (ua + 0x7FFFu + ((ua >> 16) & 1u)) >> 16;
    unsigned ub = __float_as_uint(b);
    ub = (ub + 0x7FFFu + ((ub >> 16) & 1u)) & 0xFFFF0000u;
    return ua | ub;
}
__device__ __forceinline__ float bf_lo(unsigned g) { return __uint_as_float(g << 16); }
__device__ __forceinline__ float bf_hi(unsigned g) { return __uint_as_float(g & 0xFFFF0000u); }

// ---------------- CSR build ----------------

__global__ void k_count(const int* __restrict__ ei, int* __restrict__ cnt) {
    int i = blockIdx.x * blockDim.x + threadIdx.x;
    if (i < N_EDGES) atomicAdd(&cnt[ei[N_EDGES + i]], 1);
}

__global__ void k_scan1(const int* __restrict__ cnt, int* __restrict__ offs,
                        float* __restrict__ dinv, int* __restrict__ bsum) {
    __shared__ int buf[2][1024];
    int t = threadIdx.x, b = blockIdx.x;
    int i = b * 1024 + t;
    int v = (i < N_NODES) ? cnt[i] : 0;
    buf[0][t] = v; __syncthreads();
    int pi = 0;
    for (int off = 1; off < 1024; off <<= 1) {
        int x = buf[pi][t];
        if (t >= off) x += buf[pi][t - off];
        buf[pi ^ 1][t] = x; __syncthreads(); pi ^= 1;
    }
    int incl = buf[pi][t];
    if (i < N_NODES) {
        offs[i] = incl - v;
        dinv[i] = rsqrtf((float)(v + 1));
    }
    if (t == 1023) bsum[b] = incl;
}

__global__ void k_scan2(int* __restrict__ bsum, int nb) {
    __shared__ int buf[2][1024];
    int t = threadIdx.x;
    int v = (t < nb) ? bsum[t] : 0;
    buf[0][t] = v; __syncthreads();
    int pi = 0;
    for (int off = 1; off < 1024; off <<= 1) {
        int x = buf[pi][t];
        if (t >= off) x += buf[pi][t - off];
        buf[pi ^ 1][t] = x; __syncthreads(); pi ^= 1;
    }
    int incl = buf[pi][t];
    if (t < nb) bsum[t] = incl - v;
}

__global__ void k_scan3(const int* __restrict__ bsum, int* __restrict__ offs) {
    int b = blockIdx.x;
    int i = b * 1024 + threadIdx.x;
    if (i < N_NODES) offs[i] += bsum[b];
    if (i == 0) offs[N_NODES] = N_EDGES;
}

__global__ void k_fill(const int* __restrict__ ei, const int* __restrict__ offs,
                       int* __restrict__ cursor, const float* __restrict__ dinv,
                       int* __restrict__ csr_src, int* __restrict__ csr_eid,
                       float* __restrict__ csr_norm) {
    int i = blockIdx.x * blockDim.x + threadIdx.x;
    if (i >= N_EDGES) return;
    int s = ei[i], d = ei[N_EDGES + i];
    int pos = offs[d] + atomicAdd(&cursor[d], 1);
    csr_src[pos] = s;
    csr_eid[pos] = i;
    csr_norm[pos] = dinv[s];
}

// ---------------- pure streaming convert: ebf = bf16(e), eid order ----------------
// No index/dinv loads at all (norm is applied in k_agg3 which loads csr_norm anyway).
// Each thread: 32B in (2 x float4), 16B out (uint4).

__global__ __launch_bounds__(256) void k_conv(const float4* __restrict__ e4,
                                              uint4* __restrict__ eb4) {
    int i = blockIdx.x * 256 + threadIdx.x;     // 4M threads, 8 floats each
    float4 a = e4[(size_t)2 * i];
    float4 b = e4[(size_t)2 * i + 1];
    uint4 pk;
    pk.x = pk_bf16(a.x, a.y); pk.y = pk_bf16(a.z, a.w);
    pk.z = pk_bf16(b.x, b.y); pk.w = pk_bf16(b.z, b.w);
    eb4[i] = pk;
}

// ---------------- edge aggregation: quarter-wave per node ----------------
// 16 lanes x 4B (bf16x2) = one 64B edge row; unroll 4 -> 16 gathers/wave in flight.
// agg[v] = dinv[v] * sum norm_e * ebf[eid]; wsum[v] = dinv[v] * sum norm_e.

__global__ __launch_bounds__(256) void k_agg3(const unsigned* __restrict__ ebfu,
                                              const int* __restrict__ csr_eid,
                                              const float* __restrict__ csr_norm,
                                              const int* __restrict__ offs,
                                              const float* __restrict__ dinv,
                                              float* __restrict__ agg,
                                              float* __restrict__ wsumv) {
    int v = (blockIdx.x * 256 + threadIdx.x) >> 4;
    if (v >= N_NODES) return;
    int q = threadIdx.x & 15;                  // uint index = dims 2q, 2q+1
    int start = offs[v], end = offs[v + 1];
    float ax = 0.f, ay = 0.f, wacc = 0.f;
    for (int i = start; i < end; i += 4) {
        int i1 = i + 1, i2 = i + 2, i3 = i + 3;
        int e0 = csr_eid[i];
        int e1 = (i1 < end) ? csr_eid[i1] : 0;
        int e2 = (i2 < end) ? csr_eid[i2] : 0;
        int e3 = (i3 < end) ? csr_eid[i3] : 0;
        float n0 = csr_norm[i];
        float n1 = (i1 < end) ? csr_norm[i1] : 0.f;
        float n2 = (i2 < end) ? csr_norm[i2] : 0.f;
        float n3 = (i3 < end) ? csr_norm[i3] : 0.f;
        unsigned g0 = ebfu[(size_t)e0 * 16 + q];
        unsigned g1 = ebfu[(size_t)e1 * 16 + q];
        unsigned g2 = ebfu[(size_t)e2 * 16 + q];
        unsigned g3 = ebfu[(size_t)e3 * 16 + q];
        ax += n0 * bf_lo(g0) + n1 * bf_lo(g1) + n2 * bf_lo(g2) + n3 * bf_lo(g3);
        ay += n0 * bf_hi(g0) + n1 * bf_hi(g1) + n2 * bf_hi(g2) + n3 * bf_hi(g3);
        wacc += n0 + n1 + n2 + n3;
    }
    float dv = dinv[v];
    *(float2*)&agg[(size_t)v * EDIM + q * 2] = make_float2(dv * ax, dv * ay);
    if (q == 0) wsumv[v] = dv * wacc;
}

// ---------------- node encoder (tiled GEMM): hb0 = bf16(x @ w_node + b) ----------------

__global__ __launch_bounds__(256) void k_h0t(const float* __restrict__ x,
                                             const float* __restrict__ w,
                                             const float* __restrict__ bias,
                                             unsigned* __restrict__ hbf) {
    __shared__ float ws[NDIM * HID];   // 32 KB
    __shared__ float xt[256 * 33];     // 33.8 KB
    for (int i = threadIdx.x; i < NDIM * HID; i += 256) ws[i] = w[i];
    int tid = threadIdx.x;
    int lane = tid & 63, wave = tid >> 6;
    int lr = lane >> 3, lc = lane & 7;
    int rbase = wave * 64 + lr * 8;
    int cbase = lc * 8;
    float bA[8];
    #pragma unroll
    for (int j = 0; j < 8; ++j) bA[j] = bias[cbase + j];
    for (int tile = blockIdx.x; tile < HTILES; tile += gridDim.x) {
        int row0 = tile * 256;
        float acc[8][8];
        #pragma unroll
        for (int i = 0; i < 8; ++i)
            #pragma unroll
            for (int j = 0; j < 8; ++j) acc[i][j] = 0.f;
        for (int ch = 0; ch < 4; ++ch) {
            __syncthreads();
            #pragma unroll
            for (int p = 0; p < 8; ++p) {
                int idx = p * 256 + tid;
                int row = idx >> 3, kq = idx & 7;
                int gk = ch * 32 + kq * 4;
                float4 v = make_float4(0.f, 0.f, 0.f, 0.f);
                int gr = row0 + row;
                if (gr < N_NODES) v = *(const float4*)&x[(size_t)gr * NDIM + gk];
                float* d = &xt[row * 33 + kq * 4];
                d[0] = v.x; d[1] = v.y; d[2] = v.z; d[3] = v.w;
            }
            __syncthreads();
            for (int k = 0; k < 32; ++k) {
                float u[8];
                #pragma unroll
                for (int i = 0; i < 8; ++i) u[i] = xt[(rbase + i) * 33 + k];
                const float* wrow = &ws[(ch * 32 + k) * HID + cbase];
                float4 wa = *(const float4*)&wrow[0];
                float4 wb = *(const float4*)&wrow[4];
                #pragma unroll
                for (int i = 0; i < 8; ++i) {
                    acc[i][0] += u[i] * wa.x; acc[i][1] += u[i] * wa.y;
                    acc[i][2] += u[i] * wa.z; acc[i][3] += u[i] * wa.w;
                    acc[i][4] += u[i] * wb.x; acc[i][5] += u[i] * wb.y;
                    acc[i][6] += u[i] * wb.z; acc[i][7] += u[i] * wb.w;
                }
            }
        }
        #pragma unroll
        for (int i = 0; i < 8; ++i) {
            int gr = row0 + rbase + i;
            if (gr < N_NODES) {
                uint4 pk;
                pk.x = pk_bf16(acc[i][0] + bA[0], acc[i][1] + bA[1]);
                pk.y = pk_bf16(acc[i][2] + bA[2], acc[i][3] + bA[3]);
                pk.z = pk_bf16(acc[i][4] + bA[4], acc[i][5] + bA[5]);
                pk.w = pk_bf16(acc[i][6] + bA[6], acc[i][7] + bA[7]);
                *(uint4*)&hbf[(size_t)gr * 32 + (cbase >> 1)] = pk;
            }
        }
    }
}

// ---------------- s_e = agg @ w_edge + wsum * b_edge ----------------

__global__ __launch_bounds__(256) void k_se(const float* __restrict__ agg,
                                            const float* __restrict__ wsumv,
                                            const float* __restrict__ we,
                                            const float* __restrict__ be,
                                            float* __restrict__ se) {
    int lane = threadIdx.x & 63, wid = threadIdx.x >> 6;
    float wreg[EDIM];
    #pragma unroll
    for (int k = 0; k < EDIM; ++k) wreg[k] = we[k * HID + lane];
    float bl = be[lane];
    for (int v = blockIdx.x * 4 + wid; v < N_NODES; v += gridDim.x * 4) {
        const float4* ar = (const float4*)(agg + (size_t)v * EDIM);
        float acc = wsumv[v] * bl;
        #pragma unroll
        for (int k4 = 0; k4 < EDIM / 4; ++k4) {
            float4 av = ar[k4];
            int k = k4 * 4;
            acc += av.x * wreg[k + 0] + av.y * wreg[k + 1] +
                   av.z * wreg[k + 2] + av.w * wreg[k + 3];
        }
        se[(size_t)v * HID + lane] = acc;
    }
}

// ---------------- one GCN layer (pull; bf16 h, no hsum, unroll 8) ----------------

__global__ __launch_bounds__(256) void k_layer(const unsigned* __restrict__ hold,
                                               const float* __restrict__ se,
                                               const int* __restrict__ csr_src,
                                               const float* __restrict__ csr_norm,
                                               const int* __restrict__ offs,
                                               const float* __restrict__ dinv,
                                               unsigned* __restrict__ hnew) {
    int gw = (blockIdx.x * 256 + threadIdx.x) >> 6;
    int lane = threadIdx.x & 63;
    int half = lane >> 5, dp = lane & 31;          // dim pair 2*dp, 2*dp+1
    int v = gw * 2 + half;
    if (v >= N_NODES) return;
    int start = offs[v], end = offs[v + 1];
    float dv = dinv[v];
    size_t vp = (size_t)v * 32 + dp;
    unsigned hv = hold[vp];
    float a0 = dv * bf_lo(hv), a1 = dv * bf_hi(hv);   // self loop (x dv again below)
    for (int i = start; i < end; i += 8) {
        int idx[8]; float nn[8]; unsigned gg[8];
        #pragma unroll
        for (int u = 0; u < 8; ++u) {
            int ii = i + u;
            idx[u] = (ii < end) ? csr_src[ii] : 0;
            nn[u]  = (ii < end) ? csr_norm[ii] : 0.f;
        }
        #pragma unroll
        for (int u = 0; u < 8; ++u) gg[u] = hold[(size_t)idx[u] * 32 + dp];
        #pragma unroll
        for (int u = 0; u < 8; ++u) {
            a0 += nn[u] * bf_lo(gg[u]);
            a1 += nn[u] * bf_hi(gg[u]);
        }
    }
    size_t vi = (size_t)v * HID + dp * 2;
    float2 sv = *(const float2*)&se[vi];
    float r0 = sv.x + dv * a0;
    float r1 = sv.y + dv * a1;
    r0 = (r0 > 0.f) ? r0 : 0.2f * r0;
    r1 = (r1 > 0.f) ? r1 : 0.2f * r1;
    hnew[vp] = pk_bf16(r0, r1);
}

// ---------------- z GEMM + BN stats (hsum = hb0+hb1+hb2+hb3 at staging) ----------------

__global__ __launch_bounds__(256) void k_zstats(const unsigned* __restrict__ hb0,
                                                const unsigned* __restrict__ hb1,
                                                const unsigned* __restrict__ hb2,
                                                const unsigned* __restrict__ hb3,
                                                const float* __restrict__ cfeat,
                                                const float* __restrict__ w1,
                                                const float* __restrict__ b1,
                                                float* __restrict__ z,
                                                float* __restrict__ stats) {
    __shared__ float ws[K1 * C1];    // 48 KB
    __shared__ float ut[128 * 49];   // 24.5 KB
    __shared__ float red[4][64];     // 1 KB
    for (int i = threadIdx.x; i < K1 * C1; i += 256) ws[i] = w1[i];
    int tid = threadIdx.x;
    int lane = tid & 63, wave = tid >> 6;
    int lr = lane >> 3, lc = lane & 7;
    int wr = wave >> 1, wc = wave & 1;
    int rbase = wr * 64 + lr * 8;
    int cbase = wc * 64 + lc * 8;
    float bA[8];
    #pragma unroll
    for (int j = 0; j < 8; ++j) bA[j] = b1[cbase + j];
    float s[8], q[8];
    #pragma unroll
    for (int j = 0; j < 8; ++j) { s[j] = 0.f; q[j] = 0.f; }

    for (int tile = blockIdx.x; tile < ZTILES; tile += gridDim.x) {
        int row0 = tile * 128;
        float acc[8][8];
        #pragma unroll
        for (int i = 0; i < 8; ++i)
            #pragma unroll
            for (int j = 0; j < 8; ++j) acc[i][j] = 0.f;
        for (int ch = 0; ch < 2; ++ch) {
            int kbase = ch * 48;
            __syncthreads();
            #pragma unroll
            for (int p = 0; p < 6; ++p) {
                int idx = p * 256 + tid;
                int row = idx / 12, kq = idx % 12;
                int gk = kbase + kq * 4;
                int gr = row0 + row;
                float f0 = 0.f, f1 = 0.f, f2 = 0.f, f3 = 0.f;
                if (gr < N_NODES) {
                    if (gk < HID) {
                        size_t o = (size_t)gr * 32 + (gk >> 1);
                        uint2 g0 = *(const uint2*)&hb0[o];
                        uint2 g1 = *(const uint2*)&hb1[o];
                        uint2 g2 = *(const uint2*)&hb2[o];
                        uint2 g3 = *(const uint2*)&hb3[o];
                        f0 = bf_lo(g0.x) + bf_lo(g1.x) + bf_lo(g2.x) + bf_lo(g3.x);
                        f1 = bf_hi(g0.x) + bf_hi(g1.x) + bf_hi(g2.x) + bf_hi(g3.x);
                        f2 = bf_lo(g0.y) + bf_lo(g1.y) + bf_lo(g2.y) + bf_lo(g3.y);
                        f3 = bf_hi(g0.y) + bf_hi(g1.y) + bf_hi(g2.y) + bf_hi(g3.y);
                    } else {
                        float4 v = *(const float4*)&cfeat[(size_t)gr * HIER + (gk - HID)];
                        f0 = v.x; f1 = v.y; f2 = v.z; f3 = v.w;
                    }
                }
                float* d = &ut[row * 49 + kq * 4];
                d[0] = f0; d[1] = f1; d[2] = f2; d[3] = f3;
            }
            __syncthreads();
            for (int k = 0; k < 48; ++k) {
                float u[8];
                #pragma unroll
                for (int i = 0; i < 8; ++i) u[i] = ut[(rbase + i) * 49 + k];
                const float* wrow = &ws[(kbase + k) * C1 + cbase];
                float4 wa = *(const float4*)&wrow[0];
                float4 wb = *(const float4*)&wrow[4];
                #pragma unroll
                for (int i = 0; i < 8; ++i) {
                    acc[i][0] += u[i] * wa.x; acc[i][1] += u[i] * wa.y;
                    acc[i][2] += u[i] * wa.z; acc[i][3] += u[i] * wa.w;
                    acc[i][4] += u[i] * wb.x; acc[i][5] += u[i] * wb.y;
                    acc[i][6] += u[i] * wb.z; acc[i][7] += u[i] * wb.w;
                }
            }
        }
        #pragma unroll
        for (int i = 0; i < 8; ++i) {
            int gr = row0 + rbase + i;
            if (gr < N_NODES) {
                float zz[8];
                #pragma unroll
                for (int j = 0; j < 8; ++j) {
                    zz[j] = acc[i][j] + bA[j];
                    s[j] += zz[j]; q[j] += zz[j] * zz[j];
                }
                *(float4*)&z[(size_t)gr * C1 + cbase] =
                    make_float4(zz[0], zz[1], zz[2], zz[3]);
                *(float4*)&z[(size_t)gr * C1 + cbase + 4] =
                    make_float4(zz[4], zz[5], zz[6], zz[7]);
            }
        }
    }

    #pragma unroll
    for (int j = 0; j < 8; ++j) {
        s[j] += __shfl_xor(s[j], 8); s[j] += __shfl_xor(s[j], 16); s[j] += __shfl_xor(s[j], 32);
        q[j] += __shfl_xor(q[j], 8); q[j] += __shfl_xor(q[j], 16); q[j] += __shfl_xor(q[j], 32);
    }
    __syncthreads();
    if (lr == 0) {
        #pragma unroll
        for (int j = 0; j < 8; ++j) red[wave][lc * 8 + j] = s[j];
    }
    __syncthreads();
    if (tid < 128) {
        int wc2 = tid >> 6, cl = tid & 63;
        atomicAdd(&stats[wc2 * 64 + cl], red[wc2][cl] + red[wc2 + 2][cl]);
    }
    __syncthreads();
    if (lr == 0) {
        #pragma unroll
        for (int j = 0; j < 8; ++j) red[wave][lc * 8 + j] = q[j];
    }
    __syncthreads();
    if (tid < 128) {
        int wc2 = tid >> 6, cl = tid & 63;
        atomicAdd(&stats[C1 + wc2 * 64 + cl], red[wc2][cl] + red[wc2 + 2][cl]);
    }
}

__global__ void k_ab(const float* __restrict__ stats, const float* __restrict__ gamma,
                     const float* __restrict__ beta, float* __restrict__ ab) {
    int t = threadIdx.x;
    if (t < C1) {
        float mu = stats[t] / (float)N_NODES;
        float var = stats[C1 + t] / (float)N_NODES - mu * mu;
        float inv = rsqrtf(var + BN_EPS);
        float a = gamma[t] * inv;
        ab[t] = a;
        ab[C1 + t] = beta[t] - mu * a;
    }
}

// ---------------- output: PReLU(BN(z)) @ w_out2 + b_out2 (streaming z) ----------------

__global__ __launch_bounds__(256) void k_out2(const float* __restrict__ z,
                                              const float* __restrict__ ab,
                                              const float* __restrict__ pa,
                                              const float* __restrict__ w2,
                                              const float* __restrict__ b2,
                                              float* __restrict__ out) {
    int lane = threadIdx.x & 63, wid = threadIdx.x >> 6;
    float w2a[NCLS], w2b[NCLS], bb[NCLS];
    #pragma unroll
    for (int j = 0; j < NCLS; ++j) {
        w2a[j] = w2[lane * NCLS + j];
        w2b[j] = w2[(64 + lane) * NCLS + j];
        bb[j] = b2[j];
    }
    float sa0 = ab[lane], sa1 = ab[64 + lane];
    float sb0 = ab[C1 + lane], sb1 = ab[C1 + 64 + lane];
    float alpha = pa[0];
    for (int v = blockIdx.x * 4 + wid; v < N_NODES; v += gridDim.x * 4) {
        float z0 = z[(size_t)v * C1 + lane];
        float z1 = z[(size_t)v * C1 + 64 + lane];
        float p0 = z0 * sa0 + sb0; p0 = (p0 > 0.f) ? p0 : alpha * p0;
        float p1 = z1 * sa1 + sb1; p1 = (p1 > 0.f) ? p1 : alpha * p1;
        float pj[NCLS];
        #pragma unroll
        for (int j = 0; j < NCLS; ++j) pj[j] = p0 * w2a[j] + p1 * w2b[j];
        #pragma unroll
        for (int j = 0; j < NCLS; ++j) {
            #pragma unroll
            for (int d = 32; d >= 1; d >>= 1) pj[j] += __shfl_xor(pj[j], d);
        }
        if (lane == 0) {
            #pragma unroll
            for (int j = 0; j < NCLS; ++j)
                out[(size_t)v * NCLS + j] = pj[j] + bb[j];
        }
    }
}

// ---------------- host ----------------

extern "C" void kernel_launch(void* const* d_in, const int* in_sizes, int n_in,
                              void* d_out, int out_size, void* d_ws, size_t ws_size,
                              hipStream_t stream) {
    const float* x      = (const float*)d_in[0];
    const float* e      = (const float*)d_in[1];
    const float* c      = (const float*)d_in[2];
    const float* w_node = (const float*)d_in[3];
    const float* b_node = (const float*)d_in[4];
    const float* w_edge = (const float*)d_in[5];
    const float* b_edge = (const float*)d_in[6];
    const float* w_out1 = (const float*)d_in[7];
    const float* b_out1 = (const float*)d_in[8];
    const float* gamma  = (const float*)d_in[9];
    const float* beta   = (const float*)d_in[10];
    const float* pa     = (const float*)d_in[11];
    const float* w_out2 = (const float*)d_in[12];
    const float* b_out2 = (const float*)d_in[13];
    const int*   ei     = (const int*)d_in[14];
    float* out = (float*)d_out;

    char* wsb = (char*)d_ws;
    // Region A (64MB): ebf [bf16 1M x 32] eid order; dead after k_agg3.
    //   Then se (25.6MB) at offset 0 (lives through layers);
    //   z (51.2MB) at offset 0 overlays se after layers are done.
    ushort* ebf = (ushort*)wsb;
    float*  se  = (float*)wsb;
    float*  z   = (float*)wsb;
    size_t off = (64000000 + 255) & ~(size_t)255;
    auto alloc = [&](size_t bytes) {
        void* p = wsb + off;
        off = (off + bytes + 255) & ~(size_t)255;
        return p;
    };
    int*      cnt      = (int*)alloc(4ull * N_NODES);
    int*      offs     = (int*)alloc(4ull * (N_NODES + 1));
    float*    dinv     = (float*)alloc(4ull * N_NODES);
    int*      bsum     = (int*)alloc(4ull * 128);
    int*      csr_src  = (int*)alloc(4ull * N_EDGES);
    int*      csr_eid  = (int*)alloc(4ull * N_EDGES);
    float*    csr_norm = (float*)alloc(4ull * N_EDGES);
    float*    agg      = (float*)alloc(4ull * N_NODES * EDIM);
    float*    wsumv    = (float*)alloc(4ull * N_NODES);
    float*    stats    = (float*)alloc(4ull * 256);
    float*    ab       = (float*)alloc(4ull * 256);
    unsigned* hb0      = (unsigned*)alloc(4ull * N_NODES * 32);  // bf16x2 packed
    unsigned* hb1      = (unsigned*)alloc(4ull * N_NODES * 32);
    unsigned* hb2      = (unsigned*)alloc(4ull * N_NODES * 32);
    unsigned* hb3      = (unsigned*)alloc(4ull * N_NODES * 32);

    hipMemsetAsync(cnt, 0, 4ull * N_NODES, stream);
    hipMemsetAsync(stats, 0, 4ull * 256, stream);

    k_count<<<(N_EDGES + 255) / 256, 256, 0, stream>>>(ei, cnt);
    k_scan1<<<SCAN_B, 1024, 0, stream>>>(cnt, offs, dinv, bsum);
    k_scan2<<<1, 1024, 0, stream>>>(bsum, SCAN_B);
    k_scan3<<<SCAN_B, 1024, 0, stream>>>(bsum, offs);
    hipMemsetAsync(cnt, 0, 4ull * N_NODES, stream);
    k_fill<<<(N_EDGES + 255) / 256, 256, 0, stream>>>(ei, offs, cnt, dinv,
                                                      csr_src, csr_eid, csr_norm);

    // pure-stream bf16 convert (32M floats / 8 per thread = 15625 blocks)
    k_conv<<<15625, 256, 0, stream>>>((const float4*)e, (uint4*)ebf);
    k_agg3<<<N_NODES * 16 / 256, 256, 0, stream>>>((const unsigned*)ebf, csr_eid,
                                                   csr_norm, offs, dinv, agg, wsumv);

    k_se<<<1280, 256, 0, stream>>>(agg, wsumv, w_edge, b_edge, se);   // se over dead ebf
    k_h0t<<<HTILES, 256, 0, stream>>>(x, w_node, b_node, hb0);

    k_layer<<<N_NODES / 8, 256, 0, stream>>>(hb0, se, csr_src, csr_norm, offs, dinv, hb1);
    k_layer<<<N_NODES / 8, 256, 0, stream>>>(hb1, se, csr_src, csr_norm, offs, dinv, hb2);
    k_layer<<<N_NODES / 8, 256, 0, stream>>>(hb2, se, csr_src, csr_norm, offs, dinv, hb3);

    k_zstats<<<512, 256, 0, stream>>>(hb0, hb1, hb2, hb3, c, w_out1, b_out1, z, stats);
    k_ab<<<1, 128, 0, stream>>>(stats, gamma, beta, ab);
    k_out2<<<2048, 256, 0, stream>>>(z, ab, pa, w_out2, b_out2, out);
}

// Round 10
// 495.230 us; speedup vs baseline: 2.1336x; 1.0466x over previous
//
#include <hip/hip_runtime.h>
#include <math.h>

#define N_NODES 100000
#define N_EDGES 1000000
#define HID     64
#define HIER    32
#define NDIM    128
#define EDIM    32
#define K1      96    // HIER + HID
#define C1      128   // 2*HID
#define NCLS    10
#define BN_EPS  1e-5f
#define SCAN_B  98    // ceil(N_NODES/1024)
#define ZTILES  782   // ceil(N_NODES/128)
#define HTILES  391   // ceil(N_NODES/256)

// pack two f32 -> (bf16(a) | bf16(b)<<16), round-to-nearest-even
__device__ __forceinline__ unsigned pk_bf16(float a, float b) {
    unsigned ua = __float_as_uint(a);
    ua = (ua + 0x7FFFu + ((ua >> 16) & 1u)) >> 16;
    unsigned ub = __float_as_uint(b);
    ub = (ub + 0x7FFFu + ((ub >> 16) & 1u)) & 0xFFFF0000u;
    return ua | ub;
}
__device__ __forceinline__ float bf_lo(unsigned g) { return __uint_as_float(g << 16); }
__device__ __forceinline__ float bf_hi(unsigned g) { return __uint_as_float(g & 0xFFFF0000u); }

// ---------------- CSR build ----------------

__global__ void k_count(const int* __restrict__ ei, int* __restrict__ cnt) {
    int i = blockIdx.x * blockDim.x + threadIdx.x;
    if (i < N_EDGES) atomicAdd(&cnt[ei[N_EDGES + i]], 1);
}

__global__ void k_scan1(const int* __restrict__ cnt, int* __restrict__ offs,
                        float* __restrict__ dinv, int* __restrict__ bsum) {
    __shared__ int buf[2][1024];
    int t = threadIdx.x, b = blockIdx.x;
    int i = b * 1024 + t;
    int v = (i < N_NODES) ? cnt[i] : 0;
    buf[0][t] = v; __syncthreads();
    int pi = 0;
    for (int off = 1; off < 1024; off <<= 1) {
        int x = buf[pi][t];
        if (t >= off) x += buf[pi][t - off];
        buf[pi ^ 1][t] = x; __syncthreads(); pi ^= 1;
    }
    int incl = buf[pi][t];
    if (i < N_NODES) {
        offs[i] = incl - v;
        dinv[i] = rsqrtf((float)(v + 1));
    }
    if (t == 1023) bsum[b] = incl;
}

__global__ void k_scan2(int* __restrict__ bsum, int nb) {
    __shared__ int buf[2][1024];
    int t = threadIdx.x;
    int v = (t < nb) ? bsum[t] : 0;
    buf[0][t] = v; __syncthreads();
    int pi = 0;
    for (int off = 1; off < 1024; off <<= 1) {
        int x = buf[pi][t];
        if (t >= off) x += buf[pi][t - off];
        buf[pi ^ 1][t] = x; __syncthreads(); pi ^= 1;
    }
    int incl = buf[pi][t];
    if (t < nb) bsum[t] = incl - v;
}

__global__ void k_scan3(const int* __restrict__ bsum, int* __restrict__ offs) {
    int b = blockIdx.x;
    int i = b * 1024 + threadIdx.x;
    if (i < N_NODES) offs[i] += bsum[b];
    if (i == 0) offs[N_NODES] = N_EDGES;
}

// packed CSR record: {src, eid, norm_bits, pad} -> ONE 16B scattered store/edge
__global__ void k_fill(const int* __restrict__ ei, const int* __restrict__ offs,
                       int* __restrict__ cursor, const float* __restrict__ dinv,
                       int4* __restrict__ epk) {
    int i = blockIdx.x * blockDim.x + threadIdx.x;
    if (i >= N_EDGES) return;
    int s = ei[i], d = ei[N_EDGES + i];
    int pos = offs[d] + atomicAdd(&cursor[d], 1);
    epk[pos] = make_int4(s, i, __float_as_int(dinv[s]), 0);
}

// ---------------- pure streaming convert: ebf = bf16(e), eid order ----------------

__global__ __launch_bounds__(256) void k_conv(const float4* __restrict__ e4,
                                              uint4* __restrict__ eb4) {
    int i = blockIdx.x * 256 + threadIdx.x;     // 4M threads, 8 floats each
    float4 a = e4[(size_t)2 * i];
    float4 b = e4[(size_t)2 * i + 1];
    uint4 pk;
    pk.x = pk_bf16(a.x, a.y); pk.y = pk_bf16(a.z, a.w);
    pk.z = pk_bf16(b.x, b.y); pk.w = pk_bf16(b.z, b.w);
    eb4[i] = pk;
}

// ---------------- edge aggregation: quarter-wave per node ----------------
// agg[v] = dinv[v] * sum norm_e * ebf[eid]; wsum[v] = dinv[v] * sum norm_e.

__global__ __launch_bounds__(256) void k_agg3(const unsigned* __restrict__ ebfu,
                                              const int4* __restrict__ epk,
                                              const int* __restrict__ offs,
                                              const float* __restrict__ dinv,
                                              float* __restrict__ agg,
                                              float* __restrict__ wsumv) {
    int v = (blockIdx.x * 256 + threadIdx.x) >> 4;
    if (v >= N_NODES) return;
    int q = threadIdx.x & 15;                  // uint index = dims 2q, 2q+1
    int start = offs[v], end = offs[v + 1];
    float ax = 0.f, ay = 0.f, wacc = 0.f;
    for (int i = start; i < end; i += 4) {
        int i1 = i + 1, i2 = i + 2, i3 = i + 3;
        int4 p0 = epk[i];
        int4 p1 = (i1 < end) ? epk[i1] : make_int4(0, 0, 0, 0);
        int4 p2 = (i2 < end) ? epk[i2] : make_int4(0, 0, 0, 0);
        int4 p3 = (i3 < end) ? epk[i3] : make_int4(0, 0, 0, 0);
        float n0 = __int_as_float(p0.z), n1 = __int_as_float(p1.z);
        float n2 = __int_as_float(p2.z), n3 = __int_as_float(p3.z);
        unsigned g0 = ebfu[(size_t)p0.y * 16 + q];
        unsigned g1 = ebfu[(size_t)p1.y * 16 + q];
        unsigned g2 = ebfu[(size_t)p2.y * 16 + q];
        unsigned g3 = ebfu[(size_t)p3.y * 16 + q];
        ax += n0 * bf_lo(g0) + n1 * bf_lo(g1) + n2 * bf_lo(g2) + n3 * bf_lo(g3);
        ay += n0 * bf_hi(g0) + n1 * bf_hi(g1) + n2 * bf_hi(g2) + n3 * bf_hi(g3);
        wacc += n0 + n1 + n2 + n3;
    }
    float dv = dinv[v];
    *(float2*)&agg[(size_t)v * EDIM + q * 2] = make_float2(dv * ax, dv * ay);
    if (q == 0) wsumv[v] = dv * wacc;
}

// ---------------- node encoder (tiled GEMM): hb0 = bf16(x @ w_node + b) ----------------

__global__ __launch_bounds__(256) void k_h0t(const float* __restrict__ x,
                                             const float* __restrict__ w,
                                             const float* __restrict__ bias,
                                             unsigned* __restrict__ hbf) {
    __shared__ float ws[NDIM * HID];   // 32 KB
    __shared__ float xt[256 * 33];     // 33.8 KB
    for (int i = threadIdx.x; i < NDIM * HID; i += 256) ws[i] = w[i];
    int tid = threadIdx.x;
    int lane = tid & 63, wave = tid >> 6;
    int lr = lane >> 3, lc = lane & 7;
    int rbase = wave * 64 + lr * 8;
    int cbase = lc * 8;
    float bA[8];
    #pragma unroll
    for (int j = 0; j < 8; ++j) bA[j] = bias[cbase + j];
    for (int tile = blockIdx.x; tile < HTILES; tile += gridDim.x) {
        int row0 = tile * 256;
        float acc[8][8];
        #pragma unroll
        for (int i = 0; i < 8; ++i)
            #pragma unroll
            for (int j = 0; j < 8; ++j) acc[i][j] = 0.f;
        for (int ch = 0; ch < 4; ++ch) {
            __syncthreads();
            #pragma unroll
            for (int p = 0; p < 8; ++p) {
                int idx = p * 256 + tid;
                int row = idx >> 3, kq = idx & 7;
                int gk = ch * 32 + kq * 4;
                float4 v = make_float4(0.f, 0.f, 0.f, 0.f);
                int gr = row0 + row;
                if (gr < N_NODES) v = *(const float4*)&x[(size_t)gr * NDIM + gk];
                float* d = &xt[row * 33 + kq * 4];
                d[0] = v.x; d[1] = v.y; d[2] = v.z; d[3] = v.w;
            }
            __syncthreads();
            for (int k = 0; k < 32; ++k) {
                float u[8];
                #pragma unroll
                for (int i = 0; i < 8; ++i) u[i] = xt[(rbase + i) * 33 + k];
                const float* wrow = &ws[(ch * 32 + k) * HID + cbase];
                float4 wa = *(const float4*)&wrow[0];
                float4 wb = *(const float4*)&wrow[4];
                #pragma unroll
                for (int i = 0; i < 8; ++i) {
                    acc[i][0] += u[i] * wa.x; acc[i][1] += u[i] * wa.y;
                    acc[i][2] += u[i] * wa.z; acc[i][3] += u[i] * wa.w;
                    acc[i][4] += u[i] * wb.x; acc[i][5] += u[i] * wb.y;
                    acc[i][6] += u[i] * wb.z; acc[i][7] += u[i] * wb.w;
                }
            }
        }
        #pragma unroll
        for (int i = 0; i < 8; ++i) {
            int gr = row0 + rbase + i;
            if (gr < N_NODES) {
                uint4 pk;
                pk.x = pk_bf16(acc[i][0] + bA[0], acc[i][1] + bA[1]);
                pk.y = pk_bf16(acc[i][2] + bA[2], acc[i][3] + bA[3]);
                pk.z = pk_bf16(acc[i][4] + bA[4], acc[i][5] + bA[5]);
                pk.w = pk_bf16(acc[i][6] + bA[6], acc[i][7] + bA[7]);
                *(uint4*)&hbf[(size_t)gr * 32 + (cbase >> 1)] = pk;
            }
        }
    }
}

// ---------------- s_e = bf16(agg @ w_edge + wsum * b_edge), packed pairs ----------------

__global__ __launch_bounds__(256) void k_se(const float* __restrict__ agg,
                                            const float* __restrict__ wsumv,
                                            const float* __restrict__ we,
                                            const float* __restrict__ be,
                                            unsigned* __restrict__ sebf) {
    int lane = threadIdx.x & 63, wid = threadIdx.x >> 6;
    float wreg[EDIM];
    #pragma unroll
    for (int k = 0; k < EDIM; ++k) wreg[k] = we[k * HID + lane];
    float bl = be[lane];
    for (int v = blockIdx.x * 4 + wid; v < N_NODES; v += gridDim.x * 4) {
        const float4* ar = (const float4*)(agg + (size_t)v * EDIM);
        float acc = wsumv[v] * bl;
        #pragma unroll
        for (int k4 = 0; k4 < EDIM / 4; ++k4) {
            float4 av = ar[k4];
            int k = k4 * 4;
            acc += av.x * wreg[k + 0] + av.y * wreg[k + 1] +
                   av.z * wreg[k + 2] + av.w * wreg[k + 3];
        }
        float partner = __shfl_xor(acc, 1);
        if ((lane & 1) == 0)
            sebf[(size_t)v * 32 + (lane >> 1)] = pk_bf16(acc, partner);
    }
}

// ---------------- one GCN layer (pull; bf16 h + bf16 se, packed CSR, unroll 8) ----------------

__global__ __launch_bounds__(256) void k_layer(const unsigned* __restrict__ hold,
                                               const unsigned* __restrict__ sebf,
                                               const int4* __restrict__ epk,
                                               const int* __restrict__ offs,
                                               const float* __restrict__ dinv,
                                               unsigned* __restrict__ hnew) {
    int gw = (blockIdx.x * 256 + threadIdx.x) >> 6;
    int lane = threadIdx.x & 63;
    int half = lane >> 5, dp = lane & 31;          // dim pair 2*dp, 2*dp+1
    int v = gw * 2 + half;
    if (v >= N_NODES) return;
    int start = offs[v], end = offs[v + 1];
    float dv = dinv[v];
    size_t vp = (size_t)v * 32 + dp;
    unsigned hv = hold[vp];
    float a0 = dv * bf_lo(hv), a1 = dv * bf_hi(hv);   // self loop (x dv again below)
    for (int i = start; i < end; i += 8) {
        int idx[8]; float nn[8]; unsigned gg[8];
        #pragma unroll
        for (int u = 0; u < 8; ++u) {
            int ii = i + u;
            int4 p = (ii < end) ? epk[ii] : make_int4(0, 0, 0, 0);
            idx[u] = p.x;
            nn[u]  = __int_as_float(p.z);
        }
        #pragma unroll
        for (int u = 0; u < 8; ++u) gg[u] = hold[(size_t)idx[u] * 32 + dp];
        #pragma unroll
        for (int u = 0; u < 8; ++u) {
            a0 += nn[u] * bf_lo(gg[u]);
            a1 += nn[u] * bf_hi(gg[u]);
        }
    }
    unsigned sv = sebf[vp];
    float r0 = bf_lo(sv) + dv * a0;
    float r1 = bf_hi(sv) + dv * a1;
    r0 = (r0 > 0.f) ? r0 : 0.2f * r0;
    r1 = (r1 > 0.f) ? r1 : 0.2f * r1;
    hnew[vp] = pk_bf16(r0, r1);
}

// ---------------- z GEMM + BN stats (hsum = hb0+hb1+hb2+hb3 at staging) ----------------

__global__ __launch_bounds__(256) void k_zstats(const unsigned* __restrict__ hb0,
                                                const unsigned* __restrict__ hb1,
                                                const unsigned* __restrict__ hb2,
                                                const unsigned* __restrict__ hb3,
                                                const float* __restrict__ cfeat,
                                                const float* __restrict__ w1,
                                                const float* __restrict__ b1,
                                                float* __restrict__ z,
                                                float* __restrict__ stats) {
    __shared__ float ws[K1 * C1];    // 48 KB
    __shared__ float ut[128 * 49];   // 24.5 KB
    __shared__ float red[4][64];     // 1 KB
    for (int i = threadIdx.x; i < K1 * C1; i += 256) ws[i] = w1[i];
    int tid = threadIdx.x;
    int lane = tid & 63, wave = tid >> 6;
    int lr = lane >> 3, lc = lane & 7;
    int wr = wave >> 1, wc = wave & 1;
    int rbase = wr * 64 + lr * 8;
    int cbase = wc * 64 + lc * 8;
    float bA[8];
    #pragma unroll
    for (int j = 0; j < 8; ++j) bA[j] = b1[cbase + j];
    float s[8], q[8];
    #pragma unroll
    for (int j = 0; j < 8; ++j) { s[j] = 0.f; q[j] = 0.f; }

    for (int tile = blockIdx.x; tile < ZTILES; tile += gridDim.x) {
        int row0 = tile * 128;
        float acc[8][8];
        #pragma unroll
        for (int i = 0; i < 8; ++i)
            #pragma unroll
            for (int j = 0; j < 8; ++j) acc[i][j] = 0.f;
        for (int ch = 0; ch < 2; ++ch) {
            int kbase = ch * 48;
            __syncthreads();
            #pragma unroll
            for (int p = 0; p < 6; ++p) {
                int idx = p * 256 + tid;
                int row = idx / 12, kq = idx % 12;
                int gk = kbase + kq * 4;
                int gr = row0 + row;
                float f0 = 0.f, f1 = 0.f, f2 = 0.f, f3 = 0.f;
                if (gr < N_NODES) {
                    if (gk < HID) {
                        size_t o = (size_t)gr * 32 + (gk >> 1);
                        uint2 g0 = *(const uint2*)&hb0[o];
                        uint2 g1 = *(const uint2*)&hb1[o];
                        uint2 g2 = *(const uint2*)&hb2[o];
                        uint2 g3 = *(const uint2*)&hb3[o];
                        f0 = bf_lo(g0.x) + bf_lo(g1.x) + bf_lo(g2.x) + bf_lo(g3.x);
                        f1 = bf_hi(g0.x) + bf_hi(g1.x) + bf_hi(g2.x) + bf_hi(g3.x);
                        f2 = bf_lo(g0.y) + bf_lo(g1.y) + bf_lo(g2.y) + bf_lo(g3.y);
                        f3 = bf_hi(g0.y) + bf_hi(g1.y) + bf_hi(g2.y) + bf_hi(g3.y);
                    } else {
                        float4 v = *(const float4*)&cfeat[(size_t)gr * HIER + (gk - HID)];
                        f0 = v.x; f1 = v.y; f2 = v.z; f3 = v.w;
                    }
                }
                float* d = &ut[row * 49 + kq * 4];
                d[0] = f0; d[1] = f1; d[2] = f2; d[3] = f3;
            }
            __syncthreads();
            for (int k = 0; k < 48; ++k) {
                float u[8];
                #pragma unroll
                for (int i = 0; i < 8; ++i) u[i] = ut[(rbase + i) * 49 + k];
                const float* wrow = &ws[(kbase + k) * C1 + cbase];
                float4 wa = *(const float4*)&wrow[0];
                float4 wb = *(const float4*)&wrow[4];
                #pragma unroll
                for (int i = 0; i < 8; ++i) {
                    acc[i][0] += u[i] * wa.x; acc[i][1] += u[i] * wa.y;
                    acc[i][2] += u[i] * wa.z; acc[i][3] += u[i] * wa.w;
                    acc[i][4] += u[i] * wb.x; acc[i][5] += u[i] * wb.y;
                    acc[i][6] += u[i] * wb.z; acc[i][7] += u[i] * wb.w;
                }
            }
        }
        #pragma unroll
        for (int i = 0; i < 8; ++i) {
            int gr = row0 + rbase + i;
            if (gr < N_NODES) {
                float zz[8];
                #pragma unroll
                for (int j = 0; j < 8; ++j) {
                    zz[j] = acc[i][j] + bA[j];
                    s[j] += zz[j]; q[j] += zz[j] * zz[j];
                }
                *(float4*)&z[(size_t)gr * C1 + cbase] =
                    make_float4(zz[0], zz[1], zz[2], zz[3]);
                *(float4*)&z[(size_t)gr * C1 + cbase + 4] =
                    make_float4(zz[4], zz[5], zz[6], zz[7]);
            }
        }
    }

    #pragma unroll
    for (int j = 0; j < 8; ++j) {
        s[j] += __shfl_xor(s[j], 8); s[j] += __shfl_xor(s[j], 16); s[j] += __shfl_xor(s[j], 32);
        q[j] += __shfl_xor(q[j], 8); q[j] += __shfl_xor(q[j], 16); q[j] += __shfl_xor(q[j], 32);
    }
    __syncthreads();
    if (lr == 0) {
        #pragma unroll
        for (int j = 0; j < 8; ++j) red[wave][lc * 8 + j] = s[j];
    }
    __syncthreads();
    if (tid < 128) {
        int wc2 = tid >> 6, cl = tid & 63;
        atomicAdd(&stats[wc2 * 64 + cl], red[wc2][cl] + red[wc2 + 2][cl]);
    }
    __syncthreads();
    if (lr == 0) {
        #pragma unroll
        for (int j = 0; j < 8; ++j) red[wave][lc * 8 + j] = q[j];
    }
    __syncthreads();
    if (tid < 128) {
        int wc2 = tid >> 6, cl = tid & 63;
        atomicAdd(&stats[C1 + wc2 * 64 + cl], red[wc2][cl] + red[wc2 + 2][cl]);
    }
}

__global__ void k_ab(const float* __restrict__ stats, const float* __restrict__ gamma,
                     const float* __restrict__ beta, float* __restrict__ ab) {
    int t = threadIdx.x;
    if (t < C1) {
        float mu = stats[t] / (float)N_NODES;
        float var = stats[C1 + t] / (float)N_NODES - mu * mu;
        float inv = rsqrtf(var + BN_EPS);
        float a = gamma[t] * inv;
        ab[t] = a;
        ab[C1 + t] = beta[t] - mu * a;
    }
}

// ---------------- output: PReLU(BN(z)) @ w_out2 + b_out2 (streaming z) ----------------

__global__ __launch_bounds__(256) void k_out2(const float* __restrict__ z,
                                              const float* __restrict__ ab,
                                              const float* __restrict__ pa,
                                              const float* __restrict__ w2,
                                              const float* __restrict__ b2,
                                              float* __restrict__ out) {
    int lane = threadIdx.x & 63, wid = threadIdx.x >> 6;
    float w2a[NCLS], w2b[NCLS], bb[NCLS];
    #pragma unroll
    for (int j = 0; j < NCLS; ++j) {
        w2a[j] = w2[lane * NCLS + j];
        w2b[j] = w2[(64 + lane) * NCLS + j];
        bb[j] = b2[j];
    }
    float sa0 = ab[lane], sa1 = ab[64 + lane];
    float sb0 = ab[C1 + lane], sb1 = ab[C1 + 64 + lane];
    float alpha = pa[0];
    for (int v = blockIdx.x * 4 + wid; v < N_NODES; v += gridDim.x * 4) {
        float z0 = z[(size_t)v * C1 + lane];
        float z1 = z[(size_t)v * C1 + 64 + lane];
        float p0 = z0 * sa0 + sb0; p0 = (p0 > 0.f) ? p0 : alpha * p0;
        float p1 = z1 * sa1 + sb1; p1 = (p1 > 0.f) ? p1 : alpha * p1;
        float pj[NCLS];
        #pragma unroll
        for (int j = 0; j < NCLS; ++j) pj[j] = p0 * w2a[j] + p1 * w2b[j];
        #pragma unroll
        for (int j = 0; j < NCLS; ++j) {
            #pragma unroll
            for (int d = 32; d >= 1; d >>= 1) pj[j] += __shfl_xor(pj[j], d);
        }
        if (lane == 0) {
            #pragma unroll
            for (int j = 0; j < NCLS; ++j)
                out[(size_t)v * NCLS + j] = pj[j] + bb[j];
        }
    }
}

// ---------------- host ----------------

extern "C" void kernel_launch(void* const* d_in, const int* in_sizes, int n_in,
                              void* d_out, int out_size, void* d_ws, size_t ws_size,
                              hipStream_t stream) {
    const float* x      = (const float*)d_in[0];
    const float* e      = (const float*)d_in[1];
    const float* c      = (const float*)d_in[2];
    const float* w_node = (const float*)d_in[3];
    const float* b_node = (const float*)d_in[4];
    const float* w_edge = (const float*)d_in[5];
    const float* b_edge = (const float*)d_in[6];
    const float* w_out1 = (const float*)d_in[7];
    const float* b_out1 = (const float*)d_in[8];
    const float* gamma  = (const float*)d_in[9];
    const float* beta   = (const float*)d_in[10];
    const float* pa     = (const float*)d_in[11];
    const float* w_out2 = (const float*)d_in[12];
    const float* b_out2 = (const float*)d_in[13];
    const int*   ei     = (const int*)d_in[14];
    float* out = (float*)d_out;

    char* wsb = (char*)d_ws;
    // Region A (64MB): ebf [bf16 1M x 32] eid order; dead after k_agg3.
    //   Then sebf (12.8MB, packed bf16) at offset 0 (lives through layers);
    //   z f32 (51.2MB) at offset 12.8MB (written in zstats, after ebf is dead;
    //   does not overlap sebf). 12.8 + 51.2 = 64MB exactly.
    ushort*   ebf  = (ushort*)wsb;
    unsigned* sebf = (unsigned*)wsb;
    float*    z    = (float*)(wsb + 12800000);
    size_t off = (64000000 + 255) & ~(size_t)255;
    auto alloc = [&](size_t bytes) {
        void* p = wsb + off;
        off = (off + bytes + 255) & ~(size_t)255;
        return p;
    };
    int*      cnt      = (int*)alloc(4ull * N_NODES);
    int*      offs     = (int*)alloc(4ull * (N_NODES + 1));
    float*    dinv     = (float*)alloc(4ull * N_NODES);
    int*      bsum     = (int*)alloc(4ull * 128);
    int4*     epk      = (int4*)alloc(16ull * N_EDGES);          // packed CSR
    float*    agg      = (float*)alloc(4ull * N_NODES * EDIM);
    float*    wsumv    = (float*)alloc(4ull * N_NODES);
    float*    stats    = (float*)alloc(4ull * 256);
    float*    ab       = (float*)alloc(4ull * 256);
    unsigned* hb0      = (unsigned*)alloc(4ull * N_NODES * 32);  // bf16x2 packed
    unsigned* hb1      = (unsigned*)alloc(4ull * N_NODES * 32);
    unsigned* hb2      = (unsigned*)alloc(4ull * N_NODES * 32);
    unsigned* hb3      = (unsigned*)alloc(4ull * N_NODES * 32);

    hipMemsetAsync(cnt, 0, 4ull * N_NODES, stream);
    hipMemsetAsync(stats, 0, 4ull * 256, stream);

    k_count<<<(N_EDGES + 255) / 256, 256, 0, stream>>>(ei, cnt);
    k_scan1<<<SCAN_B, 1024, 0, stream>>>(cnt, offs, dinv, bsum);
    k_scan2<<<1, 1024, 0, stream>>>(bsum, SCAN_B);
    k_scan3<<<SCAN_B, 1024, 0, stream>>>(bsum, offs);
    hipMemsetAsync(cnt, 0, 4ull * N_NODES, stream);
    k_fill<<<(N_EDGES + 255) / 256, 256, 0, stream>>>(ei, offs, cnt, dinv, epk);

    // pure-stream bf16 convert (32M floats / 8 per thread = 15625 blocks)
    k_conv<<<15625, 256, 0, stream>>>((const float4*)e, (uint4*)ebf);
    k_agg3<<<N_NODES * 16 / 256, 256, 0, stream>>>((const unsigned*)ebf, epk,
                                                   offs, dinv, agg, wsumv);

    k_se<<<1280, 256, 0, stream>>>(agg, wsumv, w_edge, b_edge, sebf);  // over dead ebf
    k_h0t<<<HTILES, 256, 0, stream>>>(x, w_node, b_node, hb0);

    k_layer<<<N_NODES / 8, 256, 0, stream>>>(hb0, sebf, epk, offs, dinv, hb1);
    k_layer<<<N_NODES / 8, 256, 0, stream>>>(hb1, sebf, epk, offs, dinv, hb2);
    k_layer<<<N_NODES / 8, 256, 0, stream>>>(hb2, sebf, epk, offs, dinv, hb3);

    k_zstats<<<512, 256, 0, stream>>>(hb0, hb1, hb2, hb3, c, w_out1, b_out1, z, stats);
    k_ab<<<1, 128, 0, stream>>>(stats, gamma, beta, ab);
    k_out2<<<2048, 256, 0, stream>>>(z, ab, pa, w_out2, b_out2, out);
}

// Round 11
// 457.152 us; speedup vs baseline: 2.3113x; 1.0833x over previous
//
#include <hip/hip_runtime.h>
#include <math.h>

#define N_NODES 100000
#define N_EDGES 1000000
#define HID     64
#define HIER    32
#define NDIM    128
#define EDIM    32
#define K1      96    // HIER + HID
#define C1      128   // 2*HID
#define NCLS    10
#define BN_EPS  1e-5f
#define SCAN_B  98    // ceil(N_NODES/1024)
#define ZTILES  782   // ceil(N_NODES/128)
#define HTILES  391   // ceil(N_NODES/256)

// pack two f32 -> (bf16(a) | bf16(b)<<16), round-to-nearest-even
__device__ __forceinline__ unsigned pk_bf16(float a, float b) {
    unsigned ua = __float_as_uint(a);
    ua = (ua + 0x7FFFu + ((ua >> 16) & 1u)) >> 16;
    unsigned ub = __float_as_uint(b);
    ub = (ub + 0x7FFFu + ((ub >> 16) & 1u)) & 0xFFFF0000u;
    return ua | ub;
}
__device__ __forceinline__ float bf_lo(unsigned g) { return __uint_as_float(g << 16); }
__device__ __forceinline__ float bf_hi(unsigned g) { return __uint_as_float(g & 0xFFFF0000u); }

// ---------------- CSR build ----------------

__global__ void k_count(const int* __restrict__ ei, int* __restrict__ cnt) {
    int i = blockIdx.x * blockDim.x + threadIdx.x;
    if (i < N_EDGES) atomicAdd(&cnt[ei[N_EDGES + i]], 1);
}

__global__ void k_scan1(const int* __restrict__ cnt, int* __restrict__ offs,
                        float* __restrict__ dinv, int* __restrict__ bsum) {
    __shared__ int buf[2][1024];
    int t = threadIdx.x, b = blockIdx.x;
    int i = b * 1024 + t;
    int v = (i < N_NODES) ? cnt[i] : 0;
    buf[0][t] = v; __syncthreads();
    int pi = 0;
    for (int off = 1; off < 1024; off <<= 1) {
        int x = buf[pi][t];
        if (t >= off) x += buf[pi][t - off];
        buf[pi ^ 1][t] = x; __syncthreads(); pi ^= 1;
    }
    int incl = buf[pi][t];
    if (i < N_NODES) {
        offs[i] = incl - v;
        dinv[i] = rsqrtf((float)(v + 1));
    }
    if (t == 1023) bsum[b] = incl;
}

__global__ void k_scan2(int* __restrict__ bsum, int nb) {
    __shared__ int buf[2][1024];
    int t = threadIdx.x;
    int v = (t < nb) ? bsum[t] : 0;
    buf[0][t] = v; __syncthreads();
    int pi = 0;
    for (int off = 1; off < 1024; off <<= 1) {
        int x = buf[pi][t];
        if (t >= off) x += buf[pi][t - off];
        buf[pi ^ 1][t] = x; __syncthreads(); pi ^= 1;
    }
    int incl = buf[pi][t];
    if (t < nb) bsum[t] = incl - v;
}

__global__ void k_scan3(const int* __restrict__ bsum, int* __restrict__ offs) {
    int b = blockIdx.x;
    int i = b * 1024 + threadIdx.x;
    if (i < N_NODES) offs[i] += bsum[b];
    if (i == 0) offs[N_NODES] = N_EDGES;
}

// packed CSR record: {src, eid, norm_bits, pad} -> ONE 16B scattered store/edge
__global__ void k_fill(const int* __restrict__ ei, const int* __restrict__ offs,
                       int* __restrict__ cursor, const float* __restrict__ dinv,
                       int4* __restrict__ epk) {
    int i = blockIdx.x * blockDim.x + threadIdx.x;
    if (i >= N_EDGES) return;
    int s = ei[i], d = ei[N_EDGES + i];
    int pos = offs[d] + atomicAdd(&cursor[d], 1);
    epk[pos] = make_int4(s, i, __float_as_int(dinv[s]), 0);
}

// ---------------- pure streaming convert: ebf = bf16(e), eid order ----------------

__global__ __launch_bounds__(256) void k_conv(const float4* __restrict__ e4,
                                              uint4* __restrict__ eb4) {
    int i = blockIdx.x * 256 + threadIdx.x;     // 4M threads, 8 floats each
    float4 a = e4[(size_t)2 * i];
    float4 b = e4[(size_t)2 * i + 1];
    uint4 pk;
    pk.x = pk_bf16(a.x, a.y); pk.y = pk_bf16(a.z, a.w);
    pk.z = pk_bf16(b.x, b.y); pk.w = pk_bf16(b.z, b.w);
    eb4[i] = pk;
}

// ---------------- edge aggregation: quarter-wave per node ----------------
// agg[v] = dinv[v] * sum norm_e * ebf[eid]; wsum[v] = dinv[v] * sum norm_e.

__global__ __launch_bounds__(256) void k_agg3(const unsigned* __restrict__ ebfu,
                                              const int4* __restrict__ epk,
                                              const int* __restrict__ offs,
                                              const float* __restrict__ dinv,
                                              float* __restrict__ agg,
                                              float* __restrict__ wsumv) {
    int v = (blockIdx.x * 256 + threadIdx.x) >> 4;
    if (v >= N_NODES) return;
    int q = threadIdx.x & 15;                  // uint index = dims 2q, 2q+1
    int start = offs[v], end = offs[v + 1];
    float ax = 0.f, ay = 0.f, wacc = 0.f;
    for (int i = start; i < end; i += 4) {
        int i1 = i + 1, i2 = i + 2, i3 = i + 3;
        int4 p0 = epk[i];
        int4 p1 = (i1 < end) ? epk[i1] : make_int4(0, 0, 0, 0);
        int4 p2 = (i2 < end) ? epk[i2] : make_int4(0, 0, 0, 0);
        int4 p3 = (i3 < end) ? epk[i3] : make_int4(0, 0, 0, 0);
        float n0 = __int_as_float(p0.z), n1 = __int_as_float(p1.z);
        float n2 = __int_as_float(p2.z), n3 = __int_as_float(p3.z);
        unsigned g0 = ebfu[(size_t)p0.y * 16 + q];
        unsigned g1 = ebfu[(size_t)p1.y * 16 + q];
        unsigned g2 = ebfu[(size_t)p2.y * 16 + q];
        unsigned g3 = ebfu[(size_t)p3.y * 16 + q];
        ax += n0 * bf_lo(g0) + n1 * bf_lo(g1) + n2 * bf_lo(g2) + n3 * bf_lo(g3);
        ay += n0 * bf_hi(g0) + n1 * bf_hi(g1) + n2 * bf_hi(g2) + n3 * bf_hi(g3);
        wacc += n0 + n1 + n2 + n3;
    }
    float dv = dinv[v];
    *(float2*)&agg[(size_t)v * EDIM + q * 2] = make_float2(dv * ax, dv * ay);
    if (q == 0) wsumv[v] = dv * wacc;
}

// ---------------- node encoder (tiled GEMM): hb0 = bf16(x @ w_node + b) ----------------

__global__ __launch_bounds__(256) void k_h0t(const float* __restrict__ x,
                                             const float* __restrict__ w,
                                             const float* __restrict__ bias,
                                             unsigned* __restrict__ hbf) {
    __shared__ float ws[NDIM * HID];   // 32 KB
    __shared__ float xt[256 * 33];     // 33.8 KB
    for (int i = threadIdx.x; i < NDIM * HID; i += 256) ws[i] = w[i];
    int tid = threadIdx.x;
    int lane = tid & 63, wave = tid >> 6;
    int lr = lane >> 3, lc = lane & 7;
    int rbase = wave * 64 + lr * 8;
    int cbase = lc * 8;
    float bA[8];
    #pragma unroll
    for (int j = 0; j < 8; ++j) bA[j] = bias[cbase + j];
    for (int tile = blockIdx.x; tile < HTILES; tile += gridDim.x) {
        int row0 = tile * 256;
        float acc[8][8];
        #pragma unroll
        for (int i = 0; i < 8; ++i)
            #pragma unroll
            for (int j = 0; j < 8; ++j) acc[i][j] = 0.f;
        for (int ch = 0; ch < 4; ++ch) {
            __syncthreads();
            #pragma unroll
            for (int p = 0; p < 8; ++p) {
                int idx = p * 256 + tid;
                int row = idx >> 3, kq = idx & 7;
                int gk = ch * 32 + kq * 4;
                float4 v = make_float4(0.f, 0.f, 0.f, 0.f);
                int gr = row0 + row;
                if (gr < N_NODES) v = *(const float4*)&x[(size_t)gr * NDIM + gk];
                float* d = &xt[row * 33 + kq * 4];
                d[0] = v.x; d[1] = v.y; d[2] = v.z; d[3] = v.w;
            }
            __syncthreads();
            for (int k = 0; k < 32; ++k) {
                float u[8];
                #pragma unroll
                for (int i = 0; i < 8; ++i) u[i] = xt[(rbase + i) * 33 + k];
                const float* wrow = &ws[(ch * 32 + k) * HID + cbase];
                float4 wa = *(const float4*)&wrow[0];
                float4 wb = *(const float4*)&wrow[4];
                #pragma unroll
                for (int i = 0; i < 8; ++i) {
                    acc[i][0] += u[i] * wa.x; acc[i][1] += u[i] * wa.y;
                    acc[i][2] += u[i] * wa.z; acc[i][3] += u[i] * wa.w;
                    acc[i][4] += u[i] * wb.x; acc[i][5] += u[i] * wb.y;
                    acc[i][6] += u[i] * wb.z; acc[i][7] += u[i] * wb.w;
                }
            }
        }
        #pragma unroll
        for (int i = 0; i < 8; ++i) {
            int gr = row0 + rbase + i;
            if (gr < N_NODES) {
                uint4 pk;
                pk.x = pk_bf16(acc[i][0] + bA[0], acc[i][1] + bA[1]);
                pk.y = pk_bf16(acc[i][2] + bA[2], acc[i][3] + bA[3]);
                pk.z = pk_bf16(acc[i][4] + bA[4], acc[i][5] + bA[5]);
                pk.w = pk_bf16(acc[i][6] + bA[6], acc[i][7] + bA[7]);
                *(uint4*)&hbf[(size_t)gr * 32 + (cbase >> 1)] = pk;
            }
        }
    }
}

// ---------------- s_e = bf16(agg @ w_edge + wsum * b_edge), packed pairs ----------------

__global__ __launch_bounds__(256) void k_se(const float* __restrict__ agg,
                                            const float* __restrict__ wsumv,
                                            const float* __restrict__ we,
                                            const float* __restrict__ be,
                                            unsigned* __restrict__ sebf) {
    int lane = threadIdx.x & 63, wid = threadIdx.x >> 6;
    float wreg[EDIM];
    #pragma unroll
    for (int k = 0; k < EDIM; ++k) wreg[k] = we[k * HID + lane];
    float bl = be[lane];
    for (int v = blockIdx.x * 4 + wid; v < N_NODES; v += gridDim.x * 4) {
        const float4* ar = (const float4*)(agg + (size_t)v * EDIM);
        float acc = wsumv[v] * bl;
        #pragma unroll
        for (int k4 = 0; k4 < EDIM / 4; ++k4) {
            float4 av = ar[k4];
            int k = k4 * 4;
            acc += av.x * wreg[k + 0] + av.y * wreg[k + 1] +
                   av.z * wreg[k + 2] + av.w * wreg[k + 3];
        }
        float partner = __shfl_xor(acc, 1);
        if ((lane & 1) == 0)
            sebf[(size_t)v * 32 + (lane >> 1)] = pk_bf16(acc, partner);
    }
}

// ---------------- one GCN layer (pull; bf16 h + bf16 se, packed CSR, unroll 8) ----------------

__global__ __launch_bounds__(256) void k_layer(const unsigned* __restrict__ hold,
                                               const unsigned* __restrict__ sebf,
                                               const int4* __restrict__ epk,
                                               const int* __restrict__ offs,
                                               const float* __restrict__ dinv,
                                               unsigned* __restrict__ hnew) {
    int gw = (blockIdx.x * 256 + threadIdx.x) >> 6;
    int lane = threadIdx.x & 63;
    int half = lane >> 5, dp = lane & 31;          // dim pair 2*dp, 2*dp+1
    int v = gw * 2 + half;
    if (v >= N_NODES) return;
    int start = offs[v], end = offs[v + 1];
    float dv = dinv[v];
    size_t vp = (size_t)v * 32 + dp;
    unsigned hv = hold[vp];
    float a0 = dv * bf_lo(hv), a1 = dv * bf_hi(hv);   // self loop (x dv again below)
    for (int i = start; i < end; i += 8) {
        int idx[8]; float nn[8]; unsigned gg[8];
        #pragma unroll
        for (int u = 0; u < 8; ++u) {
            int ii = i + u;
            int4 p = (ii < end) ? epk[ii] : make_int4(0, 0, 0, 0);
            idx[u] = p.x;
            nn[u]  = __int_as_float(p.z);
        }
        #pragma unroll
        for (int u = 0; u < 8; ++u) gg[u] = hold[(size_t)idx[u] * 32 + dp];
        #pragma unroll
        for (int u = 0; u < 8; ++u) {
            a0 += nn[u] * bf_lo(gg[u]);
            a1 += nn[u] * bf_hi(gg[u]);
        }
    }
    unsigned sv = sebf[vp];
    float r0 = bf_lo(sv) + dv * a0;
    float r1 = bf_hi(sv) + dv * a1;
    r0 = (r0 > 0.f) ? r0 : 0.2f * r0;
    r1 = (r1 > 0.f) ? r1 : 0.2f * r1;
    hnew[vp] = pk_bf16(r0, r1);
}

// ---------------- z GEMM + BN stats (hsum = hb0+hb1+hb2+hb3 at staging; z packed bf16) ----------------

__global__ __launch_bounds__(256) void k_zstats(const unsigned* __restrict__ hb0,
                                                const unsigned* __restrict__ hb1,
                                                const unsigned* __restrict__ hb2,
                                                const unsigned* __restrict__ hb3,
                                                const float* __restrict__ cfeat,
                                                const float* __restrict__ w1,
                                                const float* __restrict__ b1,
                                                unsigned* __restrict__ zbf,
                                                float* __restrict__ stats) {
    __shared__ float ws[K1 * C1];    // 48 KB
    __shared__ float ut[128 * 49];   // 24.5 KB
    __shared__ float red[4][64];     // 1 KB
    for (int i = threadIdx.x; i < K1 * C1; i += 256) ws[i] = w1[i];
    int tid = threadIdx.x;
    int lane = tid & 63, wave = tid >> 6;
    int lr = lane >> 3, lc = lane & 7;
    int wr = wave >> 1, wc = wave & 1;
    int rbase = wr * 64 + lr * 8;
    int cbase = wc * 64 + lc * 8;
    float bA[8];
    #pragma unroll
    for (int j = 0; j < 8; ++j) bA[j] = b1[cbase + j];
    float s[8], q[8];
    #pragma unroll
    for (int j = 0; j < 8; ++j) { s[j] = 0.f; q[j] = 0.f; }

    for (int tile = blockIdx.x; tile < ZTILES; tile += gridDim.x) {
        int row0 = tile * 128;
        float acc[8][8];
        #pragma unroll
        for (int i = 0; i < 8; ++i)
            #pragma unroll
            for (int j = 0; j < 8; ++j) acc[i][j] = 0.f;
        for (int ch = 0; ch < 2; ++ch) {
            int kbase = ch * 48;
            __syncthreads();
            #pragma unroll
            for (int p = 0; p < 6; ++p) {
                int idx = p * 256 + tid;
                int row = idx / 12, kq = idx % 12;
                int gk = kbase + kq * 4;
                int gr = row0 + row;
                float f0 = 0.f, f1 = 0.f, f2 = 0.f, f3 = 0.f;
                if (gr < N_NODES) {
                    if (gk < HID) {
                        size_t o = (size_t)gr * 32 + (gk >> 1);
                        uint2 g0 = *(const uint2*)&hb0[o];
                        uint2 g1 = *(const uint2*)&hb1[o];
                        uint2 g2 = *(const uint2*)&hb2[o];
                        uint2 g3 = *(const uint2*)&hb3[o];
                        f0 = bf_lo(g0.x) + bf_lo(g1.x) + bf_lo(g2.x) + bf_lo(g3.x);
                        f1 = bf_hi(g0.x) + bf_hi(g1.x) + bf_hi(g2.x) + bf_hi(g3.x);
                        f2 = bf_lo(g0.y) + bf_lo(g1.y) + bf_lo(g2.y) + bf_lo(g3.y);
                        f3 = bf_hi(g0.y) + bf_hi(g1.y) + bf_hi(g2.y) + bf_hi(g3.y);
                    } else {
                        float4 v = *(const float4*)&cfeat[(size_t)gr * HIER + (gk - HID)];
                        f0 = v.x; f1 = v.y; f2 = v.z; f3 = v.w;
                    }
                }
                float* d = &ut[row * 49 + kq * 4];
                d[0] = f0; d[1] = f1; d[2] = f2; d[3] = f3;
            }
            __syncthreads();
            for (int k = 0; k < 48; ++k) {
                float u[8];
                #pragma unroll
                for (int i = 0; i < 8; ++i) u[i] = ut[(rbase + i) * 49 + k];
                const float* wrow = &ws[(kbase + k) * C1 + cbase];
                float4 wa = *(const float4*)&wrow[0];
                float4 wb = *(const float4*)&wrow[4];
                #pragma unroll
                for (int i = 0; i < 8; ++i) {
                    acc[i][0] += u[i] * wa.x; acc[i][1] += u[i] * wa.y;
                    acc[i][2] += u[i] * wa.z; acc[i][3] += u[i] * wa.w;
                    acc[i][4] += u[i] * wb.x; acc[i][5] += u[i] * wb.y;
                    acc[i][6] += u[i] * wb.z; acc[i][7] += u[i] * wb.w;
                }
            }
        }
        #pragma unroll
        for (int i = 0; i < 8; ++i) {
            int gr = row0 + rbase + i;
            if (gr < N_NODES) {
                float zz[8];
                #pragma unroll
                for (int j = 0; j < 8; ++j) {
                    zz[j] = acc[i][j] + bA[j];
                    s[j] += zz[j]; q[j] += zz[j] * zz[j];
                }
                uint4 pk;
                pk.x = pk_bf16(zz[0], zz[1]); pk.y = pk_bf16(zz[2], zz[3]);
                pk.z = pk_bf16(zz[4], zz[5]); pk.w = pk_bf16(zz[6], zz[7]);
                *(uint4*)&zbf[(size_t)gr * 64 + (cbase >> 1)] = pk;
            }
        }
    }

    #pragma unroll
    for (int j = 0; j < 8; ++j) {
        s[j] += __shfl_xor(s[j], 8); s[j] += __shfl_xor(s[j], 16); s[j] += __shfl_xor(s[j], 32);
        q[j] += __shfl_xor(q[j], 8); q[j] += __shfl_xor(q[j], 16); q[j] += __shfl_xor(q[j], 32);
    }
    __syncthreads();
    if (lr == 0) {
        #pragma unroll
        for (int j = 0; j < 8; ++j) red[wave][lc * 8 + j] = s[j];
    }
    __syncthreads();
    if (tid < 128) {
        int wc2 = tid >> 6, cl = tid & 63;
        atomicAdd(&stats[wc2 * 64 + cl], red[wc2][cl] + red[wc2 + 2][cl]);
    }
    __syncthreads();
    if (lr == 0) {
        #pragma unroll
        for (int j = 0; j < 8; ++j) red[wave][lc * 8 + j] = q[j];
    }
    __syncthreads();
    if (tid < 128) {
        int wc2 = tid >> 6, cl = tid & 63;
        atomicAdd(&stats[C1 + wc2 * 64 + cl], red[wc2][cl] + red[wc2 + 2][cl]);
    }
}

__global__ void k_ab(const float* __restrict__ stats, const float* __restrict__ gamma,
                     const float* __restrict__ beta, float* __restrict__ ab) {
    int t = threadIdx.x;
    if (t < C1) {
        float mu = stats[t] / (float)N_NODES;
        float var = stats[C1 + t] / (float)N_NODES - mu * mu;
        float inv = rsqrtf(var + BN_EPS);
        float a = gamma[t] * inv;
        ab[t] = a;
        ab[C1 + t] = beta[t] - mu * a;
    }
}

// ---------------- output: thread-per-node, scalar-broadcast weights, NO shuffles ----------------
// out[v] = PReLU(zbf[v]*a+b) @ w2 + b2. All ab/w2/b2 indices are wave-uniform ->
// compiler emits s_load (constant cache); per node: 16 x uint4 z loads + ~1.5k VALU.

__global__ __launch_bounds__(256) void k_out3(const unsigned* __restrict__ zbf,
                                              const float* __restrict__ ab,
                                              const float* __restrict__ pa,
                                              const float* __restrict__ w2,
                                              const float* __restrict__ b2,
                                              float* __restrict__ out) {
    int v = blockIdx.x * 256 + threadIdx.x;
    if (v >= N_NODES) return;
    float alpha = pa[0];
    float acc[NCLS];
    #pragma unroll
    for (int j = 0; j < NCLS; ++j) acc[j] = b2[j];
    const uint4* zr = (const uint4*)(zbf + (size_t)v * 64);
    #pragma unroll
    for (int pk4 = 0; pk4 < 16; ++pk4) {
        uint4 g = zr[pk4];
        unsigned gw[4] = {g.x, g.y, g.z, g.w};
        #pragma unroll
        for (int w = 0; w < 4; ++w) {
            int d0 = pk4 * 8 + w * 2;
            float p0 = bf_lo(gw[w]) * ab[d0]     + ab[C1 + d0];
            float p1 = bf_hi(gw[w]) * ab[d0 + 1] + ab[C1 + d0 + 1];
            p0 = (p0 > 0.f) ? p0 : alpha * p0;
            p1 = (p1 > 0.f) ? p1 : alpha * p1;
            #pragma unroll
            for (int j = 0; j < NCLS; ++j)
                acc[j] += p0 * w2[d0 * NCLS + j] + p1 * w2[(d0 + 1) * NCLS + j];
        }
    }
    #pragma unroll
    for (int j = 0; j < NCLS; ++j) out[(size_t)v * NCLS + j] = acc[j];
}

// ---------------- host ----------------

extern "C" void kernel_launch(void* const* d_in, const int* in_sizes, int n_in,
                              void* d_out, int out_size, void* d_ws, size_t ws_size,
                              hipStream_t stream) {
    const float* x      = (const float*)d_in[0];
    const float* e      = (const float*)d_in[1];
    const float* c      = (const float*)d_in[2];
    const float* w_node = (const float*)d_in[3];
    const float* b_node = (const float*)d_in[4];
    const float* w_edge = (const float*)d_in[5];
    const float* b_edge = (const float*)d_in[6];
    const float* w_out1 = (const float*)d_in[7];
    const float* b_out1 = (const float*)d_in[8];
    const float* gamma  = (const float*)d_in[9];
    const float* beta   = (const float*)d_in[10];
    const float* pa     = (const float*)d_in[11];
    const float* w_out2 = (const float*)d_in[12];
    const float* b_out2 = (const float*)d_in[13];
    const int*   ei     = (const int*)d_in[14];
    float* out = (float*)d_out;

    char* wsb = (char*)d_ws;
    // Region A (64MB): ebf [bf16 1M x 32] eid order; dead after k_agg3.
    //   Then sebf (12.8MB, packed bf16) at offset 0 (lives through layers);
    //   zbf (25.6MB, packed bf16) at offset 12.8MB (written in zstats, after
    //   ebf is dead; does not overlap sebf). 12.8 + 25.6 = 38.4MB < 64MB.
    ushort*   ebf  = (ushort*)wsb;
    unsigned* sebf = (unsigned*)wsb;
    unsigned* zbf  = (unsigned*)(wsb + 12800000);
    size_t off = (64000000 + 255) & ~(size_t)255;
    auto alloc = [&](size_t bytes) {
        void* p = wsb + off;
        off = (off + bytes + 255) & ~(size_t)255;
        return p;
    };
    int*      cnt      = (int*)alloc(4ull * N_NODES);
    int*      offs     = (int*)alloc(4ull * (N_NODES + 1));
    float*    dinv     = (float*)alloc(4ull * N_NODES);
    int*      bsum     = (int*)alloc(4ull * 128);
    int4*     epk      = (int4*)alloc(16ull * N_EDGES);          // packed CSR
    float*    agg      = (float*)alloc(4ull * N_NODES * EDIM);
    float*    wsumv    = (float*)alloc(4ull * N_NODES);
    float*    stats    = (float*)alloc(4ull * 256);
    float*    ab       = (float*)alloc(4ull * 256);
    unsigned* hb0      = (unsigned*)alloc(4ull * N_NODES * 32);  // bf16x2 packed
    unsigned* hb1      = (unsigned*)alloc(4ull * N_NODES * 32);
    unsigned* hb2      = (unsigned*)alloc(4ull * N_NODES * 32);
    unsigned* hb3      = (unsigned*)alloc(4ull * N_NODES * 32);

    hipMemsetAsync(cnt, 0, 4ull * N_NODES, stream);
    hipMemsetAsync(stats, 0, 4ull * 256, stream);

    k_count<<<(N_EDGES + 255) / 256, 256, 0, stream>>>(ei, cnt);
    k_scan1<<<SCAN_B, 1024, 0, stream>>>(cnt, offs, dinv, bsum);
    k_scan2<<<1, 1024, 0, stream>>>(bsum, SCAN_B);
    k_scan3<<<SCAN_B, 1024, 0, stream>>>(bsum, offs);
    hipMemsetAsync(cnt, 0, 4ull * N_NODES, stream);
    k_fill<<<(N_EDGES + 255) / 256, 256, 0, stream>>>(ei, offs, cnt, dinv, epk);

    // pure-stream bf16 convert (32M floats / 8 per thread = 15625 blocks)
    k_conv<<<15625, 256, 0, stream>>>((const float4*)e, (uint4*)ebf);
    k_agg3<<<N_NODES * 16 / 256, 256, 0, stream>>>((const unsigned*)ebf, epk,
                                                   offs, dinv, agg, wsumv);

    k_se<<<1280, 256, 0, stream>>>(agg, wsumv, w_edge, b_edge, sebf);  // over dead ebf
    k_h0t<<<HTILES, 256, 0, stream>>>(x, w_node, b_node, hb0);

    k_layer<<<N_NODES / 8, 256, 0, stream>>>(hb0, sebf, epk, offs, dinv, hb1);
    k_layer<<<N_NODES / 8, 256, 0, stream>>>(hb1, sebf, epk, offs, dinv, hb2);
    k_layer<<<N_NODES / 8, 256, 0, stream>>>(hb2, sebf, epk, offs, dinv, hb3);

    k_zstats<<<512, 256, 0, stream>>>(hb0, hb1, hb2, hb3, c, w_out1, b_out1, zbf, stats);
    k_ab<<<1, 128, 0, stream>>>(stats, gamma, beta, ab);
    k_out3<<<(N_NODES + 255) / 256, 256, 0, stream>>>(zbf, ab, pa, w_out2, b_out2, out);
}

// Round 12
// 455.112 us; speedup vs baseline: 2.3217x; 1.0045x over previous
//
#include <hip/hip_runtime.h>
#include <math.h>

#define N_NODES 100000
#define N_EDGES 1000000
#define HID     64
#define HIER    32
#define NDIM    128
#define EDIM    32
#define K1      96    // HIER + HID
#define C1      128   // 2*HID
#define NCLS    10
#define BN_EPS  1e-5f
#define SCAN_B  98    // ceil(N_NODES/1024)
#define ZTILES  782   // ceil(N_NODES/128)
#define HTILES2 782   // ceil(N_NODES/128)

// pack two f32 -> (bf16(a) | bf16(b)<<16), round-to-nearest-even
__device__ __forceinline__ unsigned pk_bf16(float a, float b) {
    unsigned ua = __float_as_uint(a);
    ua = (ua + 0x7FFFu + ((ua >> 16) & 1u)) >> 16;
    unsigned ub = __float_as_uint(b);
    ub = (ub + 0x7FFFu + ((ub >> 16) & 1u)) & 0xFFFF0000u;
    return ua | ub;
}
__device__ __forceinline__ float bf_lo(unsigned g) { return __uint_as_float(g << 16); }
__device__ __forceinline__ float bf_hi(unsigned g) { return __uint_as_float(g & 0xFFFF0000u); }

// ---------------- CSR build ----------------

__global__ void k_count(const int* __restrict__ ei, int* __restrict__ cnt) {
    int i = blockIdx.x * blockDim.x + threadIdx.x;
    if (i < N_EDGES) atomicAdd(&cnt[ei[N_EDGES + i]], 1);
}

__global__ void k_scan1(const int* __restrict__ cnt, int* __restrict__ offs,
                        float* __restrict__ dinv, int* __restrict__ bsum) {
    __shared__ int buf[2][1024];
    int t = threadIdx.x, b = blockIdx.x;
    int i = b * 1024 + t;
    int v = (i < N_NODES) ? cnt[i] : 0;
    buf[0][t] = v; __syncthreads();
    int pi = 0;
    for (int off = 1; off < 1024; off <<= 1) {
        int x = buf[pi][t];
        if (t >= off) x += buf[pi][t - off];
        buf[pi ^ 1][t] = x; __syncthreads(); pi ^= 1;
    }
    int incl = buf[pi][t];
    if (i < N_NODES) {
        offs[i] = incl - v;
        dinv[i] = rsqrtf((float)(v + 1));
    }
    if (t == 1023) bsum[b] = incl;
}

__global__ void k_scan2(int* __restrict__ bsum, int nb) {
    __shared__ int buf[2][1024];
    int t = threadIdx.x;
    int v = (t < nb) ? bsum[t] : 0;
    buf[0][t] = v; __syncthreads();
    int pi = 0;
    for (int off = 1; off < 1024; off <<= 1) {
        int x = buf[pi][t];
        if (t >= off) x += buf[pi][t - off];
        buf[pi ^ 1][t] = x; __syncthreads(); pi ^= 1;
    }
    int incl = buf[pi][t];
    if (t < nb) bsum[t] = incl - v;
}

__global__ void k_scan3(const int* __restrict__ bsum, int* __restrict__ offs) {
    int b = blockIdx.x;
    int i = b * 1024 + threadIdx.x;
    if (i < N_NODES) offs[i] += bsum[b];
    if (i == 0) offs[N_NODES] = N_EDGES;
}

// packed CSR record: {src, eid, norm_bits, pad} -> ONE 16B scattered store/edge
__global__ void k_fill(const int* __restrict__ ei, const int* __restrict__ offs,
                       int* __restrict__ cursor, const float* __restrict__ dinv,
                       int4* __restrict__ epk) {
    int i = blockIdx.x * blockDim.x + threadIdx.x;
    if (i >= N_EDGES) return;
    int s = ei[i], d = ei[N_EDGES + i];
    int pos = offs[d] + atomicAdd(&cursor[d], 1);
    epk[pos] = make_int4(s, i, __float_as_int(dinv[s]), 0);
}

// ---------------- pure streaming convert: ebf = bf16(e), eid order ----------------

__global__ __launch_bounds__(256) void k_conv(const float4* __restrict__ e4,
                                              uint4* __restrict__ eb4) {
    int i = blockIdx.x * 256 + threadIdx.x;     // 4M threads, 8 floats each
    float4 a = e4[(size_t)2 * i];
    float4 b = e4[(size_t)2 * i + 1];
    uint4 pk;
    pk.x = pk_bf16(a.x, a.y); pk.y = pk_bf16(a.z, a.w);
    pk.z = pk_bf16(b.x, b.y); pk.w = pk_bf16(b.z, b.w);
    eb4[i] = pk;
}

// ---------------- edge aggregation: quarter-wave per node ----------------

__global__ __launch_bounds__(256) void k_agg3(const unsigned* __restrict__ ebfu,
                                              const int4* __restrict__ epk,
                                              const int* __restrict__ offs,
                                              const float* __restrict__ dinv,
                                              float* __restrict__ agg,
                                              float* __restrict__ wsumv) {
    int v = (blockIdx.x * 256 + threadIdx.x) >> 4;
    if (v >= N_NODES) return;
    int q = threadIdx.x & 15;                  // uint index = dims 2q, 2q+1
    int start = offs[v], end = offs[v + 1];
    float ax = 0.f, ay = 0.f, wacc = 0.f;
    for (int i = start; i < end; i += 4) {
        int i1 = i + 1, i2 = i + 2, i3 = i + 3;
        int4 p0 = epk[i];
        int4 p1 = (i1 < end) ? epk[i1] : make_int4(0, 0, 0, 0);
        int4 p2 = (i2 < end) ? epk[i2] : make_int4(0, 0, 0, 0);
        int4 p3 = (i3 < end) ? epk[i3] : make_int4(0, 0, 0, 0);
        float n0 = __int_as_float(p0.z), n1 = __int_as_float(p1.z);
        float n2 = __int_as_float(p2.z), n3 = __int_as_float(p3.z);
        unsigned g0 = ebfu[(size_t)p0.y * 16 + q];
        unsigned g1 = ebfu[(size_t)p1.y * 16 + q];
        unsigned g2 = ebfu[(size_t)p2.y * 16 + q];
        unsigned g3 = ebfu[(size_t)p3.y * 16 + q];
        ax += n0 * bf_lo(g0) + n1 * bf_lo(g1) + n2 * bf_lo(g2) + n3 * bf_lo(g3);
        ay += n0 * bf_hi(g0) + n1 * bf_hi(g1) + n2 * bf_hi(g2) + n3 * bf_hi(g3);
        wacc += n0 + n1 + n2 + n3;
    }
    float dv = dinv[v];
    *(float2*)&agg[(size_t)v * EDIM + q * 2] = make_float2(dv * ax, dv * ay);
    if (q == 0) wsumv[v] = dv * wacc;
}

// ---------------- node encoder (tiled GEMM, bf16 W in LDS): hb0 = bf16(x @ w_node + b) ----
// 128-row tiles (grid 782 -> 3-4 blocks/CU); W packed bf16 [128][36] (conflict-free b128);
// thread tile 4 rows x 8 cols.

__global__ __launch_bounds__(256) void k_h0t2(const float* __restrict__ x,
                                              const float* __restrict__ w,
                                              const float* __restrict__ bias,
                                              unsigned* __restrict__ hbf) {
    __shared__ unsigned wpk[NDIM * 36];  // 18.4 KB: row k -> 32 packed cols + pad
    __shared__ float xt[128 * 33];       // 16.9 KB
    for (int i = threadIdx.x; i < NDIM * 32; i += 256) {
        int k = i >> 5, j = i & 31;
        wpk[k * 36 + j] = pk_bf16(w[k * HID + 2 * j], w[k * HID + 2 * j + 1]);
    }
    int tid = threadIdx.x;
    int lane = tid & 63, wave = tid >> 6;
    int lr = lane >> 3, lc = lane & 7;
    int rbase = wave * 32 + lr * 4;      // 4 rows per thread
    int cbase = lc * 8;                  // 8 cols per thread
    float bA[8];
    #pragma unroll
    for (int j = 0; j < 8; ++j) bA[j] = bias[cbase + j];
    for (int tile = blockIdx.x; tile < HTILES2; tile += gridDim.x) {
        int row0 = tile * 128;
        float acc[4][8];
        #pragma unroll
        for (int i = 0; i < 4; ++i)
            #pragma unroll
            for (int j = 0; j < 8; ++j) acc[i][j] = 0.f;
        for (int ch = 0; ch < 4; ++ch) {
            __syncthreads();
            #pragma unroll
            for (int p = 0; p < 4; ++p) {
                int idx = p * 256 + tid;
                int row = idx >> 3, kq = idx & 7;
                int gk = ch * 32 + kq * 4;
                float4 v = make_float4(0.f, 0.f, 0.f, 0.f);
                int gr = row0 + row;
                if (gr < N_NODES) v = *(const float4*)&x[(size_t)gr * NDIM + gk];
                float* d = &xt[row * 33 + kq * 4];
                d[0] = v.x; d[1] = v.y; d[2] = v.z; d[3] = v.w;
            }
            __syncthreads();
            for (int k = 0; k < 32; ++k) {
                float u[4];
                #pragma unroll
                for (int i = 0; i < 4; ++i) u[i] = xt[(rbase + i) * 33 + k];
                uint4 wp = *(const uint4*)&wpk[(ch * 32 + k) * 36 + lc * 4];
                float wv[8];
                wv[0] = bf_lo(wp.x); wv[1] = bf_hi(wp.x);
                wv[2] = bf_lo(wp.y); wv[3] = bf_hi(wp.y);
                wv[4] = bf_lo(wp.z); wv[5] = bf_hi(wp.z);
                wv[6] = bf_lo(wp.w); wv[7] = bf_hi(wp.w);
                #pragma unroll
                for (int i = 0; i < 4; ++i)
                    #pragma unroll
                    for (int j = 0; j < 8; ++j) acc[i][j] += u[i] * wv[j];
            }
        }
        #pragma unroll
        for (int i = 0; i < 4; ++i) {
            int gr = row0 + rbase + i;
            if (gr < N_NODES) {
                uint4 pk;
                pk.x = pk_bf16(acc[i][0] + bA[0], acc[i][1] + bA[1]);
                pk.y = pk_bf16(acc[i][2] + bA[2], acc[i][3] + bA[3]);
                pk.z = pk_bf16(acc[i][4] + bA[4], acc[i][5] + bA[5]);
                pk.w = pk_bf16(acc[i][6] + bA[6], acc[i][7] + bA[7]);
                *(uint4*)&hbf[(size_t)gr * 32 + (cbase >> 1)] = pk;
            }
        }
    }
}

// ---------------- s_e = bf16(agg @ w_edge + wsum * b_edge), packed pairs ----------------

__global__ __launch_bounds__(256) void k_se(const float* __restrict__ agg,
                                            const float* __restrict__ wsumv,
                                            const float* __restrict__ we,
                                            const float* __restrict__ be,
                                            unsigned* __restrict__ sebf) {
    int lane = threadIdx.x & 63, wid = threadIdx.x >> 6;
    float wreg[EDIM];
    #pragma unroll
    for (int k = 0; k < EDIM; ++k) wreg[k] = we[k * HID + lane];
    float bl = be[lane];
    for (int v = blockIdx.x * 4 + wid; v < N_NODES; v += gridDim.x * 4) {
        const float4* ar = (const float4*)(agg + (size_t)v * EDIM);
        float acc = wsumv[v] * bl;
        #pragma unroll
        for (int k4 = 0; k4 < EDIM / 4; ++k4) {
            float4 av = ar[k4];
            int k = k4 * 4;
            acc += av.x * wreg[k + 0] + av.y * wreg[k + 1] +
                   av.z * wreg[k + 2] + av.w * wreg[k + 3];
        }
        float partner = __shfl_xor(acc, 1);
        if ((lane & 1) == 0)
            sebf[(size_t)v * 32 + (lane >> 1)] = pk_bf16(acc, partner);
    }
}

// ---------------- one GCN layer (pull; bf16 h + bf16 se, packed CSR, unroll 8) ----------------

__global__ __launch_bounds__(256) void k_layer(const unsigned* __restrict__ hold,
                                               const unsigned* __restrict__ sebf,
                                               const int4* __restrict__ epk,
                                               const int* __restrict__ offs,
                                               const float* __restrict__ dinv,
                                               unsigned* __restrict__ hnew) {
    int gw = (blockIdx.x * 256 + threadIdx.x) >> 6;
    int lane = threadIdx.x & 63;
    int half = lane >> 5, dp = lane & 31;          // dim pair 2*dp, 2*dp+1
    int v = gw * 2 + half;
    if (v >= N_NODES) return;
    int start = offs[v], end = offs[v + 1];
    float dv = dinv[v];
    size_t vp = (size_t)v * 32 + dp;
    unsigned hv = hold[vp];
    float a0 = dv * bf_lo(hv), a1 = dv * bf_hi(hv);   // self loop (x dv again below)
    for (int i = start; i < end; i += 8) {
        int idx[8]; float nn[8]; unsigned gg[8];
        #pragma unroll
        for (int u = 0; u < 8; ++u) {
            int ii = i + u;
            int4 p = (ii < end) ? epk[ii] : make_int4(0, 0, 0, 0);
            idx[u] = p.x;
            nn[u]  = __int_as_float(p.z);
        }
        #pragma unroll
        for (int u = 0; u < 8; ++u) gg[u] = hold[(size_t)idx[u] * 32 + dp];
        #pragma unroll
        for (int u = 0; u < 8; ++u) {
            a0 += nn[u] * bf_lo(gg[u]);
            a1 += nn[u] * bf_hi(gg[u]);
        }
    }
    unsigned sv = sebf[vp];
    float r0 = bf_lo(sv) + dv * a0;
    float r1 = bf_hi(sv) + dv * a1;
    r0 = (r0 > 0.f) ? r0 : 0.2f * r0;
    r1 = (r1 > 0.f) ? r1 : 0.2f * r1;
    hnew[vp] = pk_bf16(r0, r1);
}

// ---------------- z GEMM + BN stats (bf16 W in LDS; z packed bf16) ----------------
// wpk [96][68] packed bf16 (26.1 KB, 16B-aligned rows, 2-bank-wrap -> conflict-free);
// ut [128][49] f32 (24.5 KB). Total ~52 KB -> 3 blocks/CU.

__global__ __launch_bounds__(256) void k_zstats(const unsigned* __restrict__ hb0,
                                                const unsigned* __restrict__ hb1,
                                                const unsigned* __restrict__ hb2,
                                                const unsigned* __restrict__ hb3,
                                                const float* __restrict__ cfeat,
                                                const float* __restrict__ w1,
                                                const float* __restrict__ b1,
                                                unsigned* __restrict__ zbf,
                                                float* __restrict__ stats) {
    __shared__ unsigned wpk[K1 * 68];  // 26.1 KB
    __shared__ float ut[128 * 49];     // 24.5 KB
    __shared__ float red[4][64];       // 1 KB
    for (int i = threadIdx.x; i < K1 * 64; i += 256) {
        int k = i >> 6, j = i & 63;
        wpk[k * 68 + j] = pk_bf16(w1[k * C1 + 2 * j], w1[k * C1 + 2 * j + 1]);
    }
    int tid = threadIdx.x;
    int lane = tid & 63, wave = tid >> 6;
    int lr = lane >> 3, lc = lane & 7;
    int wr = wave >> 1, wc = wave & 1;
    int rbase = wr * 64 + lr * 8;
    int cbase = wc * 64 + lc * 8;
    float bA[8];
    #pragma unroll
    for (int j = 0; j < 8; ++j) bA[j] = b1[cbase + j];
    float s[8], q[8];
    #pragma unroll
    for (int j = 0; j < 8; ++j) { s[j] = 0.f; q[j] = 0.f; }

    for (int tile = blockIdx.x; tile < ZTILES; tile += gridDim.x) {
        int row0 = tile * 128;
        float acc[8][8];
        #pragma unroll
        for (int i = 0; i < 8; ++i)
            #pragma unroll
            for (int j = 0; j < 8; ++j) acc[i][j] = 0.f;
        for (int ch = 0; ch < 2; ++ch) {
            int kbase = ch * 48;
            __syncthreads();
            #pragma unroll
            for (int p = 0; p < 6; ++p) {
                int idx = p * 256 + tid;
                int row = idx / 12, kq = idx % 12;
                int gk = kbase + kq * 4;
                int gr = row0 + row;
                float f0 = 0.f, f1 = 0.f, f2 = 0.f, f3 = 0.f;
                if (gr < N_NODES) {
                    if (gk < HID) {
                        size_t o = (size_t)gr * 32 + (gk >> 1);
                        uint2 g0 = *(const uint2*)&hb0[o];
                        uint2 g1 = *(const uint2*)&hb1[o];
                        uint2 g2 = *(const uint2*)&hb2[o];
                        uint2 g3 = *(const uint2*)&hb3[o];
                        f0 = bf_lo(g0.x) + bf_lo(g1.x) + bf_lo(g2.x) + bf_lo(g3.x);
                        f1 = bf_hi(g0.x) + bf_hi(g1.x) + bf_hi(g2.x) + bf_hi(g3.x);
                        f2 = bf_lo(g0.y) + bf_lo(g1.y) + bf_lo(g2.y) + bf_lo(g3.y);
                        f3 = bf_hi(g0.y) + bf_hi(g1.y) + bf_hi(g2.y) + bf_hi(g3.y);
                    } else {
                        float4 v = *(const float4*)&cfeat[(size_t)gr * HIER + (gk - HID)];
                        f0 = v.x; f1 = v.y; f2 = v.z; f3 = v.w;
                    }
                }
                float* d = &ut[row * 49 + kq * 4];
                d[0] = f0; d[1] = f1; d[2] = f2; d[3] = f3;
            }
            __syncthreads();
            for (int k = 0; k < 48; ++k) {
                float u[8];
                #pragma unroll
                for (int i = 0; i < 8; ++i) u[i] = ut[(rbase + i) * 49 + k];
                uint4 wp = *(const uint4*)&wpk[(kbase + k) * 68 + (cbase >> 1)];
                float wv[8];
                wv[0] = bf_lo(wp.x); wv[1] = bf_hi(wp.x);
                wv[2] = bf_lo(wp.y); wv[3] = bf_hi(wp.y);
                wv[4] = bf_lo(wp.z); wv[5] = bf_hi(wp.z);
                wv[6] = bf_lo(wp.w); wv[7] = bf_hi(wp.w);
                #pragma unroll
                for (int i = 0; i < 8; ++i) {
                    acc[i][0] += u[i] * wv[0]; acc[i][1] += u[i] * wv[1];
                    acc[i][2] += u[i] * wv[2]; acc[i][3] += u[i] * wv[3];
                    acc[i][4] += u[i] * wv[4]; acc[i][5] += u[i] * wv[5];
                    acc[i][6] += u[i] * wv[6]; acc[i][7] += u[i] * wv[7];
                }
            }
        }
        #pragma unroll
        for (int i = 0; i < 8; ++i) {
            int gr = row0 + rbase + i;
            if (gr < N_NODES) {
                float zz[8];
                #pragma unroll
                for (int j = 0; j < 8; ++j) {
                    zz[j] = acc[i][j] + bA[j];
                    s[j] += zz[j]; q[j] += zz[j] * zz[j];
                }
                uint4 pk;
                pk.x = pk_bf16(zz[0], zz[1]); pk.y = pk_bf16(zz[2], zz[3]);
                pk.z = pk_bf16(zz[4], zz[5]); pk.w = pk_bf16(zz[6], zz[7]);
                *(uint4*)&zbf[(size_t)gr * 64 + (cbase >> 1)] = pk;
            }
        }
    }

    #pragma unroll
    for (int j = 0; j < 8; ++j) {
        s[j] += __shfl_xor(s[j], 8); s[j] += __shfl_xor(s[j], 16); s[j] += __shfl_xor(s[j], 32);
        q[j] += __shfl_xor(q[j], 8); q[j] += __shfl_xor(q[j], 16); q[j] += __shfl_xor(q[j], 32);
    }
    __syncthreads();
    if (lr == 0) {
        #pragma unroll
        for (int j = 0; j < 8; ++j) red[wave][lc * 8 + j] = s[j];
    }
    __syncthreads();
    if (tid < 128) {
        int wc2 = tid >> 6, cl = tid & 63;
        atomicAdd(&stats[wc2 * 64 + cl], red[wc2][cl] + red[wc2 + 2][cl]);
    }
    __syncthreads();
    if (lr == 0) {
        #pragma unroll
        for (int j = 0; j < 8; ++j) red[wave][lc * 8 + j] = q[j];
    }
    __syncthreads();
    if (tid < 128) {
        int wc2 = tid >> 6, cl = tid & 63;
        atomicAdd(&stats[C1 + wc2 * 64 + cl], red[wc2][cl] + red[wc2 + 2][cl]);
    }
}

__global__ void k_ab(const float* __restrict__ stats, const float* __restrict__ gamma,
                     const float* __restrict__ beta, float* __restrict__ ab) {
    int t = threadIdx.x;
    if (t < C1) {
        float mu = stats[t] / (float)N_NODES;
        float var = stats[C1 + t] / (float)N_NODES - mu * mu;
        float inv = rsqrtf(var + BN_EPS);
        float a = gamma[t] * inv;
        ab[t] = a;
        ab[C1 + t] = beta[t] - mu * a;
    }
}

// ---------------- output: thread-per-node, scalar-broadcast weights, NO shuffles ----------------

__global__ __launch_bounds__(256) void k_out3(const unsigned* __restrict__ zbf,
                                              const float* __restrict__ ab,
                                              const float* __restrict__ pa,
                                              const float* __restrict__ w2,
                                              const float* __restrict__ b2,
                                              float* __restrict__ out) {
    int v = blockIdx.x * 256 + threadIdx.x;
    if (v >= N_NODES) return;
    float alpha = pa[0];
    float acc[NCLS];
    #pragma unroll
    for (int j = 0; j < NCLS; ++j) acc[j] = b2[j];
    const uint4* zr = (const uint4*)(zbf + (size_t)v * 64);
    #pragma unroll
    for (int pk4 = 0; pk4 < 16; ++pk4) {
        uint4 g = zr[pk4];
        unsigned gw[4] = {g.x, g.y, g.z, g.w};
        #pragma unroll
        for (int w = 0; w < 4; ++w) {
            int d0 = pk4 * 8 + w * 2;
            float p0 = bf_lo(gw[w]) * ab[d0]     + ab[C1 + d0];
            float p1 = bf_hi(gw[w]) * ab[d0 + 1] + ab[C1 + d0 + 1];
            p0 = (p0 > 0.f) ? p0 : alpha * p0;
            p1 = (p1 > 0.f) ? p1 : alpha * p1;
            #pragma unroll
            for (int j = 0; j < NCLS; ++j)
                acc[j] += p0 * w2[d0 * NCLS + j] + p1 * w2[(d0 + 1) * NCLS + j];
        }
    }
    #pragma unroll
    for (int j = 0; j < NCLS; ++j) out[(size_t)v * NCLS + j] = acc[j];
}

// ---------------- host ----------------

extern "C" void kernel_launch(void* const* d_in, const int* in_sizes, int n_in,
                              void* d_out, int out_size, void* d_ws, size_t ws_size,
                              hipStream_t stream) {
    const float* x      = (const float*)d_in[0];
    const float* e      = (const float*)d_in[1];
    const float* c      = (const float*)d_in[2];
    const float* w_node = (const float*)d_in[3];
    const float* b_node = (const float*)d_in[4];
    const float* w_edge = (const float*)d_in[5];
    const float* b_edge = (const float*)d_in[6];
    const float* w_out1 = (const float*)d_in[7];
    const float* b_out1 = (const float*)d_in[8];
    const float* gamma  = (const float*)d_in[9];
    const float* beta   = (const float*)d_in[10];
    const float* pa     = (const float*)d_in[11];
    const float* w_out2 = (const float*)d_in[12];
    const float* b_out2 = (const float*)d_in[13];
    const int*   ei     = (const int*)d_in[14];
    float* out = (float*)d_out;

    char* wsb = (char*)d_ws;
    // Region A (64MB): ebf [bf16 1M x 32] eid order; dead after k_agg3.
    //   Then sebf (12.8MB, packed bf16) at offset 0 (lives through layers);
    //   zbf (25.6MB, packed bf16) at offset 12.8MB. 12.8 + 25.6 = 38.4MB < 64MB.
    ushort*   ebf  = (ushort*)wsb;
    unsigned* sebf = (unsigned*)wsb;
    unsigned* zbf  = (unsigned*)(wsb + 12800000);
    size_t off = (64000000 + 255) & ~(size_t)255;
    auto alloc = [&](size_t bytes) {
        void* p = wsb + off;
        off = (off + bytes + 255) & ~(size_t)255;
        return p;
    };
    int*      cnt      = (int*)alloc(4ull * N_NODES);
    int*      offs     = (int*)alloc(4ull * (N_NODES + 1));
    float*    dinv     = (float*)alloc(4ull * N_NODES);
    int*      bsum     = (int*)alloc(4ull * 128);
    int4*     epk      = (int4*)alloc(16ull * N_EDGES);          // packed CSR
    float*    agg      = (float*)alloc(4ull * N_NODES * EDIM);
    float*    wsumv    = (float*)alloc(4ull * N_NODES);
    float*    stats    = (float*)alloc(4ull * 256);
    float*    ab       = (float*)alloc(4ull * 256);
    unsigned* hb0      = (unsigned*)alloc(4ull * N_NODES * 32);  // bf16x2 packed
    unsigned* hb1      = (unsigned*)alloc(4ull * N_NODES * 32);
    unsigned* hb2      = (unsigned*)alloc(4ull * N_NODES * 32);
    unsigned* hb3      = (unsigned*)alloc(4ull * N_NODES * 32);

    hipMemsetAsync(cnt, 0, 4ull * N_NODES, stream);
    hipMemsetAsync(stats, 0, 4ull * 256, stream);

    k_count<<<(N_EDGES + 255) / 256, 256, 0, stream>>>(ei, cnt);
    k_scan1<<<SCAN_B, 1024, 0, stream>>>(cnt, offs, dinv, bsum);
    k_scan2<<<1, 1024, 0, stream>>>(bsum, SCAN_B);
    k_scan3<<<SCAN_B, 1024, 0, stream>>>(bsum, offs);
    hipMemsetAsync(cnt, 0, 4ull * N_NODES, stream);
    k_fill<<<(N_EDGES + 255) / 256, 256, 0, stream>>>(ei, offs, cnt, dinv, epk);

    // pure-stream bf16 convert (32M floats / 8 per thread = 15625 blocks)
    k_conv<<<15625, 256, 0, stream>>>((const float4*)e, (uint4*)ebf);
    k_agg3<<<N_NODES * 16 / 256, 256, 0, stream>>>((const unsigned*)ebf, epk,
                                                   offs, dinv, agg, wsumv);

    k_se<<<1280, 256, 0, stream>>>(agg, wsumv, w_edge, b_edge, sebf);  // over dead ebf
    k_h0t2<<<HTILES2, 256, 0, stream>>>(x, w_node, b_node, hb0);

    k_layer<<<N_NODES / 8, 256, 0, stream>>>(hb0, sebf, epk, offs, dinv, hb1);
    k_layer<<<N_NODES / 8, 256, 0, stream>>>(hb1, sebf, epk, offs, dinv, hb2);
    k_layer<<<N_NODES / 8, 256, 0, stream>>>(hb2, sebf, epk, offs, dinv, hb3);

    k_zstats<<<ZTILES, 256, 0, stream>>>(hb0, hb1, hb2, hb3, c, w_out1, b_out1, zbf, stats);
    k_ab<<<1, 128, 0, stream>>>(stats, gamma, beta, ab);
    k_out3<<<(N_NODES + 255) / 256, 256, 0, stream>>>(zbf, ab, pa, w_out2, b_out2, out);
}

// Round 13
// 434.979 us; speedup vs baseline: 2.4292x; 1.0463x over previous
//
#include <hip/hip_runtime.h>
#include <math.h>

#define N_NODES 100000
#define N_EDGES 1000000
#define HID     64
#define HIER    32
#define NDIM    128
#define EDIM    32
#define K1      96    // HIER + HID
#define C1      128   // 2*HID
#define NCLS    10
#define BN_EPS  1e-5f
#define SCAN_B  98    // ceil(N_NODES/1024)
#define ZTILES  782   // ceil(N_NODES/128)
#define HTILES2 782   // ceil(N_NODES/128)

// pack two f32 -> (bf16(a) | bf16(b)<<16), round-to-nearest-even
__device__ __forceinline__ unsigned pk_bf16(float a, float b) {
    unsigned ua = __float_as_uint(a);
    ua = (ua + 0x7FFFu + ((ua >> 16) & 1u)) >> 16;
    unsigned ub = __float_as_uint(b);
    ub = (ub + 0x7FFFu + ((ub >> 16) & 1u)) & 0xFFFF0000u;
    return ua | ub;
}
__device__ __forceinline__ float bf_lo(unsigned g) { return __uint_as_float(g << 16); }
__device__ __forceinline__ float bf_hi(unsigned g) { return __uint_as_float(g & 0xFFFF0000u); }

// ---------------- CSR build ----------------

__global__ void k_count(const int* __restrict__ ei, int* __restrict__ cnt) {
    int i = blockIdx.x * blockDim.x + threadIdx.x;
    if (i < N_EDGES) atomicAdd(&cnt[ei[N_EDGES + i]], 1);
}

__global__ void k_scan1(const int* __restrict__ cnt, int* __restrict__ offs,
                        float* __restrict__ dinv, int* __restrict__ bsum) {
    __shared__ int buf[2][1024];
    int t = threadIdx.x, b = blockIdx.x;
    int i = b * 1024 + t;
    int v = (i < N_NODES) ? cnt[i] : 0;
    buf[0][t] = v; __syncthreads();
    int pi = 0;
    for (int off = 1; off < 1024; off <<= 1) {
        int x = buf[pi][t];
        if (t >= off) x += buf[pi][t - off];
        buf[pi ^ 1][t] = x; __syncthreads(); pi ^= 1;
    }
    int incl = buf[pi][t];
    if (i < N_NODES) {
        offs[i] = incl - v;
        dinv[i] = rsqrtf((float)(v + 1));
    }
    if (t == 1023) bsum[b] = incl;
}

__global__ void k_scan2(int* __restrict__ bsum, int nb) {
    __shared__ int buf[2][1024];
    int t = threadIdx.x;
    int v = (t < nb) ? bsum[t] : 0;
    buf[0][t] = v; __syncthreads();
    int pi = 0;
    for (int off = 1; off < 1024; off <<= 1) {
        int x = buf[pi][t];
        if (t >= off) x += buf[pi][t - off];
        buf[pi ^ 1][t] = x; __syncthreads(); pi ^= 1;
    }
    int incl = buf[pi][t];
    if (t < nb) bsum[t] = incl - v;
}

__global__ void k_scan3(const int* __restrict__ bsum, int* __restrict__ offs) {
    int b = blockIdx.x;
    int i = b * 1024 + threadIdx.x;
    if (i < N_NODES) offs[i] += bsum[b];
    if (i == 0) offs[N_NODES] = N_EDGES;
}

// packed CSR record: {src, eid, norm_bits, pad} -> ONE 16B scattered store/edge
__global__ void k_fill(const int* __restrict__ ei, const int* __restrict__ offs,
                       int* __restrict__ cursor, const float* __restrict__ dinv,
                       int4* __restrict__ epk) {
    int i = blockIdx.x * blockDim.x + threadIdx.x;
    if (i >= N_EDGES) return;
    int s = ei[i], d = ei[N_EDGES + i];
    int pos = offs[d] + atomicAdd(&cursor[d], 1);
    epk[pos] = make_int4(s, i, __float_as_int(dinv[s]), 0);
}

// ---------------- pure streaming converts ----------------

__global__ __launch_bounds__(256) void k_conv(const float4* __restrict__ e4,
                                              uint4* __restrict__ eb4) {
    int i = blockIdx.x * 256 + threadIdx.x;     // 4M threads, 8 floats each
    float4 a = e4[(size_t)2 * i];
    float4 b = e4[(size_t)2 * i + 1];
    uint4 pk;
    pk.x = pk_bf16(a.x, a.y); pk.y = pk_bf16(a.z, a.w);
    pk.z = pk_bf16(b.x, b.y); pk.w = pk_bf16(b.z, b.w);
    eb4[i] = pk;
}

// c [N x 32 f32] -> cbf packed bf16 [N x 16 uints]
__global__ __launch_bounds__(256) void k_conv2(const float4* __restrict__ c4,
                                               uint2* __restrict__ cb2) {
    int i = blockIdx.x * 256 + threadIdx.x;     // N*8 float4s
    if (i >= N_NODES * 8) return;
    float4 a = c4[i];
    cb2[i] = make_uint2(pk_bf16(a.x, a.y), pk_bf16(a.z, a.w));
}

// ---------------- edge aggregation: quarter-wave per node ----------------

__global__ __launch_bounds__(256) void k_agg3(const unsigned* __restrict__ ebfu,
                                              const int4* __restrict__ epk,
                                              const int* __restrict__ offs,
                                              const float* __restrict__ dinv,
                                              float* __restrict__ agg,
                                              float* __restrict__ wsumv) {
    int v = (blockIdx.x * 256 + threadIdx.x) >> 4;
    if (v >= N_NODES) return;
    int q = threadIdx.x & 15;                  // uint index = dims 2q, 2q+1
    int start = offs[v], end = offs[v + 1];
    float ax = 0.f, ay = 0.f, wacc = 0.f;
    for (int i = start; i < end; i += 4) {
        int i1 = i + 1, i2 = i + 2, i3 = i + 3;
        int4 p0 = epk[i];
        int4 p1 = (i1 < end) ? epk[i1] : make_int4(0, 0, 0, 0);
        int4 p2 = (i2 < end) ? epk[i2] : make_int4(0, 0, 0, 0);
        int4 p3 = (i3 < end) ? epk[i3] : make_int4(0, 0, 0, 0);
        float n0 = __int_as_float(p0.z), n1 = __int_as_float(p1.z);
        float n2 = __int_as_float(p2.z), n3 = __int_as_float(p3.z);
        unsigned g0 = ebfu[(size_t)p0.y * 16 + q];
        unsigned g1 = ebfu[(size_t)p1.y * 16 + q];
        unsigned g2 = ebfu[(size_t)p2.y * 16 + q];
        unsigned g3 = ebfu[(size_t)p3.y * 16 + q];
        ax += n0 * bf_lo(g0) + n1 * bf_lo(g1) + n2 * bf_lo(g2) + n3 * bf_lo(g3);
        ay += n0 * bf_hi(g0) + n1 * bf_hi(g1) + n2 * bf_hi(g2) + n3 * bf_hi(g3);
        wacc += n0 + n1 + n2 + n3;
    }
    float dv = dinv[v];
    *(float2*)&agg[(size_t)v * EDIM + q * 2] = make_float2(dv * ax, dv * ay);
    if (q == 0) wsumv[v] = dv * wacc;
}

// ---------------- node encoder (tiled GEMM, bf16 W in LDS) ----------------

__global__ __launch_bounds__(256) void k_h0t2(const float* __restrict__ x,
                                              const float* __restrict__ w,
                                              const float* __restrict__ bias,
                                              unsigned* __restrict__ hbf) {
    __shared__ __align__(16) unsigned wpk[NDIM * 36];  // 18.4 KB
    __shared__ float xt[128 * 33];                     // 16.9 KB
    for (int i = threadIdx.x; i < NDIM * 32; i += 256) {
        int k = i >> 5, j = i & 31;
        wpk[k * 36 + j] = pk_bf16(w[k * HID + 2 * j], w[k * HID + 2 * j + 1]);
    }
    int tid = threadIdx.x;
    int lane = tid & 63, wave = tid >> 6;
    int lr = lane >> 3, lc = lane & 7;
    int rbase = wave * 32 + lr * 4;      // 4 rows per thread
    int cbase = lc * 8;                  // 8 cols per thread
    float bA[8];
    #pragma unroll
    for (int j = 0; j < 8; ++j) bA[j] = bias[cbase + j];
    for (int tile = blockIdx.x; tile < HTILES2; tile += gridDim.x) {
        int row0 = tile * 128;
        float acc[4][8];
        #pragma unroll
        for (int i = 0; i < 4; ++i)
            #pragma unroll
            for (int j = 0; j < 8; ++j) acc[i][j] = 0.f;
        for (int ch = 0; ch < 4; ++ch) {
            __syncthreads();
            #pragma unroll
            for (int p = 0; p < 4; ++p) {
                int idx = p * 256 + tid;
                int row = idx >> 3, kq = idx & 7;
                int gk = ch * 32 + kq * 4;
                float4 v = make_float4(0.f, 0.f, 0.f, 0.f);
                int gr = row0 + row;
                if (gr < N_NODES) v = *(const float4*)&x[(size_t)gr * NDIM + gk];
                float* d = &xt[row * 33 + kq * 4];
                d[0] = v.x; d[1] = v.y; d[2] = v.z; d[3] = v.w;
            }
            __syncthreads();
            for (int k = 0; k < 32; ++k) {
                float u[4];
                #pragma unroll
                for (int i = 0; i < 4; ++i) u[i] = xt[(rbase + i) * 33 + k];
                uint4 wp = *(const uint4*)&wpk[(ch * 32 + k) * 36 + lc * 4];
                float wv[8];
                wv[0] = bf_lo(wp.x); wv[1] = bf_hi(wp.x);
                wv[2] = bf_lo(wp.y); wv[3] = bf_hi(wp.y);
                wv[4] = bf_lo(wp.z); wv[5] = bf_hi(wp.z);
                wv[6] = bf_lo(wp.w); wv[7] = bf_hi(wp.w);
                #pragma unroll
                for (int i = 0; i < 4; ++i)
                    #pragma unroll
                    for (int j = 0; j < 8; ++j) acc[i][j] += u[i] * wv[j];
            }
        }
        #pragma unroll
        for (int i = 0; i < 4; ++i) {
            int gr = row0 + rbase + i;
            if (gr < N_NODES) {
                uint4 pk;
                pk.x = pk_bf16(acc[i][0] + bA[0], acc[i][1] + bA[1]);
                pk.y = pk_bf16(acc[i][2] + bA[2], acc[i][3] + bA[3]);
                pk.z = pk_bf16(acc[i][4] + bA[4], acc[i][5] + bA[5]);
                pk.w = pk_bf16(acc[i][6] + bA[6], acc[i][7] + bA[7]);
                *(uint4*)&hbf[(size_t)gr * 32 + (cbase >> 1)] = pk;
            }
        }
    }
}

// ---------------- s_e = bf16(agg @ w_edge + wsum * b_edge), packed pairs ----------------

__global__ __launch_bounds__(256) void k_se(const float* __restrict__ agg,
                                            const float* __restrict__ wsumv,
                                            const float* __restrict__ we,
                                            const float* __restrict__ be,
                                            unsigned* __restrict__ sebf) {
    int lane = threadIdx.x & 63, wid = threadIdx.x >> 6;
    float wreg[EDIM];
    #pragma unroll
    for (int k = 0; k < EDIM; ++k) wreg[k] = we[k * HID + lane];
    float bl = be[lane];
    for (int v = blockIdx.x * 4 + wid; v < N_NODES; v += gridDim.x * 4) {
        const float4* ar = (const float4*)(agg + (size_t)v * EDIM);
        float acc = wsumv[v] * bl;
        #pragma unroll
        for (int k4 = 0; k4 < EDIM / 4; ++k4) {
            float4 av = ar[k4];
            int k = k4 * 4;
            acc += av.x * wreg[k + 0] + av.y * wreg[k + 1] +
                   av.z * wreg[k + 2] + av.w * wreg[k + 3];
        }
        float partner = __shfl_xor(acc, 1);
        if ((lane & 1) == 0)
            sebf[(size_t)v * 32 + (lane >> 1)] = pk_bf16(acc, partner);
    }
}

// ---------------- GCN layer (quarter-wave: 4 nodes/wave, uint2 lanes, unroll 8) ----------------

__global__ __launch_bounds__(256) void k_layer4(const unsigned* __restrict__ hold,
                                                const unsigned* __restrict__ sebf,
                                                const int4* __restrict__ epk,
                                                const int* __restrict__ offs,
                                                const float* __restrict__ dinv,
                                                unsigned* __restrict__ hnew) {
    int v = (blockIdx.x * 256 + threadIdx.x) >> 4;
    if (v >= N_NODES) return;
    int q = threadIdx.x & 15;                 // uint2 index: dims 4q..4q+3
    int start = offs[v], end = offs[v + 1];
    float dv = dinv[v];
    size_t vp = (size_t)v * 16 + q;
    uint2 hv = ((const uint2*)hold)[vp];
    float a0 = dv * bf_lo(hv.x), a1 = dv * bf_hi(hv.x);
    float a2 = dv * bf_lo(hv.y), a3 = dv * bf_hi(hv.y);
    for (int i = start; i < end; i += 8) {
        int idx[8]; float nn[8]; uint2 gg[8];
        #pragma unroll
        for (int u = 0; u < 8; ++u) {
            int ii = i + u;
            int4 p = (ii < end) ? epk[ii] : make_int4(0, 0, 0, 0);
            idx[u] = p.x;
            nn[u]  = __int_as_float(p.z);
        }
        #pragma unroll
        for (int u = 0; u < 8; ++u) gg[u] = ((const uint2*)hold)[(size_t)idx[u] * 16 + q];
        #pragma unroll
        for (int u = 0; u < 8; ++u) {
            a0 += nn[u] * bf_lo(gg[u].x); a1 += nn[u] * bf_hi(gg[u].x);
            a2 += nn[u] * bf_lo(gg[u].y); a3 += nn[u] * bf_hi(gg[u].y);
        }
    }
    uint2 sv = ((const uint2*)sebf)[vp];
    float r0 = bf_lo(sv.x) + dv * a0;
    float r1 = bf_hi(sv.x) + dv * a1;
    float r2 = bf_lo(sv.y) + dv * a2;
    float r3 = bf_hi(sv.y) + dv * a3;
    r0 = (r0 > 0.f) ? r0 : 0.2f * r0;
    r1 = (r1 > 0.f) ? r1 : 0.2f * r1;
    r2 = (r2 > 0.f) ? r2 : 0.2f * r2;
    r3 = (r3 > 0.f) ? r3 : 0.2f * r3;
    ((uint2*)hnew)[vp] = make_uint2(pk_bf16(r0, r1), pk_bf16(r2, r3));
}

// layer 3 variant: also emits hsbf = bf16(h0 + h1 + h2 + h3)
__global__ __launch_bounds__(256) void k_layer4s(const unsigned* __restrict__ hold, // = h2
                                                 const unsigned* __restrict__ hb0,
                                                 const unsigned* __restrict__ hb1,
                                                 const unsigned* __restrict__ sebf,
                                                 const int4* __restrict__ epk,
                                                 const int* __restrict__ offs,
                                                 const float* __restrict__ dinv,
                                                 unsigned* __restrict__ hnew,
                                                 unsigned* __restrict__ hsbf) {
    int v = (blockIdx.x * 256 + threadIdx.x) >> 4;
    if (v >= N_NODES) return;
    int q = threadIdx.x & 15;
    int start = offs[v], end = offs[v + 1];
    float dv = dinv[v];
    size_t vp = (size_t)v * 16 + q;
    uint2 hv = ((const uint2*)hold)[vp];
    float a0 = dv * bf_lo(hv.x), a1 = dv * bf_hi(hv.x);
    float a2 = dv * bf_lo(hv.y), a3 = dv * bf_hi(hv.y);
    for (int i = start; i < end; i += 8) {
        int idx[8]; float nn[8]; uint2 gg[8];
        #pragma unroll
        for (int u = 0; u < 8; ++u) {
            int ii = i + u;
            int4 p = (ii < end) ? epk[ii] : make_int4(0, 0, 0, 0);
            idx[u] = p.x;
            nn[u]  = __int_as_float(p.z);
        }
        #pragma unroll
        for (int u = 0; u < 8; ++u) gg[u] = ((const uint2*)hold)[(size_t)idx[u] * 16 + q];
        #pragma unroll
        for (int u = 0; u < 8; ++u) {
            a0 += nn[u] * bf_lo(gg[u].x); a1 += nn[u] * bf_hi(gg[u].x);
            a2 += nn[u] * bf_lo(gg[u].y); a3 += nn[u] * bf_hi(gg[u].y);
        }
    }
    uint2 sv = ((const uint2*)sebf)[vp];
    float r0 = bf_lo(sv.x) + dv * a0;
    float r1 = bf_hi(sv.x) + dv * a1;
    float r2 = bf_lo(sv.y) + dv * a2;
    float r3 = bf_hi(sv.y) + dv * a3;
    r0 = (r0 > 0.f) ? r0 : 0.2f * r0;
    r1 = (r1 > 0.f) ? r1 : 0.2f * r1;
    r2 = (r2 > 0.f) ? r2 : 0.2f * r2;
    r3 = (r3 > 0.f) ? r3 : 0.2f * r3;
    ((uint2*)hnew)[vp] = make_uint2(pk_bf16(r0, r1), pk_bf16(r2, r3));
    uint2 g0 = ((const uint2*)hb0)[vp];
    uint2 g1 = ((const uint2*)hb1)[vp];
    float s0 = r0 + bf_lo(g0.x) + bf_lo(g1.x) + bf_lo(hv.x);
    float s1 = r1 + bf_hi(g0.x) + bf_hi(g1.x) + bf_hi(hv.x);
    float s2 = r2 + bf_lo(g0.y) + bf_lo(g1.y) + bf_lo(hv.y);
    float s3 = r3 + bf_hi(g0.y) + bf_hi(g1.y) + bf_hi(hv.y);
    ((uint2*)hsbf)[vp] = make_uint2(pk_bf16(s0, s1), pk_bf16(s2, s3));
}

// ---------------- z GEMM + BN stats (transposed bf16 U panel in LDS) ----------------
// ut[k][rp] packs rows (2rp, 2rp+1) at element k -> thread's 8 rows at k = ONE b128.
// Per k-step: 1 b128 (u, 8-lane broadcast) + 1 b128 (w) -- conflict-free.
// LDS: ut 96x68 uints (26.1KB) + wpk 96x68 (26.1KB) + red 1KB = 53KB -> 3 blocks/CU.

__global__ __launch_bounds__(256) void k_zstats(const unsigned* __restrict__ hsbf,
                                                const unsigned* __restrict__ cbf,
                                                const float* __restrict__ w1,
                                                const float* __restrict__ b1,
                                                unsigned* __restrict__ zbf,
                                                float* __restrict__ stats) {
    __shared__ __align__(16) unsigned wpk[K1 * 68];  // 26.1 KB
    __shared__ __align__(16) unsigned ut[K1 * 68];   // 26.1 KB
    __shared__ float red[4][64];                     // 1 KB
    for (int i = threadIdx.x; i < K1 * 64; i += 256) {
        int k = i >> 6, j = i & 63;
        wpk[k * 68 + j] = pk_bf16(w1[k * C1 + 2 * j], w1[k * C1 + 2 * j + 1]);
    }
    int tid = threadIdx.x;
    int lane = tid & 63, wave = tid >> 6;
    int lr = lane >> 3, lc = lane & 7;
    int wr = wave >> 1, wc = wave & 1;
    int rbase = wr * 64 + lr * 8;
    int cbase = wc * 64 + lc * 8;
    int kslot = wave;           // stage: wave = k-slot, lane = row-pair
    int rp = lane;
    float bA[8];
    #pragma unroll
    for (int j = 0; j < 8; ++j) bA[j] = b1[cbase + j];
    float s[8], q[8];
    #pragma unroll
    for (int j = 0; j < 8; ++j) { s[j] = 0.f; q[j] = 0.f; }

    for (int tile = blockIdx.x; tile < ZTILES; tile += gridDim.x) {
        int row0 = tile * 128;
        __syncthreads();
        // ---- stage: transpose + row-pair pack into ut ----
        {
            int r0g = row0 + 2 * rp, r1g = r0g + 1;
            bool ok0 = r0g < N_NODES, ok1 = r1g < N_NODES;
            #pragma unroll
            for (int kku = 0; kku < 12; ++kku) {
                int ku = kslot * 12 + kku;
                unsigned A = 0u, B = 0u;
                if (ku < 32) {
                    if (ok0) A = hsbf[(size_t)r0g * 32 + ku];
                    if (ok1) B = hsbf[(size_t)r1g * 32 + ku];
                } else {
                    if (ok0) A = cbf[(size_t)r0g * 16 + (ku - 32)];
                    if (ok1) B = cbf[(size_t)r1g * 16 + (ku - 32)];
                }
                int k0 = 2 * ku;
                ut[k0 * 68 + rp]       = (A & 0xFFFFu) | (B << 16);
                ut[(k0 + 1) * 68 + rp] = (A >> 16) | (B & 0xFFFF0000u);
            }
        }
        __syncthreads();
        // ---- compute ----
        float acc[8][8];
        #pragma unroll
        for (int i = 0; i < 8; ++i)
            #pragma unroll
            for (int j = 0; j < 8; ++j) acc[i][j] = 0.f;
        for (int k = 0; k < K1; ++k) {
            uint4 up = *(const uint4*)&ut[k * 68 + wr * 32 + lr * 4];
            uint4 wp = *(const uint4*)&wpk[k * 68 + wc * 32 + lc * 4];
            float u[8], wv[8];
            u[0] = bf_lo(up.x); u[1] = bf_hi(up.x);
            u[2] = bf_lo(up.y); u[3] = bf_hi(up.y);
            u[4] = bf_lo(up.z); u[5] = bf_hi(up.z);
            u[6] = bf_lo(up.w); u[7] = bf_hi(up.w);
            wv[0] = bf_lo(wp.x); wv[1] = bf_hi(wp.x);
            wv[2] = bf_lo(wp.y); wv[3] = bf_hi(wp.y);
            wv[4] = bf_lo(wp.z); wv[5] = bf_hi(wp.z);
            wv[6] = bf_lo(wp.w); wv[7] = bf_hi(wp.w);
            #pragma unroll
            for (int i = 0; i < 8; ++i) {
                acc[i][0] += u[i] * wv[0]; acc[i][1] += u[i] * wv[1];
                acc[i][2] += u[i] * wv[2]; acc[i][3] += u[i] * wv[3];
                acc[i][4] += u[i] * wv[4]; acc[i][5] += u[i] * wv[5];
                acc[i][6] += u[i] * wv[6]; acc[i][7] += u[i] * wv[7];
            }
        }
        #pragma unroll
        for (int i = 0; i < 8; ++i) {
            int gr = row0 + rbase + i;
            if (gr < N_NODES) {
                float zz[8];
                #pragma unroll
                for (int j = 0; j < 8; ++j) {
                    zz[j] = acc[i][j] + bA[j];
                    s[j] += zz[j]; q[j] += zz[j] * zz[j];
                }
                uint4 pk;
                pk.x = pk_bf16(zz[0], zz[1]); pk.y = pk_bf16(zz[2], zz[3]);
                pk.z = pk_bf16(zz[4], zz[5]); pk.w = pk_bf16(zz[6], zz[7]);
                *(uint4*)&zbf[(size_t)gr * 64 + (cbase >> 1)] = pk;
            }
        }
    }

    #pragma unroll
    for (int j = 0; j < 8; ++j) {
        s[j] += __shfl_xor(s[j], 8); s[j] += __shfl_xor(s[j], 16); s[j] += __shfl_xor(s[j], 32);
        q[j] += __shfl_xor(q[j], 8); q[j] += __shfl_xor(q[j], 16); q[j] += __shfl_xor(q[j], 32);
    }
    __syncthreads();
    if (lr == 0) {
        #pragma unroll
        for (int j = 0; j < 8; ++j) red[wave][lc * 8 + j] = s[j];
    }
    __syncthreads();
    if (tid < 128) {
        int wc2 = tid >> 6, cl = tid & 63;
        atomicAdd(&stats[wc2 * 64 + cl], red[wc2][cl] + red[wc2 + 2][cl]);
    }
    __syncthreads();
    if (lr == 0) {
        #pragma unroll
        for (int j = 0; j < 8; ++j) red[wave][lc * 8 + j] = q[j];
    }
    __syncthreads();
    if (tid < 128) {
        int wc2 = tid >> 6, cl = tid & 63;
        atomicAdd(&stats[C1 + wc2 * 64 + cl], red[wc2][cl] + red[wc2 + 2][cl]);
    }
}

__global__ void k_ab(const float* __restrict__ stats, const float* __restrict__ gamma,
                     const float* __restrict__ beta, float* __restrict__ ab) {
    int t = threadIdx.x;
    if (t < C1) {
        float mu = stats[t] / (float)N_NODES;
        float var = stats[C1 + t] / (float)N_NODES - mu * mu;
        float inv = rsqrtf(var + BN_EPS);
        float a = gamma[t] * inv;
        ab[t] = a;
        ab[C1 + t] = beta[t] - mu * a;
    }
}

// ---------------- output: thread-per-node, scalar-broadcast weights ----------------

__global__ __launch_bounds__(256) void k_out3(const unsigned* __restrict__ zbf,
                                              const float* __restrict__ ab,
                                              const float* __restrict__ pa,
                                              const float* __restrict__ w2,
                                              const float* __restrict__ b2,
                                              float* __restrict__ out) {
    int v = blockIdx.x * 256 + threadIdx.x;
    if (v >= N_NODES) return;
    float alpha = pa[0];
    float acc[NCLS];
    #pragma unroll
    for (int j = 0; j < NCLS; ++j) acc[j] = b2[j];
    const uint4* zr = (const uint4*)(zbf + (size_t)v * 64);
    #pragma unroll
    for (int pk4 = 0; pk4 < 16; ++pk4) {
        uint4 g = zr[pk4];
        unsigned gw[4] = {g.x, g.y, g.z, g.w};
        #pragma unroll
        for (int w = 0; w < 4; ++w) {
            int d0 = pk4 * 8 + w * 2;
            float p0 = bf_lo(gw[w]) * ab[d0]     + ab[C1 + d0];
            float p1 = bf_hi(gw[w]) * ab[d0 + 1] + ab[C1 + d0 + 1];
            p0 = (p0 > 0.f) ? p0 : alpha * p0;
            p1 = (p1 > 0.f) ? p1 : alpha * p1;
            #pragma unroll
            for (int j = 0; j < NCLS; ++j)
                acc[j] += p0 * w2[d0 * NCLS + j] + p1 * w2[(d0 + 1) * NCLS + j];
        }
    }
    #pragma unroll
    for (int j = 0; j < NCLS; ++j) out[(size_t)v * NCLS + j] = acc[j];
}

// ---------------- host ----------------

extern "C" void kernel_launch(void* const* d_in, const int* in_sizes, int n_in,
                              void* d_out, int out_size, void* d_ws, size_t ws_size,
                              hipStream_t stream) {
    const float* x      = (const float*)d_in[0];
    const float* e      = (const float*)d_in[1];
    const float* c      = (const float*)d_in[2];
    const float* w_node = (const float*)d_in[3];
    const float* b_node = (const float*)d_in[4];
    const float* w_edge = (const float*)d_in[5];
    const float* b_edge = (const float*)d_in[6];
    const float* w_out1 = (const float*)d_in[7];
    const float* b_out1 = (const float*)d_in[8];
    const float* gamma  = (const float*)d_in[9];
    const float* beta   = (const float*)d_in[10];
    const float* pa     = (const float*)d_in[11];
    const float* w_out2 = (const float*)d_in[12];
    const float* b_out2 = (const float*)d_in[13];
    const int*   ei     = (const int*)d_in[14];
    float* out = (float*)d_out;

    char* wsb = (char*)d_ws;
    // Region A (64MB): ebf [bf16 1M x 32] eid order; dead after k_agg3.
    //   Then sebf (12.8MB) at 0; zbf (25.6MB) at 12.8MB. 38.4MB < 64MB.
    ushort*   ebf  = (ushort*)wsb;
    unsigned* sebf = (unsigned*)wsb;
    unsigned* zbf  = (unsigned*)(wsb + 12800000);
    size_t off = (64000000 + 255) & ~(size_t)255;
    auto alloc = [&](size_t bytes) {
        void* p = wsb + off;
        off = (off + bytes + 255) & ~(size_t)255;
        return p;
    };
    int*      cnt      = (int*)alloc(4ull * N_NODES);
    int*      offs     = (int*)alloc(4ull * (N_NODES + 1));
    float*    dinv     = (float*)alloc(4ull * N_NODES);
    int*      bsum     = (int*)alloc(4ull * 128);
    int4*     epk      = (int4*)alloc(16ull * N_EDGES);          // packed CSR
    float*    agg      = (float*)alloc(4ull * N_NODES * EDIM);   // dead after k_se
    float*    wsumv    = (float*)alloc(4ull * N_NODES);
    float*    stats    = (float*)alloc(4ull * 256);
    float*    ab       = (float*)alloc(4ull * 256);
    unsigned* hb0      = (unsigned*)alloc(4ull * N_NODES * 32);  // bf16x2 packed
    unsigned* hb1      = (unsigned*)alloc(4ull * N_NODES * 32);
    unsigned* hb2      = (unsigned*)alloc(4ull * N_NODES * 32);
    unsigned* hb3      = (unsigned*)alloc(4ull * N_NODES * 32);
    unsigned* cbf      = (unsigned*)alloc(4ull * N_NODES * 16);  // c in bf16
    unsigned* hsbf     = (unsigned*)agg;   // hsum bf16 overlays dead agg (12.8MB)

    hipMemsetAsync(cnt, 0, 4ull * N_NODES, stream);
    hipMemsetAsync(stats, 0, 4ull * 256, stream);

    k_count<<<(N_EDGES + 255) / 256, 256, 0, stream>>>(ei, cnt);
    k_scan1<<<SCAN_B, 1024, 0, stream>>>(cnt, offs, dinv, bsum);
    k_scan2<<<1, 1024, 0, stream>>>(bsum, SCAN_B);
    k_scan3<<<SCAN_B, 1024, 0, stream>>>(bsum, offs);
    hipMemsetAsync(cnt, 0, 4ull * N_NODES, stream);
    k_fill<<<(N_EDGES + 255) / 256, 256, 0, stream>>>(ei, offs, cnt, dinv, epk);

    k_conv<<<15625, 256, 0, stream>>>((const float4*)e, (uint4*)ebf);
    k_agg3<<<N_NODES * 16 / 256, 256, 0, stream>>>((const unsigned*)ebf, epk,
                                                   offs, dinv, agg, wsumv);

    k_se<<<1280, 256, 0, stream>>>(agg, wsumv, w_edge, b_edge, sebf);  // over dead ebf
    k_conv2<<<(N_NODES * 8 + 255) / 256, 256, 0, stream>>>((const float4*)c, (uint2*)cbf);
    k_h0t2<<<HTILES2, 256, 0, stream>>>(x, w_node, b_node, hb0);

    k_layer4<<<N_NODES * 16 / 256, 256, 0, stream>>>(hb0, sebf, epk, offs, dinv, hb1);
    k_layer4<<<N_NODES * 16 / 256, 256, 0, stream>>>(hb1, sebf, epk, offs, dinv, hb2);
    k_layer4s<<<N_NODES * 16 / 256, 256, 0, stream>>>(hb2, hb0, hb1, sebf, epk, offs,
                                                      dinv, hb3, hsbf);

    k_zstats<<<ZTILES, 256, 0, stream>>>(hsbf, cbf, w_out1, b_out1, zbf, stats);
    k_ab<<<1, 128, 0, stream>>>(stats, gamma, beta, ab);
    k_out3<<<(N_NODES + 255) / 256, 256, 0, stream>>>(zbf, ab, pa, w_out2, b_out2, out);
}